// Round 2
// baseline (1395.747 us; speedup 1.0000x reference)
//
#include <hip/hip_runtime.h>
#include <hip/hip_bf16.h>

// ---------------------------------------------------------------------------
// VQ-VAE forward, fp32. NCHW.
// R17: res_fused3 = wide-block residual fusion. R16 post-mortem: splitting
// px 256->128 doubled halo fetch (36->46MB) + staging/barrier overhead and
// ate the occupancy gain. R17 keeps 256 px/block (R15 staging economics:
// 36MB fetch, 64 barriers/block) but widens to 512 threads / 8 waves ->
// 2 blocks/CU x 8 waves = 16 waves/CU (4/SIMD), double R15's latency hiding.
//   - conv1: thread owns 8 couts x 2 px (float2 LDS reads, 2-way alias=free)
//   - staging: 36 wave-uniform (tap,row) groups of 64 lanes; SALU ih check
//   - conv2: thread owns 16 couts x 2 px
// Per-output scalar FMA chains bit-identical to R15/R16 (cin asc, tap asc;
// conv2 k asc; same staged relu/zeros; same residual order) => VQ argmin
// unchanged (R3 lesson). All other kernels byte-identical to R16.
// ---------------------------------------------------------------------------

__device__ __forceinline__ float rp_elem(const float* __restrict__ src,
                                         int i, int COUT, int CIN, int KK)
{
    const int co = i % COUT;
    const int t  = i / COUT;
    const int kk = t % KK;
    const int ci = t / KK;
    return src[(co * CIN + ci) * KK + kk];
}

// One kernel repacks all weights + codebook-transpose into WR.
__global__ __launch_bounds__(256) void repack_all(
    const float* __restrict__ e1,  const float* __restrict__ e2,
    const float* __restrict__ er1a, const float* __restrict__ er1b,
    const float* __restrict__ er2a, const float* __restrict__ er2b,
    const float* __restrict__ pre, const float* __restrict__ d1,
    const float* __restrict__ dr1a, const float* __restrict__ dr1b,
    const float* __restrict__ dr2a, const float* __restrict__ dr2b,
    const float* __restrict__ t1, const float* __restrict__ cb,
    float* __restrict__ WR)
{
    const int idx = blockIdx.x * 256 + threadIdx.x;
    if (idx >= 221696) return;
    float v;
    if      (idx < 512)    v = rp_elem(e1,   idx,          32,  1, 16);
    else if (idx < 33280)  v = rp_elem(e2,   idx - 512,    64, 32, 16);
    else if (idx < 51712)  v = rp_elem(er1a, idx - 33280,  32, 64,  9);
    else if (idx < 53760)  v = rp_elem(er1b, idx - 51712,  64, 32,  1);
    else if (idx < 72192)  v = rp_elem(er2a, idx - 53760,  32, 64,  9);
    else if (idx < 74240)  v = rp_elem(er2b, idx - 72192,  64, 32,  1);
    else if (idx < 78336)  v = rp_elem(pre,  idx - 74240,  64, 64,  1);
    else if (idx < 115200) v = rp_elem(d1,   idx - 78336,  64, 64,  9);
    else if (idx < 133632) v = rp_elem(dr1a, idx - 115200, 32, 64,  9);
    else if (idx < 135680) v = rp_elem(dr1b, idx - 133632, 64, 32,  1);
    else if (idx < 154112) v = rp_elem(dr2a, idx - 135680, 32, 64,  9);
    else if (idx < 156160) v = rp_elem(dr2b, idx - 154112, 64, 32,  1);
    else if (idx < 188928) {
        // t1: [pr][k2=ci*2+ta][q=pc*2+tb][co]
        const int i  = idx - 156160;
        const int co = i & 31;
        const int q  = (i >> 5) & 3;
        const int k2 = (i >> 7) & 127;
        const int pr = i >> 14;
        const int pc = q >> 1, tb = q & 1;
        const int ci = k2 >> 1, ta = k2 & 1;
        const int kh = (1 - pr) + 2 * ta, kw = (1 - pc) + 2 * tb;
        v = t1[((ci * 32 + co) * 4 + kh) * 4 + kw];
    } else {
        const int i = idx - 188928;           // cbT: [dim][code]
        const int code = i & 511;
        const int dim  = i >> 9;
        v = cb[code * 64 + dim];
    }
    WR[idx] = v;
}

// ee[k] = sum_i cb[k][i]^2, exact ascending fmaf chain (matches reference).
__global__ __launch_bounds__(256) void vq_prep_ee(
    const float* __restrict__ cb, float* __restrict__ ee)
{
    const int k = blockIdx.x * 256 + threadIdx.x;  // grid(2) -> k < 512
    const float* __restrict__ cp = cb + (size_t)k * 64;
    float s = 0.0f;
#pragma unroll
    for (int i = 0; i < 64; i++) s = fmaf(cp[i], cp[i], s);
    ee[k] = s;
}

// GEMM-form conv (validated R13). Block: CPB couts x 256 pixels; thread:
// CPTHD x 4 pixels. K-chunks double-buffered in LDS; K=4 tap-split.
template<int CTOT, int CPB, int CIN, int K, int S, int PAD,
         bool RELU_IN, bool HAS_BIAS, bool RESID, bool RELU_OUT>
__global__ __launch_bounds__(256) void conv_gemm(
    const float* __restrict__ in, const float* __restrict__ wr,
    const float* __restrict__ bias, const float* __restrict__ resid,
    float* __restrict__ out,
    int H, int W, int OH, int OW)
{
    constexpr int KK  = K * K;
    constexpr int CIC = (K == 1) ? 8 : 1;
    constexpr int TS  = (K == 4) ? 2 : 1;
    constexpr int KC  = CIC * KK / TS;
    constexpr int NCH = (CIN * TS) / CIC;
    constexpr int NT  = 256;
    constexpr int CPTHD = CPB / 4;
    __shared__ __align__(16) float As[2][KC * NT];

    const int tid = threadIdx.x;
    const int tpx = tid & 63;
    const int tco = __builtin_amdgcn_readfirstlane(tid >> 6);
    const int co0 = blockIdx.y * CPB + tco * CPTHD;

    const int ohow = OH * OW;
    const int n_st = blockIdx.x * NT + tid;
    const int b_st = n_st / ohow;
    const int hw_s = n_st % ohow;
    const int ih0 = (hw_s / OW) * S - PAD;
    const int iw0 = (hw_s % OW) * S - PAD;
    const float* __restrict__ inb = in + (size_t)b_st * CIN * H * W;

    float acc[CPTHD][4];
#pragma unroll
    for (int c = 0; c < CPTHD; c++) {
        const float bz = HAS_BIAS ? bias[co0 + c] : 0.0f;
#pragma unroll
        for (int q = 0; q < 4; q++) acc[c][q] = bz;
    }

    float pf[KC];
    auto stage_load = [&](int ch) {
#pragma unroll
        for (int t = 0; t < KC; t++) {
            int ci, kh, kw;
            if constexpr (K == 1) {
                ci = ch * 8 + t; kh = 0; kw = 0;
            } else if constexpr (K == 3) {
                ci = ch; kh = t / 3; kw = t % 3;
            } else {                                 // K == 4, TS = 2
                ci = ch >> 1;
                const int kk = ((ch & 1) << 3) + t;
                kh = kk >> 2; kw = kk & 3;
            }
            const int ih = ih0 + kh, iw = iw0 + kw;
            float v = 0.0f;
            if (ih >= 0 && ih < H && iw >= 0 && iw < W)
                v = inb[(size_t)ci * H * W + ih * W + iw];
            if (RELU_IN) v = fmaxf(v, 0.0f);
            pf[t] = v;
        }
    };

    stage_load(0);
#pragma unroll
    for (int t = 0; t < KC; t++) As[0][t * NT + tid] = pf[t];
    __syncthreads();

#pragma unroll 2
    for (int c = 0; c < NCH; c++) {
        const int cur = c & 1;
        if (c + 1 < NCH) stage_load(c + 1);

#pragma unroll
        for (int t = 0; t < KC; t++) {
            const float4 a4 = *(const float4*)(As[cur] + t * NT + tpx * 4);
            const float* __restrict__ wk =
                wr + (size_t)(c * KC + t) * CTOT + co0;
#pragma unroll
            for (int cc = 0; cc < CPTHD; cc++) {
                const float w = wk[cc];
                acc[cc][0] = fmaf(a4.x, w, acc[cc][0]);
                acc[cc][1] = fmaf(a4.y, w, acc[cc][1]);
                acc[cc][2] = fmaf(a4.z, w, acc[cc][2]);
                acc[cc][3] = fmaf(a4.w, w, acc[cc][3]);
            }
        }

        if (c + 1 < NCH) {
#pragma unroll
            for (int t = 0; t < KC; t++) As[1 - cur][t * NT + tid] = pf[t];
        }
        __syncthreads();
    }

    const int n_c  = blockIdx.x * NT + tpx * 4;
    const int b_c  = n_c / ohow;
    const int hw_c = n_c % ohow;
    float* __restrict__ op = out + (size_t)b_c * CTOT * ohow + hw_c;
    const float* __restrict__ rp =
        RESID ? (resid + (size_t)b_c * CTOT * ohow + hw_c) : nullptr;
#pragma unroll
    for (int c = 0; c < CPTHD; c++) {
        const size_t off = (size_t)(co0 + c) * ohow;
        float4 r = make_float4(acc[c][0], acc[c][1], acc[c][2], acc[c][3]);
        if (RESID) {
            const float4 rv = *(const float4*)(rp + off);
            r.x += rv.x; r.y += rv.y; r.z += rv.z; r.w += rv.w;
        }
        if (RELU_OUT) {
            r.x = fmaxf(r.x, 0.f); r.y = fmaxf(r.y, 0.f);
            r.z = fmaxf(r.z, 0.f); r.w = fmaxf(r.w, 0.f);
        }
        *(float4*)(op + off) = r;
    }
}

// Fused residual block, R17: out = in + W2.relu(W1 *3x3* relu(in)).
// 256 px/block, 512 threads (8 waves). grid 512 -> 2 blocks/CU x 8 waves
// = 16 waves/CU. Staging: 36 wave-uniform groups g = tap*4 + row, 64
// lanes each; wave w stages groups w, w+8, w+16, w+24 (+w+32 if w<4).
// ih wave-uniform -> SALU bounds check. Per-output FMA chains identical
// to R15/R16 (conv1: cin asc, tap asc; conv2: k asc; same relu/zeros;
// same residual order).
__global__ __launch_bounds__(512) void res_fused3(
    const float* __restrict__ in, const float* __restrict__ wr1,
    const float* __restrict__ wr2, float* __restrict__ out)
{
    // union: As[2][9*256] = 4608 floats (18 KB) | mid[32][256] = 8192 floats
    __shared__ __align__(16) float S[8192];           // 32 KB

    const int tid = threadIdx.x;
    const int lane = tid & 63;
    const int w = __builtin_amdgcn_readfirstlane(tid >> 6);     // 0..7
    const int cog = __builtin_amdgcn_readfirstlane(tid >> 7);   // 0..3
    const int pp = tid & 127;                                   // px pair

    const int n0 = blockIdx.x * 256;
    const int b = n0 >> 12;
    const int row0 = (n0 & 4095) >> 6;                // 4 rows of 64
    const float* __restrict__ inb = in + (size_t)b * 64 * 4096;

    const int co1 = cog * 8;
    float acc1[8][2];
#pragma unroll
    for (int c = 0; c < 8; c++) { acc1[c][0] = 0.0f; acc1[c][1] = 0.0f; }

    float pf[5];
    auto stage_load = [&](int ci) {
#pragma unroll
        for (int r = 0; r < 5; r++) {
            const int g = w + 8 * r;
            if (g < 36) {
                const int t  = g >> 2;                // tap 0..8
                const int rr = g & 3;                 // row 0..3
                const int ih = row0 + rr + t / 3 - 1; // wave-uniform
                const int iw = lane + t % 3 - 1;
                float v = 0.0f;
                if (ih >= 0 && ih < 64 && iw >= 0 && iw < 64)
                    v = inb[(size_t)ci * 4096 + ih * 64 + iw];
                pf[r] = fmaxf(v, 0.0f);
            }
        }
    };
    auto stage_write = [&](int buf) {
#pragma unroll
        for (int r = 0; r < 5; r++) {
            const int g = w + 8 * r;
            if (g < 36) S[buf * 2304 + g * 64 + lane] = pf[r];
        }
    };

    stage_load(0);
    stage_write(0);
    __syncthreads();

#pragma unroll 2
    for (int c = 0; c < 64; c++) {
        const int cur = c & 1;
        if (c + 1 < 64) stage_load(c + 1);

#pragma unroll
        for (int t = 0; t < 9; t++) {
            const float2 a2 =
                *(const float2*)(S + cur * 2304 + t * 256 + pp * 2);
            const float* __restrict__ wk = wr1 + (size_t)(c * 9 + t) * 32 + co1;
#pragma unroll
            for (int cc = 0; cc < 8; cc++) {
                const float wv = wk[cc];
                acc1[cc][0] = fmaf(a2.x, wv, acc1[cc][0]);
                acc1[cc][1] = fmaf(a2.y, wv, acc1[cc][1]);
            }
        }

        if (c + 1 < 64) stage_write(1 - cur);
        __syncthreads();
    }

    // mid[co][px] overlays S (safe: final barrier above drained all As reads)
#pragma unroll
    for (int cc = 0; cc < 8; cc++)
        *(float2*)(S + (co1 + cc) * 256 + pp * 2) =
            make_float2(acc1[cc][0], acc1[cc][1]);
    __syncthreads();

    const int co2 = cog * 16;
    float acc2[16][2];
#pragma unroll
    for (int c = 0; c < 16; c++) { acc2[c][0] = 0.0f; acc2[c][1] = 0.0f; }

#pragma unroll 4
    for (int k = 0; k < 32; k++) {
        float2 m2 = *(const float2*)(S + k * 256 + pp * 2);
        m2.x = fmaxf(m2.x, 0.f);
        m2.y = fmaxf(m2.y, 0.f);
        const float* __restrict__ wk = wr2 + (size_t)k * 64 + co2;
#pragma unroll
        for (int cc = 0; cc < 16; cc++) {
            const float wv = wk[cc];
            acc2[cc][0] = fmaf(m2.x, wv, acc2[cc][0]);
            acc2[cc][1] = fmaf(m2.y, wv, acc2[cc][1]);
        }
    }

    const int hw = (n0 & 4095) + pp * 2;
    const float* __restrict__ rp = in + (size_t)b * 64 * 4096 + hw;
    float* __restrict__ op = out + (size_t)b * 64 * 4096 + hw;
#pragma unroll
    for (int cc = 0; cc < 16; cc++) {
        const size_t off = (size_t)(co2 + cc) * 4096;
        const float2 rv = *(const float2*)(rp + off);
        *(float2*)(op + off) =
            make_float2(acc2[cc][0] + rv.x, acc2[cc][1] + rv.y);
    }
}

// t1 pc-merged GEMM, R15: cout-split (grid.y = 2pr x 2 cout-groups) +
// double-buffered staging (1 barrier/chunk). Wave owns 4 couts.
// FMA order per output: ci asc, ta asc, tb asc — identical to R12/R14.
__global__ __launch_bounds__(256) void convt_gemm2(
    const float* __restrict__ in, const float* __restrict__ wr,
    const float* __restrict__ bias, float* __restrict__ out)
{
    constexpr int NT = 256;
    __shared__ __align__(16) float As[2][12 * NT];   // 24 KB

    const int tid = threadIdx.x;
    const int tpx = tid & 63;
    const int tco = __builtin_amdgcn_readfirstlane(tid >> 6);
    const int pr = blockIdx.y & 1;
    const int cg = blockIdx.y >> 1;
    const int co0 = cg * 16 + tco * 4;

    const int n_st = blockIdx.x * NT + tid;
    const int b = n_st >> 12;
    const int i_st = (n_st & 4095) >> 6;
    const int j_st = n_st & 63;
    const float* __restrict__ inb = in + (size_t)b * 64 * 4096;

    float acc[4][4][2];
#pragma unroll
    for (int c = 0; c < 4; c++) {
        const float bz = bias[co0 + c];
#pragma unroll
        for (int p = 0; p < 4; p++) {
            acc[c][p][0] = bz;
            acc[c][p][1] = bz;
        }
    }

    const float* __restrict__ wpr = wr + (size_t)pr * 128 * 4 * 32;

    float pf[12];
    auto stage_load = [&](int ch) {
#pragma unroll
        for (int t = 0; t < 4; t++) {
            const int k2 = ch * 4 + t;
            const int ci = k2 >> 1;
            const int ta = k2 & 1;
            const int ih = i_st + pr - ta;
            const bool rok = (ih >= 0) && (ih < 64);
            const float* __restrict__ row = inb + (size_t)ci * 4096 + ih * 64;
#pragma unroll
            for (int m = 0; m < 3; m++) {
                const int iw = j_st + m - 1;
                float v = 0.0f;
                if (rok && iw >= 0 && iw < 64) v = row[iw];
                pf[t * 3 + m] = v;
            }
        }
    };

    stage_load(0);
#pragma unroll
    for (int t = 0; t < 12; t++) As[0][t * NT + tid] = pf[t];
    __syncthreads();

#pragma unroll 2
    for (int ch = 0; ch < 32; ch++) {
        const int cur = ch & 1;
        if (ch + 1 < 32) stage_load(ch + 1);

#pragma unroll
        for (int t = 0; t < 4; t++) {
            float4 a[3];
#pragma unroll
            for (int m = 0; m < 3; m++)
                a[m] = *(const float4*)(As[cur] + (t * 3 + m) * NT + tpx * 4);
            const float* __restrict__ wk =
                wpr + (size_t)(ch * 4 + t) * 4 * 32 + co0;
#pragma unroll
            for (int tb = 0; tb < 2; tb++) {
#pragma unroll
                for (int pc = 0; pc < 2; pc++) {
                    const int q = pc * 2 + tb;
                    const int m = pc - tb + 1;
                    const float* __restrict__ wt = wk + q * 32;
                    const float vx = a[m].x, vy = a[m].y,
                                vz = a[m].z, vw = a[m].w;
#pragma unroll
                    for (int c = 0; c < 4; c++) {
                        const float w = wt[c];
                        acc[c][0][pc] = fmaf(vx, w, acc[c][0][pc]);
                        acc[c][1][pc] = fmaf(vy, w, acc[c][1][pc]);
                        acc[c][2][pc] = fmaf(vz, w, acc[c][2][pc]);
                        acc[c][3][pc] = fmaf(vw, w, acc[c][3][pc]);
                    }
                }
            }
        }

        if (ch + 1 < 32) {
#pragma unroll
            for (int t = 0; t < 12; t++) As[1 - cur][t * NT + tid] = pf[t];
        }
        __syncthreads();
    }

    const int n_c = blockIdx.x * NT + tpx * 4;
    const int i_c = (n_c & 4095) >> 6;
    const int j_c = n_c & 63;
    const int oh = 2 * i_c + pr;
    float* __restrict__ ob =
        out + (size_t)b * 32 * 16384 + (size_t)oh * 128 + 2 * j_c;
#pragma unroll
    for (int c = 0; c < 4; c++) {
        float* __restrict__ o = ob + (size_t)(co0 + c) * 16384;
        const float4 v0 = make_float4(
            fmaxf(acc[c][0][0], 0.f), fmaxf(acc[c][0][1], 0.f),
            fmaxf(acc[c][1][0], 0.f), fmaxf(acc[c][1][1], 0.f));
        const float4 v1 = make_float4(
            fmaxf(acc[c][2][0], 0.f), fmaxf(acc[c][2][1], 0.f),
            fmaxf(acc[c][3][0], 0.f), fmaxf(acc[c][3][1], 0.f));
        *(float4*)o = v0;
        *(float4*)(o + 4) = v1;
    }
}

// Final transposed conv (32 -> 1). (validated)
__global__ __launch_bounds__(256) void convt2_quad(
    const float* __restrict__ in, const float* __restrict__ w,
    const float* __restrict__ bias, float* __restrict__ out, int B)
{
    const int IH = 128, IW = 128, CIN = 32, OW = 256;
    const int j = threadIdx.x & 127;
    const int i = (blockIdx.x << 1) + (threadIdx.x >> 7);
    const int b = blockIdx.y;

    const float* __restrict__ inb = in + (size_t)b * CIN * IH * IW;
    const float bz = bias[0];
    float a00 = bz, a01 = bz, a10 = bz, a11 = bz;

    const bool okm = (i > 0);
    const bool okp = (i < IH - 1);
    const bool olm = (j > 0);
    const bool olp = (j < IW - 1);

#pragma unroll 4
    for (int ci = 0; ci < CIN; ci++) {
        const float* __restrict__ p = inb + ((size_t)ci * IH + i) * IW + j;
        const float* __restrict__ wp = w + ci * 16;
        const float vmm = (okm && olm) ? p[-IW - 1] : 0.f;
        const float vm0 = okm ? p[-IW] : 0.f;
        const float vmp = (okm && olp) ? p[-IW + 1] : 0.f;
        const float v0m = olm ? p[-1] : 0.f;
        const float v00 = p[0];
        const float v0p = olp ? p[1] : 0.f;
        const float vpm = (okp && olm) ? p[IW - 1] : 0.f;
        const float vp0 = okp ? p[IW] : 0.f;
        const float vpp = (okp && olp) ? p[IW + 1] : 0.f;
        a00 = fmaf(v00, wp[1 * 4 + 1], a00);
        a00 = fmaf(v0m, wp[1 * 4 + 3], a00);
        a00 = fmaf(vm0, wp[3 * 4 + 1], a00);
        a00 = fmaf(vmm, wp[3 * 4 + 3], a00);
        a01 = fmaf(v0p, wp[1 * 4 + 0], a01);
        a01 = fmaf(v00, wp[1 * 4 + 2], a01);
        a01 = fmaf(vmp, wp[3 * 4 + 0], a01);
        a01 = fmaf(vm0, wp[3 * 4 + 2], a01);
        a10 = fmaf(vp0, wp[0 * 4 + 1], a10);
        a10 = fmaf(vpm, wp[0 * 4 + 3], a10);
        a10 = fmaf(v00, wp[2 * 4 + 1], a10);
        a10 = fmaf(v0m, wp[2 * 4 + 3], a10);
        a11 = fmaf(vpp, wp[0 * 4 + 0], a11);
        a11 = fmaf(vp0, wp[0 * 4 + 2], a11);
        a11 = fmaf(v0p, wp[2 * 4 + 0], a11);
        a11 = fmaf(v00, wp[2 * 4 + 2], a11);
    }

    float* __restrict__ outb = out + (size_t)b * 256 * 256;
    ((float2*)(outb + (size_t)(2 * i) * OW))[j] = make_float2(a00, a01);
    ((float2*)(outb + (size_t)(2 * i + 1) * OW))[j] = make_float2(a10, a11);
}

// VQ-GEMM (validated R9). DO NOT reorder any fmaf chain (R3).
__global__ __launch_bounds__(256) void vq_gemm(
    const float* __restrict__ h,    // (32,64,4096)
    const float* __restrict__ cb,   // (512,64) row-major (gather)
    const float* __restrict__ cbT,  // (64,512) dim-major (matmul)
    const float* __restrict__ ee,   // (512)
    float* __restrict__ q)          // (32,64,4096)
{
    __shared__ __align__(16) float As[64 * 128];
    __shared__ float xx_sh[128];
    __shared__ float pd[4 * 128];
    __shared__ int   pk[4 * 128];
    __shared__ int   bidx_sh[128];

    const int tid = threadIdx.x;
    const int tpx = tid & 63;
    const int w = __builtin_amdgcn_readfirstlane(tid >> 6);
    const int n0 = blockIdx.x * 128;
    const int b  = n0 >> 12;
    const int hw0 = n0 & 4095;

    const float* __restrict__ hb = h + (size_t)b * 64 * 4096 + hw0;
#pragma unroll
    for (int m = 0; m < 32; m++) {
        const int idx = m * 256 + tid;
        const int k = idx >> 7, p = idx & 127;
        As[idx] = hb[(size_t)k * 4096 + p];
    }
    __syncthreads();

    if (tid < 128) {
        float s = 0.0f;
#pragma unroll
        for (int i = 0; i < 64; i++) {
            const float v = As[i * 128 + tid];
            s = fmaf(v, v, s);
        }
        xx_sh[tid] = s;
    }
    __syncthreads();

    const float xx0 = xx_sh[tpx * 2];
    const float xx1 = xx_sh[tpx * 2 + 1];
    const int cwave = w * 128;

    float best0 = 3.402823466e+38f, best1 = 3.402823466e+38f;
    int bk0 = 0, bk1 = 0;

#pragma unroll 1
    for (int ch = 0; ch < 16; ch++) {
        const int cbase = cwave + ch * 8;
        float acc[8][2];
#pragma unroll
        for (int c = 0; c < 8; c++) { acc[c][0] = 0.0f; acc[c][1] = 0.0f; }

#pragma unroll 8
        for (int k = 0; k < 64; k++) {
            const float2 a2 = *(const float2*)(As + k * 128 + tpx * 2);
            const float* __restrict__ wk = cbT + (size_t)k * 512 + cbase;
#pragma unroll
            for (int c = 0; c < 8; c++) {
                const float wv = wk[c];
                acc[c][0] = fmaf(a2.x, wv, acc[c][0]);
                acc[c][1] = fmaf(a2.y, wv, acc[c][1]);
            }
        }
        const float* __restrict__ eep = ee + cbase;
#pragma unroll
        for (int c = 0; c < 8; c++) {
            const float eec = eep[c];
            const float d0 = xx0 - 2.0f * acc[c][0] + eec;
            const float d1 = xx1 - 2.0f * acc[c][1] + eec;
            if (d0 < best0) { best0 = d0; bk0 = cbase + c; }
            if (d1 < best1) { best1 = d1; bk1 = cbase + c; }
        }
    }

    pd[w * 128 + tpx * 2]     = best0;
    pd[w * 128 + tpx * 2 + 1] = best1;
    pk[w * 128 + tpx * 2]     = bk0;
    pk[w * 128 + tpx * 2 + 1] = bk1;
    __syncthreads();

    if (tid < 128) {
        float bd = pd[tid]; int bk = pk[tid];
#pragma unroll
        for (int ww = 1; ww < 4; ww++) {
            const float od = pd[ww * 128 + tid];
            if (od < bd) { bd = od; bk = pk[ww * 128 + tid]; }
        }
        bidx_sh[tid] = bk;
    }
    __syncthreads();

    {
        const int p  = tid & 127;
        const int d0 = (tid >> 7) * 32;
        const int bk = bidx_sh[p];
        const float4* __restrict__ cp4 = (const float4*)(cb + (size_t)bk * 64 + d0);
        float* __restrict__ qb = q + ((size_t)b * 64 + d0) * 4096 + hw0 + p;
#pragma unroll
        for (int i = 0; i < 8; i++) {
            const float4 v = cp4[i];
            qb[(size_t)(4 * i + 0) * 4096] = v.x;
            qb[(size_t)(4 * i + 1) * 4096] = v.y;
            qb[(size_t)(4 * i + 2) * 4096] = v.z;
            qb[(size_t)(4 * i + 3) * 4096] = v.w;
        }
    }
}

extern "C" void kernel_launch(void* const* d_in, const int* in_sizes, int n_in,
                              void* d_out, int out_size, void* d_ws, size_t ws_size,
                              hipStream_t stream) {
    const float* x      = (const float*)d_in[0];
    const float* w_e1   = (const float*)d_in[1];
    const float* b_e1   = (const float*)d_in[2];
    const float* w_e2   = (const float*)d_in[3];
    const float* b_e2   = (const float*)d_in[4];
    const float* w_er1a = (const float*)d_in[5];
    const float* w_er1b = (const float*)d_in[6];
    const float* w_er2a = (const float*)d_in[7];
    const float* w_er2b = (const float*)d_in[8];
    const float* w_pre  = (const float*)d_in[9];
    const float* b_pre  = (const float*)d_in[10];
    const float* cbk    = (const float*)d_in[11];
    const float* w_d1   = (const float*)d_in[12];
    const float* b_d1   = (const float*)d_in[13];
    const float* w_dr1a = (const float*)d_in[14];
    const float* w_dr1b = (const float*)d_in[15];
    const float* w_dr2a = (const float*)d_in[16];
    const float* w_dr2b = (const float*)d_in[17];
    const float* w_t1   = (const float*)d_in[18];
    const float* b_t1   = (const float*)d_in[19];
    const float* w_t2   = (const float*)d_in[20];
    const float* b_t2   = (const float*)d_in[21];
    float* out = (float*)d_out;

    float* A  = (float*)d_ws;            // 16777216 floats (scratch + t1 out)
    float* Bb = A  + 16777216;           // (32,64,64,64) = 8388608
    float* C  = Bb + 8388608;            // 4194304 (unused after fusion)
    float* D  = C  + 4194304;            // (32,64,64,64) = 8388608
    float* WR = D  + 8388608;            // repacked weights + cbT (221696)
    float* EE = WR + 221696;             // ee (512)

    float* r_e1  = WR;
    float* r_e2  = WR + 512;
    float* r_er1a = WR + 33280;
    float* r_er1b = WR + 51712;
    float* r_er2a = WR + 53760;
    float* r_er2b = WR + 72192;
    float* r_pre = WR + 74240;
    float* r_d1  = WR + 78336;
    float* r_dr1a = WR + 115200;
    float* r_dr1b = WR + 133632;
    float* r_dr2a = WR + 135680;
    float* r_dr2b = WR + 154112;
    float* r_t1  = WR + 156160;
    float* r_cbT = WR + 188928;

    const dim3 blk(256);
    const dim3 blk512(512);

    repack_all<<<dim3(866), blk, 0, stream>>>(
        w_e1, w_e2, w_er1a, w_er1b, w_er2a, w_er2b, w_pre, w_d1,
        w_dr1a, w_dr1b, w_dr2a, w_dr2b, w_t1, cbk, WR);
    vq_prep_ee<<<dim3(2), blk, 0, stream>>>(cbk, EE);

    // Encoder
    conv_gemm<32, 32, 1, 4, 2, 1, false, true, false, true>
        <<<dim3(2048, 1), blk, 0, stream>>>(x, r_e1, b_e1, nullptr, A,
                                            256, 256, 128, 128);
    conv_gemm<64, 16, 32, 4, 2, 1, false, true, false, false>
        <<<dim3(512, 4), blk, 0, stream>>>(A, r_e2, b_e2, nullptr, Bb,
                                           128, 128, 64, 64);
    // er1: Bb -> A ; er2: A -> Bb (ping-pong avoids in-place halo race)
    res_fused3<<<dim3(512), blk512, 0, stream>>>(Bb, r_er1a, r_er1b, A);
    res_fused3<<<dim3(512), blk512, 0, stream>>>(A, r_er2a, r_er2b, Bb);
    conv_gemm<64, 16, 64, 1, 1, 0, false, true, false, false>
        <<<dim3(512, 4), blk, 0, stream>>>(Bb, r_pre, b_pre, nullptr, D,
                                           64, 64, 64, 64);
    // VQ
    vq_gemm<<<dim3(1024), blk, 0, stream>>>(D, cbk, r_cbT, EE, Bb);
    // Decoder
    conv_gemm<64, 16, 64, 3, 1, 1, false, true, false, false>
        <<<dim3(512, 4), blk, 0, stream>>>(Bb, r_d1, b_d1, nullptr, D,
                                           64, 64, 64, 64);
    // dr1: D -> A ; dr2: A -> D
    res_fused3<<<dim3(512), blk512, 0, stream>>>(D, r_dr1a, r_dr1b, A);
    res_fused3<<<dim3(512), blk512, 0, stream>>>(A, r_dr2a, r_dr2b, D);
    // t1 (pc-merged, cout-split): grid (512, 2pr x 2cg)
    convt_gemm2<<<dim3(512, 4), blk, 0, stream>>>(D, r_t1, b_t1, A);
    // t2
    convt2_quad<<<dim3(64, 32), blk, 0, stream>>>(A, w_t2, b_t2, out, 32);
}

// Round 3
// 1061.128 us; speedup vs baseline: 1.3153x; 1.3153x over previous
//
#include <hip/hip_runtime.h>
#include <hip/hip_bf16.h>

// ---------------------------------------------------------------------------
// VQ-VAE forward, fp32. NCHW.
// R18: res_tile replaces the res_fused family. R15/R16/R17 post-mortem: all
// three occupancy configs pinned at VALUBusy ~45-47%, dur 160-194us -> the
// per-chunk {global-load, vmcnt-drain, barrier} x64 structure is the cost,
// not occupancy. res_tile stages the whole input tile ONCE (two 27KB halves
// in one 54KB LDS buffer -> 2 blocks/CU), half-1 prefetched into registers
// (T14 issue-early/write-late) during half-0 compute. Main loop = pure LDS
// reads + FMA, 5 barriers/block total (vs 66). Unaligned 3x3 columns via
// aligned float4 + two edge-float reads (register select, no shuffles).
// Per-output FMA chains bit-identical to R15 (conv1: ci asc, tap asc;
// conv2: k asc; same staged relu/zeros; same residual order) => VQ argmin
// unchanged (R3 lesson). All other kernels byte-identical to R17.
// ---------------------------------------------------------------------------

__device__ __forceinline__ float rp_elem(const float* __restrict__ src,
                                         int i, int COUT, int CIN, int KK)
{
    const int co = i % COUT;
    const int t  = i / COUT;
    const int kk = t % KK;
    const int ci = t / KK;
    return src[(co * CIN + ci) * KK + kk];
}

// One kernel repacks all weights + codebook-transpose into WR.
__global__ __launch_bounds__(256) void repack_all(
    const float* __restrict__ e1,  const float* __restrict__ e2,
    const float* __restrict__ er1a, const float* __restrict__ er1b,
    const float* __restrict__ er2a, const float* __restrict__ er2b,
    const float* __restrict__ pre, const float* __restrict__ d1,
    const float* __restrict__ dr1a, const float* __restrict__ dr1b,
    const float* __restrict__ dr2a, const float* __restrict__ dr2b,
    const float* __restrict__ t1, const float* __restrict__ cb,
    float* __restrict__ WR)
{
    const int idx = blockIdx.x * 256 + threadIdx.x;
    if (idx >= 221696) return;
    float v;
    if      (idx < 512)    v = rp_elem(e1,   idx,          32,  1, 16);
    else if (idx < 33280)  v = rp_elem(e2,   idx - 512,    64, 32, 16);
    else if (idx < 51712)  v = rp_elem(er1a, idx - 33280,  32, 64,  9);
    else if (idx < 53760)  v = rp_elem(er1b, idx - 51712,  64, 32,  1);
    else if (idx < 72192)  v = rp_elem(er2a, idx - 53760,  32, 64,  9);
    else if (idx < 74240)  v = rp_elem(er2b, idx - 72192,  64, 32,  1);
    else if (idx < 78336)  v = rp_elem(pre,  idx - 74240,  64, 64,  1);
    else if (idx < 115200) v = rp_elem(d1,   idx - 78336,  64, 64,  9);
    else if (idx < 133632) v = rp_elem(dr1a, idx - 115200, 32, 64,  9);
    else if (idx < 135680) v = rp_elem(dr1b, idx - 133632, 64, 32,  1);
    else if (idx < 154112) v = rp_elem(dr2a, idx - 135680, 32, 64,  9);
    else if (idx < 156160) v = rp_elem(dr2b, idx - 154112, 64, 32,  1);
    else if (idx < 188928) {
        // t1: [pr][k2=ci*2+ta][q=pc*2+tb][co]
        const int i  = idx - 156160;
        const int co = i & 31;
        const int q  = (i >> 5) & 3;
        const int k2 = (i >> 7) & 127;
        const int pr = i >> 14;
        const int pc = q >> 1, tb = q & 1;
        const int ci = k2 >> 1, ta = k2 & 1;
        const int kh = (1 - pr) + 2 * ta, kw = (1 - pc) + 2 * tb;
        v = t1[((ci * 32 + co) * 4 + kh) * 4 + kw];
    } else {
        const int i = idx - 188928;           // cbT: [dim][code]
        const int code = i & 511;
        const int dim  = i >> 9;
        v = cb[code * 64 + dim];
    }
    WR[idx] = v;
}

// ee[k] = sum_i cb[k][i]^2, exact ascending fmaf chain (matches reference).
__global__ __launch_bounds__(256) void vq_prep_ee(
    const float* __restrict__ cb, float* __restrict__ ee)
{
    const int k = blockIdx.x * 256 + threadIdx.x;  // grid(2) -> k < 512
    const float* __restrict__ cp = cb + (size_t)k * 64;
    float s = 0.0f;
#pragma unroll
    for (int i = 0; i < 64; i++) s = fmaf(cp[i], cp[i], s);
    ee[k] = s;
}

// GEMM-form conv (validated R13). Block: CPB couts x 256 pixels; thread:
// CPTHD x 4 pixels. K-chunks double-buffered in LDS; K=4 tap-split.
template<int CTOT, int CPB, int CIN, int K, int S, int PAD,
         bool RELU_IN, bool HAS_BIAS, bool RESID, bool RELU_OUT>
__global__ __launch_bounds__(256) void conv_gemm(
    const float* __restrict__ in, const float* __restrict__ wr,
    const float* __restrict__ bias, const float* __restrict__ resid,
    float* __restrict__ out,
    int H, int W, int OH, int OW)
{
    constexpr int KK  = K * K;
    constexpr int CIC = (K == 1) ? 8 : 1;
    constexpr int TS  = (K == 4) ? 2 : 1;
    constexpr int KC  = CIC * KK / TS;
    constexpr int NCH = (CIN * TS) / CIC;
    constexpr int NT  = 256;
    constexpr int CPTHD = CPB / 4;
    __shared__ __align__(16) float As[2][KC * NT];

    const int tid = threadIdx.x;
    const int tpx = tid & 63;
    const int tco = __builtin_amdgcn_readfirstlane(tid >> 6);
    const int co0 = blockIdx.y * CPB + tco * CPTHD;

    const int ohow = OH * OW;
    const int n_st = blockIdx.x * NT + tid;
    const int b_st = n_st / ohow;
    const int hw_s = n_st % ohow;
    const int ih0 = (hw_s / OW) * S - PAD;
    const int iw0 = (hw_s % OW) * S - PAD;
    const float* __restrict__ inb = in + (size_t)b_st * CIN * H * W;

    float acc[CPTHD][4];
#pragma unroll
    for (int c = 0; c < CPTHD; c++) {
        const float bz = HAS_BIAS ? bias[co0 + c] : 0.0f;
#pragma unroll
        for (int q = 0; q < 4; q++) acc[c][q] = bz;
    }

    float pf[KC];
    auto stage_load = [&](int ch) {
#pragma unroll
        for (int t = 0; t < KC; t++) {
            int ci, kh, kw;
            if constexpr (K == 1) {
                ci = ch * 8 + t; kh = 0; kw = 0;
            } else if constexpr (K == 3) {
                ci = ch; kh = t / 3; kw = t % 3;
            } else {                                 // K == 4, TS = 2
                ci = ch >> 1;
                const int kk = ((ch & 1) << 3) + t;
                kh = kk >> 2; kw = kk & 3;
            }
            const int ih = ih0 + kh, iw = iw0 + kw;
            float v = 0.0f;
            if (ih >= 0 && ih < H && iw >= 0 && iw < W)
                v = inb[(size_t)ci * H * W + ih * W + iw];
            if (RELU_IN) v = fmaxf(v, 0.0f);
            pf[t] = v;
        }
    };

    stage_load(0);
#pragma unroll
    for (int t = 0; t < KC; t++) As[0][t * NT + tid] = pf[t];
    __syncthreads();

#pragma unroll 2
    for (int c = 0; c < NCH; c++) {
        const int cur = c & 1;
        if (c + 1 < NCH) stage_load(c + 1);

#pragma unroll
        for (int t = 0; t < KC; t++) {
            const float4 a4 = *(const float4*)(As[cur] + t * NT + tpx * 4);
            const float* __restrict__ wk =
                wr + (size_t)(c * KC + t) * CTOT + co0;
#pragma unroll
            for (int cc = 0; cc < CPTHD; cc++) {
                const float w = wk[cc];
                acc[cc][0] = fmaf(a4.x, w, acc[cc][0]);
                acc[cc][1] = fmaf(a4.y, w, acc[cc][1]);
                acc[cc][2] = fmaf(a4.z, w, acc[cc][2]);
                acc[cc][3] = fmaf(a4.w, w, acc[cc][3]);
            }
        }

        if (c + 1 < NCH) {
#pragma unroll
            for (int t = 0; t < KC; t++) As[1 - cur][t * NT + tid] = pf[t];
        }
        __syncthreads();
    }

    const int n_c  = blockIdx.x * NT + tpx * 4;
    const int b_c  = n_c / ohow;
    const int hw_c = n_c % ohow;
    float* __restrict__ op = out + (size_t)b_c * CTOT * ohow + hw_c;
    const float* __restrict__ rp =
        RESID ? (resid + (size_t)b_c * CTOT * ohow + hw_c) : nullptr;
#pragma unroll
    for (int c = 0; c < CPTHD; c++) {
        const size_t off = (size_t)(co0 + c) * ohow;
        float4 r = make_float4(acc[c][0], acc[c][1], acc[c][2], acc[c][3]);
        if (RESID) {
            const float4 rv = *(const float4*)(rp + off);
            r.x += rv.x; r.y += rv.y; r.z += rv.z; r.w += rv.w;
        }
        if (RELU_OUT) {
            r.x = fmaxf(r.x, 0.f); r.y = fmaxf(r.y, 0.f);
            r.z = fmaxf(r.z, 0.f); r.w = fmaxf(r.w, 0.f);
        }
        *(float4*)(op + off) = r;
    }
}

// Fused residual block, R18 "stage-once": out = in + W2.relu(W1 *3x3* relu(in)).
// 512 threads, 256 px/block, grid 512. LDS = 32ch x 6rows x 72cols tile
// (54KB, relu'd + zero-padded), staged in two halves; half-1 prefetched to
// registers during half-0 compute. Main loop: pure LDS reads + FMA, no
// barriers. Thread owns 4 couts x 4 px (conv1), 8 couts x 4 px (conv2).
// Tap columns via aligned float4 + edge floats tp[-1]/tp[4] (reg select).
__global__ __launch_bounds__(512, 4) void res_tile(
    const float* __restrict__ in, const float* __restrict__ wr1,
    const float* __restrict__ wr2, float* __restrict__ out)
{
    // tile: [ci<32][r6<6][72] floats = 13824 (54KB); mid[32][256] overlays.
    __shared__ __align__(16) float S[13824];

    const int tid  = threadIdx.x;
    const int lane = tid & 63;
    const int cog  = __builtin_amdgcn_readfirstlane(tid >> 6);  // 0..7
    const int a    = lane >> 4;            // px row in block (0..3)
    const int bcol = (lane & 15) * 4;      // px col base (0..60)

    const int n0   = blockIdx.x * 256;
    const int b    = n0 >> 12;
    const int row0 = (n0 & 4095) >> 6;     // 4 rows of 64
    const float* __restrict__ inb = in + (size_t)b * 64 * 4096;

    // ---- staging: 3456 float4 per 32-ch half; 7 per thread (guarded).
    float4 pf4[7];
    auto stage_issue = [&](int half) {
#pragma unroll
        for (int m = 0; m < 7; m++) {
            const int f4 = m * 512 + tid;
            float4 v = make_float4(0.f, 0.f, 0.f, 0.f);
            if (f4 < 3456) {
                const int ci  = f4 / 108;            // 0..31
                const int rem = f4 - ci * 108;
                const int r6  = rem / 18;            // 0..5
                const int c4  = rem - r6 * 18;       // 0..17
                const int ih  = row0 + r6 - 1;
                if (ih >= 0 && ih < 64 && c4 >= 1 && c4 <= 16)
                    v = *(const float4*)(inb + (size_t)(half * 32 + ci) * 4096
                                         + ih * 64 + (c4 * 4 - 4));
            }
            pf4[m] = v;
        }
    };
    auto stage_commit = [&]() {
#pragma unroll
        for (int m = 0; m < 7; m++) {
            const int f4 = m * 512 + tid;
            if (f4 < 3456) {
                float4 v = pf4[m];
                v.x = fmaxf(v.x, 0.f); v.y = fmaxf(v.y, 0.f);
                v.z = fmaxf(v.z, 0.f); v.w = fmaxf(v.w, 0.f);
                *(float4*)(S + f4 * 4) = v;
            }
        }
    };

    const int co1 = cog * 4;
    float acc1[4][4];
#pragma unroll
    for (int c = 0; c < 4; c++)
#pragma unroll
        for (int q = 0; q < 4; q++) acc1[c][q] = 0.0f;

    // conv1 over one 32-channel half; chain per output: ci asc, tap asc.
    auto conv1_half = [&](int h) {
#pragma unroll 2
        for (int c = 0; c < 32; c++) {
            const float* __restrict__ wb =
                wr1 + (size_t)((h * 32 + c) * 9) * 32 + co1;
#pragma unroll
            for (int kh = 0; kh < 3; kh++) {
                const float* __restrict__ tp =
                    S + c * 432 + (a + kh) * 72 + 4 + bcol;
                const float4 x4 = *(const float4*)tp;
                const float  xm = tp[-1];
                const float  xp = tp[4];
                const float* __restrict__ wk = wb + (size_t)(kh * 3) * 32;
#pragma unroll
                for (int cc = 0; cc < 4; cc++) {     // kw = 0
                    const float w = wk[cc];
                    acc1[cc][0] = fmaf(xm,   w, acc1[cc][0]);
                    acc1[cc][1] = fmaf(x4.x, w, acc1[cc][1]);
                    acc1[cc][2] = fmaf(x4.y, w, acc1[cc][2]);
                    acc1[cc][3] = fmaf(x4.z, w, acc1[cc][3]);
                }
#pragma unroll
                for (int cc = 0; cc < 4; cc++) {     // kw = 1
                    const float w = wk[32 + cc];
                    acc1[cc][0] = fmaf(x4.x, w, acc1[cc][0]);
                    acc1[cc][1] = fmaf(x4.y, w, acc1[cc][1]);
                    acc1[cc][2] = fmaf(x4.z, w, acc1[cc][2]);
                    acc1[cc][3] = fmaf(x4.w, w, acc1[cc][3]);
                }
#pragma unroll
                for (int cc = 0; cc < 4; cc++) {     // kw = 2
                    const float w = wk[64 + cc];
                    acc1[cc][0] = fmaf(x4.y, w, acc1[cc][0]);
                    acc1[cc][1] = fmaf(x4.z, w, acc1[cc][1]);
                    acc1[cc][2] = fmaf(x4.w, w, acc1[cc][2]);
                    acc1[cc][3] = fmaf(xp,   w, acc1[cc][3]);
                }
            }
        }
    };

    stage_issue(0);
    stage_commit();
    __syncthreads();
    stage_issue(1);          // prefetch half 1; lands during half-0 compute
    conv1_half(0);
    __syncthreads();         // all half-0 reads done
    stage_commit();
    __syncthreads();         // half-1 tile visible
    conv1_half(1);
    __syncthreads();         // all half-1 reads done; S free for mid overlay

    // mid[co][px] (32x256 = 32KB) overlays tile region.
#pragma unroll
    for (int cc = 0; cc < 4; cc++)
        *(float4*)(S + (co1 + cc) * 256 + lane * 4) =
            make_float4(acc1[cc][0], acc1[cc][1], acc1[cc][2], acc1[cc][3]);
    __syncthreads();

    const int co2 = cog * 8;
    float acc2[8][4];
#pragma unroll
    for (int c = 0; c < 8; c++)
#pragma unroll
        for (int q = 0; q < 4; q++) acc2[c][q] = 0.0f;

#pragma unroll 4
    for (int k = 0; k < 32; k++) {
        float4 m4 = *(const float4*)(S + k * 256 + lane * 4);
        m4.x = fmaxf(m4.x, 0.f); m4.y = fmaxf(m4.y, 0.f);
        m4.z = fmaxf(m4.z, 0.f); m4.w = fmaxf(m4.w, 0.f);
        const float* __restrict__ wk = wr2 + (size_t)k * 64 + co2;
#pragma unroll
        for (int cc = 0; cc < 8; cc++) {
            const float w = wk[cc];
            acc2[cc][0] = fmaf(m4.x, w, acc2[cc][0]);
            acc2[cc][1] = fmaf(m4.y, w, acc2[cc][1]);
            acc2[cc][2] = fmaf(m4.z, w, acc2[cc][2]);
            acc2[cc][3] = fmaf(m4.w, w, acc2[cc][3]);
        }
    }

    const int hw = (n0 & 4095) + lane * 4;
    const float* __restrict__ rp = inb + hw;
    float* __restrict__ op = out + (size_t)b * 64 * 4096 + hw;
#pragma unroll
    for (int cc = 0; cc < 8; cc++) {
        const size_t off = (size_t)(co2 + cc) * 4096;
        const float4 rv = *(const float4*)(rp + off);
        *(float4*)(op + off) = make_float4(
            acc2[cc][0] + rv.x, acc2[cc][1] + rv.y,
            acc2[cc][2] + rv.z, acc2[cc][3] + rv.w);
    }
}

// t1 pc-merged GEMM, R15: cout-split (grid.y = 2pr x 2 cout-groups) +
// double-buffered staging (1 barrier/chunk). Wave owns 4 couts.
// FMA order per output: ci asc, ta asc, tb asc — identical to R12/R14.
__global__ __launch_bounds__(256) void convt_gemm2(
    const float* __restrict__ in, const float* __restrict__ wr,
    const float* __restrict__ bias, float* __restrict__ out)
{
    constexpr int NT = 256;
    __shared__ __align__(16) float As[2][12 * NT];   // 24 KB

    const int tid = threadIdx.x;
    const int tpx = tid & 63;
    const int tco = __builtin_amdgcn_readfirstlane(tid >> 6);
    const int pr = blockIdx.y & 1;
    const int cg = blockIdx.y >> 1;
    const int co0 = cg * 16 + tco * 4;

    const int n_st = blockIdx.x * NT + tid;
    const int b = n_st >> 12;
    const int i_st = (n_st & 4095) >> 6;
    const int j_st = n_st & 63;
    const float* __restrict__ inb = in + (size_t)b * 64 * 4096;

    float acc[4][4][2];
#pragma unroll
    for (int c = 0; c < 4; c++) {
        const float bz = bias[co0 + c];
#pragma unroll
        for (int p = 0; p < 4; p++) {
            acc[c][p][0] = bz;
            acc[c][p][1] = bz;
        }
    }

    const float* __restrict__ wpr = wr + (size_t)pr * 128 * 4 * 32;

    float pf[12];
    auto stage_load = [&](int ch) {
#pragma unroll
        for (int t = 0; t < 4; t++) {
            const int k2 = ch * 4 + t;
            const int ci = k2 >> 1;
            const int ta = k2 & 1;
            const int ih = i_st + pr - ta;
            const bool rok = (ih >= 0) && (ih < 64);
            const float* __restrict__ row = inb + (size_t)ci * 4096 + ih * 64;
#pragma unroll
            for (int m = 0; m < 3; m++) {
                const int iw = j_st + m - 1;
                float v = 0.0f;
                if (rok && iw >= 0 && iw < 64) v = row[iw];
                pf[t * 3 + m] = v;
            }
        }
    };

    stage_load(0);
#pragma unroll
    for (int t = 0; t < 12; t++) As[0][t * NT + tid] = pf[t];
    __syncthreads();

#pragma unroll 2
    for (int ch = 0; ch < 32; ch++) {
        const int cur = ch & 1;
        if (ch + 1 < 32) stage_load(ch + 1);

#pragma unroll
        for (int t = 0; t < 4; t++) {
            float4 a[3];
#pragma unroll
            for (int m = 0; m < 3; m++)
                a[m] = *(const float4*)(As[cur] + (t * 3 + m) * NT + tpx * 4);
            const float* __restrict__ wk =
                wpr + (size_t)(ch * 4 + t) * 4 * 32 + co0;
#pragma unroll
            for (int tb = 0; tb < 2; tb++) {
#pragma unroll
                for (int pc = 0; pc < 2; pc++) {
                    const int q = pc * 2 + tb;
                    const int m = pc - tb + 1;
                    const float* __restrict__ wt = wk + q * 32;
                    const float vx = a[m].x, vy = a[m].y,
                                vz = a[m].z, vw = a[m].w;
#pragma unroll
                    for (int c = 0; c < 4; c++) {
                        const float w = wt[c];
                        acc[c][0][pc] = fmaf(vx, w, acc[c][0][pc]);
                        acc[c][1][pc] = fmaf(vy, w, acc[c][1][pc]);
                        acc[c][2][pc] = fmaf(vz, w, acc[c][2][pc]);
                        acc[c][3][pc] = fmaf(vw, w, acc[c][3][pc]);
                    }
                }
            }
        }

        if (ch + 1 < 32) {
#pragma unroll
            for (int t = 0; t < 12; t++) As[1 - cur][t * NT + tid] = pf[t];
        }
        __syncthreads();
    }

    const int n_c = blockIdx.x * NT + tpx * 4;
    const int i_c = (n_c & 4095) >> 6;
    const int j_c = n_c & 63;
    const int oh = 2 * i_c + pr;
    float* __restrict__ ob =
        out + (size_t)b * 32 * 16384 + (size_t)oh * 128 + 2 * j_c;
#pragma unroll
    for (int c = 0; c < 4; c++) {
        float* __restrict__ o = ob + (size_t)(co0 + c) * 16384;
        const float4 v0 = make_float4(
            fmaxf(acc[c][0][0], 0.f), fmaxf(acc[c][0][1], 0.f),
            fmaxf(acc[c][1][0], 0.f), fmaxf(acc[c][1][1], 0.f));
        const float4 v1 = make_float4(
            fmaxf(acc[c][2][0], 0.f), fmaxf(acc[c][2][1], 0.f),
            fmaxf(acc[c][3][0], 0.f), fmaxf(acc[c][3][1], 0.f));
        *(float4*)o = v0;
        *(float4*)(o + 4) = v1;
    }
}

// Final transposed conv (32 -> 1). (validated)
__global__ __launch_bounds__(256) void convt2_quad(
    const float* __restrict__ in, const float* __restrict__ w,
    const float* __restrict__ bias, float* __restrict__ out, int B)
{
    const int IH = 128, IW = 128, CIN = 32, OW = 256;
    const int j = threadIdx.x & 127;
    const int i = (blockIdx.x << 1) + (threadIdx.x >> 7);
    const int b = blockIdx.y;

    const float* __restrict__ inb = in + (size_t)b * CIN * IH * IW;
    const float bz = bias[0];
    float a00 = bz, a01 = bz, a10 = bz, a11 = bz;

    const bool okm = (i > 0);
    const bool okp = (i < IH - 1);
    const bool olm = (j > 0);
    const bool olp = (j < IW - 1);

#pragma unroll 4
    for (int ci = 0; ci < CIN; ci++) {
        const float* __restrict__ p = inb + ((size_t)ci * IH + i) * IW + j;
        const float* __restrict__ wp = w + ci * 16;
        const float vmm = (okm && olm) ? p[-IW - 1] : 0.f;
        const float vm0 = okm ? p[-IW] : 0.f;
        const float vmp = (okm && olp) ? p[-IW + 1] : 0.f;
        const float v0m = olm ? p[-1] : 0.f;
        const float v00 = p[0];
        const float v0p = olp ? p[1] : 0.f;
        const float vpm = (okp && olm) ? p[IW - 1] : 0.f;
        const float vp0 = okp ? p[IW] : 0.f;
        const float vpp = (okp && olp) ? p[IW + 1] : 0.f;
        a00 = fmaf(v00, wp[1 * 4 + 1], a00);
        a00 = fmaf(v0m, wp[1 * 4 + 3], a00);
        a00 = fmaf(vm0, wp[3 * 4 + 1], a00);
        a00 = fmaf(vmm, wp[3 * 4 + 3], a00);
        a01 = fmaf(v0p, wp[1 * 4 + 0], a01);
        a01 = fmaf(v00, wp[1 * 4 + 2], a01);
        a01 = fmaf(vmp, wp[3 * 4 + 0], a01);
        a01 = fmaf(vm0, wp[3 * 4 + 2], a01);
        a10 = fmaf(vp0, wp[0 * 4 + 1], a10);
        a10 = fmaf(vpm, wp[0 * 4 + 3], a10);
        a10 = fmaf(v00, wp[2 * 4 + 1], a10);
        a10 = fmaf(v0m, wp[2 * 4 + 3], a10);
        a11 = fmaf(vpp, wp[0 * 4 + 0], a11);
        a11 = fmaf(vp0, wp[0 * 4 + 2], a11);
        a11 = fmaf(v0p, wp[2 * 4 + 0], a11);
        a11 = fmaf(v00, wp[2 * 4 + 2], a11);
    }

    float* __restrict__ outb = out + (size_t)b * 256 * 256;
    ((float2*)(outb + (size_t)(2 * i) * OW))[j] = make_float2(a00, a01);
    ((float2*)(outb + (size_t)(2 * i + 1) * OW))[j] = make_float2(a10, a11);
}

// VQ-GEMM (validated R9). DO NOT reorder any fmaf chain (R3).
__global__ __launch_bounds__(256) void vq_gemm(
    const float* __restrict__ h,    // (32,64,4096)
    const float* __restrict__ cb,   // (512,64) row-major (gather)
    const float* __restrict__ cbT,  // (64,512) dim-major (matmul)
    const float* __restrict__ ee,   // (512)
    float* __restrict__ q)          // (32,64,4096)
{
    __shared__ __align__(16) float As[64 * 128];
    __shared__ float xx_sh[128];
    __shared__ float pd[4 * 128];
    __shared__ int   pk[4 * 128];
    __shared__ int   bidx_sh[128];

    const int tid = threadIdx.x;
    const int tpx = tid & 63;
    const int w = __builtin_amdgcn_readfirstlane(tid >> 6);
    const int n0 = blockIdx.x * 128;
    const int b  = n0 >> 12;
    const int hw0 = n0 & 4095;

    const float* __restrict__ hb = h + (size_t)b * 64 * 4096 + hw0;
#pragma unroll
    for (int m = 0; m < 32; m++) {
        const int idx = m * 256 + tid;
        const int k = idx >> 7, p = idx & 127;
        As[idx] = hb[(size_t)k * 4096 + p];
    }
    __syncthreads();

    if (tid < 128) {
        float s = 0.0f;
#pragma unroll
        for (int i = 0; i < 64; i++) {
            const float v = As[i * 128 + tid];
            s = fmaf(v, v, s);
        }
        xx_sh[tid] = s;
    }
    __syncthreads();

    const float xx0 = xx_sh[tpx * 2];
    const float xx1 = xx_sh[tpx * 2 + 1];
    const int cwave = w * 128;

    float best0 = 3.402823466e+38f, best1 = 3.402823466e+38f;
    int bk0 = 0, bk1 = 0;

#pragma unroll 1
    for (int ch = 0; ch < 16; ch++) {
        const int cbase = cwave + ch * 8;
        float acc[8][2];
#pragma unroll
        for (int c = 0; c < 8; c++) { acc[c][0] = 0.0f; acc[c][1] = 0.0f; }

#pragma unroll 8
        for (int k = 0; k < 64; k++) {
            const float2 a2 = *(const float2*)(As + k * 128 + tpx * 2);
            const float* __restrict__ wk = cbT + (size_t)k * 512 + cbase;
#pragma unroll
            for (int c = 0; c < 8; c++) {
                const float wv = wk[c];
                acc[c][0] = fmaf(a2.x, wv, acc[c][0]);
                acc[c][1] = fmaf(a2.y, wv, acc[c][1]);
            }
        }
        const float* __restrict__ eep = ee + cbase;
#pragma unroll
        for (int c = 0; c < 8; c++) {
            const float eec = eep[c];
            const float d0 = xx0 - 2.0f * acc[c][0] + eec;
            const float d1 = xx1 - 2.0f * acc[c][1] + eec;
            if (d0 < best0) { best0 = d0; bk0 = cbase + c; }
            if (d1 < best1) { best1 = d1; bk1 = cbase + c; }
        }
    }

    pd[w * 128 + tpx * 2]     = best0;
    pd[w * 128 + tpx * 2 + 1] = best1;
    pk[w * 128 + tpx * 2]     = bk0;
    pk[w * 128 + tpx * 2 + 1] = bk1;
    __syncthreads();

    if (tid < 128) {
        float bd = pd[tid]; int bk = pk[tid];
#pragma unroll
        for (int ww = 1; ww < 4; ww++) {
            const float od = pd[ww * 128 + tid];
            if (od < bd) { bd = od; bk = pk[ww * 128 + tid]; }
        }
        bidx_sh[tid] = bk;
    }
    __syncthreads();

    {
        const int p  = tid & 127;
        const int d0 = (tid >> 7) * 32;
        const int bk = bidx_sh[p];
        const float4* __restrict__ cp4 = (const float4*)(cb + (size_t)bk * 64 + d0);
        float* __restrict__ qb = q + ((size_t)b * 64 + d0) * 4096 + hw0 + p;
#pragma unroll
        for (int i = 0; i < 8; i++) {
            const float4 v = cp4[i];
            qb[(size_t)(4 * i + 0) * 4096] = v.x;
            qb[(size_t)(4 * i + 1) * 4096] = v.y;
            qb[(size_t)(4 * i + 2) * 4096] = v.z;
            qb[(size_t)(4 * i + 3) * 4096] = v.w;
        }
    }
}

extern "C" void kernel_launch(void* const* d_in, const int* in_sizes, int n_in,
                              void* d_out, int out_size, void* d_ws, size_t ws_size,
                              hipStream_t stream) {
    const float* x      = (const float*)d_in[0];
    const float* w_e1   = (const float*)d_in[1];
    const float* b_e1   = (const float*)d_in[2];
    const float* w_e2   = (const float*)d_in[3];
    const float* b_e2   = (const float*)d_in[4];
    const float* w_er1a = (const float*)d_in[5];
    const float* w_er1b = (const float*)d_in[6];
    const float* w_er2a = (const float*)d_in[7];
    const float* w_er2b = (const float*)d_in[8];
    const float* w_pre  = (const float*)d_in[9];
    const float* b_pre  = (const float*)d_in[10];
    const float* cbk    = (const float*)d_in[11];
    const float* w_d1   = (const float*)d_in[12];
    const float* b_d1   = (const float*)d_in[13];
    const float* w_dr1a = (const float*)d_in[14];
    const float* w_dr1b = (const float*)d_in[15];
    const float* w_dr2a = (const float*)d_in[16];
    const float* w_dr2b = (const float*)d_in[17];
    const float* w_t1   = (const float*)d_in[18];
    const float* b_t1   = (const float*)d_in[19];
    const float* w_t2   = (const float*)d_in[20];
    const float* b_t2   = (const float*)d_in[21];
    float* out = (float*)d_out;

    float* A  = (float*)d_ws;            // 16777216 floats (scratch + t1 out)
    float* Bb = A  + 16777216;           // (32,64,64,64) = 8388608
    float* C  = Bb + 8388608;            // 4194304 (unused after fusion)
    float* D  = C  + 4194304;            // (32,64,64,64) = 8388608
    float* WR = D  + 8388608;            // repacked weights + cbT (221696)
    float* EE = WR + 221696;             // ee (512)

    float* r_e1  = WR;
    float* r_e2  = WR + 512;
    float* r_er1a = WR + 33280;
    float* r_er1b = WR + 51712;
    float* r_er2a = WR + 53760;
    float* r_er2b = WR + 72192;
    float* r_pre = WR + 74240;
    float* r_d1  = WR + 78336;
    float* r_dr1a = WR + 115200;
    float* r_dr1b = WR + 133632;
    float* r_dr2a = WR + 135680;
    float* r_dr2b = WR + 154112;
    float* r_t1  = WR + 156160;
    float* r_cbT = WR + 188928;

    const dim3 blk(256);
    const dim3 blk512(512);

    repack_all<<<dim3(866), blk, 0, stream>>>(
        w_e1, w_e2, w_er1a, w_er1b, w_er2a, w_er2b, w_pre, w_d1,
        w_dr1a, w_dr1b, w_dr2a, w_dr2b, w_t1, cbk, WR);
    vq_prep_ee<<<dim3(2), blk, 0, stream>>>(cbk, EE);

    // Encoder
    conv_gemm<32, 32, 1, 4, 2, 1, false, true, false, true>
        <<<dim3(2048, 1), blk, 0, stream>>>(x, r_e1, b_e1, nullptr, A,
                                            256, 256, 128, 128);
    conv_gemm<64, 16, 32, 4, 2, 1, false, true, false, false>
        <<<dim3(512, 4), blk, 0, stream>>>(A, r_e2, b_e2, nullptr, Bb,
                                           128, 128, 64, 64);
    // er1: Bb -> A ; er2: A -> Bb (ping-pong avoids in-place halo race)
    res_tile<<<dim3(512), blk512, 0, stream>>>(Bb, r_er1a, r_er1b, A);
    res_tile<<<dim3(512), blk512, 0, stream>>>(A, r_er2a, r_er2b, Bb);
    conv_gemm<64, 16, 64, 1, 1, 0, false, true, false, false>
        <<<dim3(512, 4), blk, 0, stream>>>(Bb, r_pre, b_pre, nullptr, D,
                                           64, 64, 64, 64);
    // VQ
    vq_gemm<<<dim3(1024), blk, 0, stream>>>(D, cbk, r_cbT, EE, Bb);
    // Decoder
    conv_gemm<64, 16, 64, 3, 1, 1, false, true, false, false>
        <<<dim3(512, 4), blk, 0, stream>>>(Bb, r_d1, b_d1, nullptr, D,
                                           64, 64, 64, 64);
    // dr1: D -> A ; dr2: A -> D
    res_tile<<<dim3(512), blk512, 0, stream>>>(D, r_dr1a, r_dr1b, A);
    res_tile<<<dim3(512), blk512, 0, stream>>>(A, r_dr2a, r_dr2b, D);
    // t1 (pc-merged, cout-split): grid (512, 2pr x 2cg)
    convt_gemm2<<<dim3(512, 4), blk, 0, stream>>>(D, r_t1, b_t1, A);
    // t2
    convt2_quad<<<dim3(64, 32), blk, 0, stream>>>(A, w_t2, b_t2, out, 32);
}

// Round 4
// 1039.398 us; speedup vs baseline: 1.3428x; 1.0209x over previous
//
#include <hip/hip_runtime.h>
#include <hip/hip_bf16.h>

// ---------------------------------------------------------------------------
// VQ-VAE forward, fp32. NCHW.
// R19: res_tile v2 - LDS-per-FMA rebalance. R18 post-mortem: conv1's thread
// tile (4 couts x 4 px) needed 24 LDS clk per (ci,kh) step (b128 + two 8-way
// conflicted edge b32s, SQ_LDS_BANK_CONFLICT=2.96e7) vs 96 VALU cyc; LDS is
// per-CU (shared by 4 SIMDs) so 16 waves x 24 = per-SIMD VALU demand ->
// both pipes saturated -> VALUBusy pinned ~45%. v2: 8 couts x 2 px per
// thread (128 px-pair lanes x 4 cout groups); per (ci,kh): 3 aligned
// ds_read_b64 (conflict-free, 12 clk) vs 96 VALU cyc -> LDS load factor 0.5.
// conv2: 16 couts x 2 px (R17-validated shape). Staging/barriers unchanged.
// Per-output FMA chains bit-identical (ci asc, kh asc, kw asc; same staged
// relu/zeros; same residual order) => VQ argmin unchanged (R3 lesson).
// All other kernels byte-identical to R18.
// ---------------------------------------------------------------------------

__device__ __forceinline__ float rp_elem(const float* __restrict__ src,
                                         int i, int COUT, int CIN, int KK)
{
    const int co = i % COUT;
    const int t  = i / COUT;
    const int kk = t % KK;
    const int ci = t / KK;
    return src[(co * CIN + ci) * KK + kk];
}

// One kernel repacks all weights + codebook-transpose into WR.
__global__ __launch_bounds__(256) void repack_all(
    const float* __restrict__ e1,  const float* __restrict__ e2,
    const float* __restrict__ er1a, const float* __restrict__ er1b,
    const float* __restrict__ er2a, const float* __restrict__ er2b,
    const float* __restrict__ pre, const float* __restrict__ d1,
    const float* __restrict__ dr1a, const float* __restrict__ dr1b,
    const float* __restrict__ dr2a, const float* __restrict__ dr2b,
    const float* __restrict__ t1, const float* __restrict__ cb,
    float* __restrict__ WR)
{
    const int idx = blockIdx.x * 256 + threadIdx.x;
    if (idx >= 221696) return;
    float v;
    if      (idx < 512)    v = rp_elem(e1,   idx,          32,  1, 16);
    else if (idx < 33280)  v = rp_elem(e2,   idx - 512,    64, 32, 16);
    else if (idx < 51712)  v = rp_elem(er1a, idx - 33280,  32, 64,  9);
    else if (idx < 53760)  v = rp_elem(er1b, idx - 51712,  64, 32,  1);
    else if (idx < 72192)  v = rp_elem(er2a, idx - 53760,  32, 64,  9);
    else if (idx < 74240)  v = rp_elem(er2b, idx - 72192,  64, 32,  1);
    else if (idx < 78336)  v = rp_elem(pre,  idx - 74240,  64, 64,  1);
    else if (idx < 115200) v = rp_elem(d1,   idx - 78336,  64, 64,  9);
    else if (idx < 133632) v = rp_elem(dr1a, idx - 115200, 32, 64,  9);
    else if (idx < 135680) v = rp_elem(dr1b, idx - 133632, 64, 32,  1);
    else if (idx < 154112) v = rp_elem(dr2a, idx - 135680, 32, 64,  9);
    else if (idx < 156160) v = rp_elem(dr2b, idx - 154112, 64, 32,  1);
    else if (idx < 188928) {
        // t1: [pr][k2=ci*2+ta][q=pc*2+tb][co]
        const int i  = idx - 156160;
        const int co = i & 31;
        const int q  = (i >> 5) & 3;
        const int k2 = (i >> 7) & 127;
        const int pr = i >> 14;
        const int pc = q >> 1, tb = q & 1;
        const int ci = k2 >> 1, ta = k2 & 1;
        const int kh = (1 - pr) + 2 * ta, kw = (1 - pc) + 2 * tb;
        v = t1[((ci * 32 + co) * 4 + kh) * 4 + kw];
    } else {
        const int i = idx - 188928;           // cbT: [dim][code]
        const int code = i & 511;
        const int dim  = i >> 9;
        v = cb[code * 64 + dim];
    }
    WR[idx] = v;
}

// ee[k] = sum_i cb[k][i]^2, exact ascending fmaf chain (matches reference).
__global__ __launch_bounds__(256) void vq_prep_ee(
    const float* __restrict__ cb, float* __restrict__ ee)
{
    const int k = blockIdx.x * 256 + threadIdx.x;  // grid(2) -> k < 512
    const float* __restrict__ cp = cb + (size_t)k * 64;
    float s = 0.0f;
#pragma unroll
    for (int i = 0; i < 64; i++) s = fmaf(cp[i], cp[i], s);
    ee[k] = s;
}

// GEMM-form conv (validated R13). Block: CPB couts x 256 pixels; thread:
// CPTHD x 4 pixels. K-chunks double-buffered in LDS; K=4 tap-split.
template<int CTOT, int CPB, int CIN, int K, int S, int PAD,
         bool RELU_IN, bool HAS_BIAS, bool RESID, bool RELU_OUT>
__global__ __launch_bounds__(256) void conv_gemm(
    const float* __restrict__ in, const float* __restrict__ wr,
    const float* __restrict__ bias, const float* __restrict__ resid,
    float* __restrict__ out,
    int H, int W, int OH, int OW)
{
    constexpr int KK  = K * K;
    constexpr int CIC = (K == 1) ? 8 : 1;
    constexpr int TS  = (K == 4) ? 2 : 1;
    constexpr int KC  = CIC * KK / TS;
    constexpr int NCH = (CIN * TS) / CIC;
    constexpr int NT  = 256;
    constexpr int CPTHD = CPB / 4;
    __shared__ __align__(16) float As[2][KC * NT];

    const int tid = threadIdx.x;
    const int tpx = tid & 63;
    const int tco = __builtin_amdgcn_readfirstlane(tid >> 6);
    const int co0 = blockIdx.y * CPB + tco * CPTHD;

    const int ohow = OH * OW;
    const int n_st = blockIdx.x * NT + tid;
    const int b_st = n_st / ohow;
    const int hw_s = n_st % ohow;
    const int ih0 = (hw_s / OW) * S - PAD;
    const int iw0 = (hw_s % OW) * S - PAD;
    const float* __restrict__ inb = in + (size_t)b_st * CIN * H * W;

    float acc[CPTHD][4];
#pragma unroll
    for (int c = 0; c < CPTHD; c++) {
        const float bz = HAS_BIAS ? bias[co0 + c] : 0.0f;
#pragma unroll
        for (int q = 0; q < 4; q++) acc[c][q] = bz;
    }

    float pf[KC];
    auto stage_load = [&](int ch) {
#pragma unroll
        for (int t = 0; t < KC; t++) {
            int ci, kh, kw;
            if constexpr (K == 1) {
                ci = ch * 8 + t; kh = 0; kw = 0;
            } else if constexpr (K == 3) {
                ci = ch; kh = t / 3; kw = t % 3;
            } else {                                 // K == 4, TS = 2
                ci = ch >> 1;
                const int kk = ((ch & 1) << 3) + t;
                kh = kk >> 2; kw = kk & 3;
            }
            const int ih = ih0 + kh, iw = iw0 + kw;
            float v = 0.0f;
            if (ih >= 0 && ih < H && iw >= 0 && iw < W)
                v = inb[(size_t)ci * H * W + ih * W + iw];
            if (RELU_IN) v = fmaxf(v, 0.0f);
            pf[t] = v;
        }
    };

    stage_load(0);
#pragma unroll
    for (int t = 0; t < KC; t++) As[0][t * NT + tid] = pf[t];
    __syncthreads();

#pragma unroll 2
    for (int c = 0; c < NCH; c++) {
        const int cur = c & 1;
        if (c + 1 < NCH) stage_load(c + 1);

#pragma unroll
        for (int t = 0; t < KC; t++) {
            const float4 a4 = *(const float4*)(As[cur] + t * NT + tpx * 4);
            const float* __restrict__ wk =
                wr + (size_t)(c * KC + t) * CTOT + co0;
#pragma unroll
            for (int cc = 0; cc < CPTHD; cc++) {
                const float w = wk[cc];
                acc[cc][0] = fmaf(a4.x, w, acc[cc][0]);
                acc[cc][1] = fmaf(a4.y, w, acc[cc][1]);
                acc[cc][2] = fmaf(a4.z, w, acc[cc][2]);
                acc[cc][3] = fmaf(a4.w, w, acc[cc][3]);
            }
        }

        if (c + 1 < NCH) {
#pragma unroll
            for (int t = 0; t < KC; t++) As[1 - cur][t * NT + tid] = pf[t];
        }
        __syncthreads();
    }

    const int n_c  = blockIdx.x * NT + tpx * 4;
    const int b_c  = n_c / ohow;
    const int hw_c = n_c % ohow;
    float* __restrict__ op = out + (size_t)b_c * CTOT * ohow + hw_c;
    const float* __restrict__ rp =
        RESID ? (resid + (size_t)b_c * CTOT * ohow + hw_c) : nullptr;
#pragma unroll
    for (int c = 0; c < CPTHD; c++) {
        const size_t off = (size_t)(co0 + c) * ohow;
        float4 r = make_float4(acc[c][0], acc[c][1], acc[c][2], acc[c][3]);
        if (RESID) {
            const float4 rv = *(const float4*)(rp + off);
            r.x += rv.x; r.y += rv.y; r.z += rv.z; r.w += rv.w;
        }
        if (RELU_OUT) {
            r.x = fmaxf(r.x, 0.f); r.y = fmaxf(r.y, 0.f);
            r.z = fmaxf(r.z, 0.f); r.w = fmaxf(r.w, 0.f);
        }
        *(float4*)(op + off) = r;
    }
}

// Fused residual block, R19 "stage-once" v2.
// 512 threads = 128 px-pair lanes x 4 cout-groups. LDS = 32ch x 6rows x 72
// cols tile (54KB), staged in two 32-ch halves, half-1 prefetched into
// registers during half-0 compute. conv1: 8 couts x 2 px/thread; per
// (ci,kh): 3 aligned ds_read_b64 (conflict-free) vs 96 VALU cyc. conv2:
// 16 couts x 2 px. 5 barriers/block.
__global__ __launch_bounds__(512, 4) void res_tile(
    const float* __restrict__ in, const float* __restrict__ wr1,
    const float* __restrict__ wr2, float* __restrict__ out)
{
    // tile: [ci<32][r6<6][72] floats = 13824 (54KB); mid[32][256] overlays.
    __shared__ __align__(16) float S[13824];

    const int tid = threadIdx.x;
    const int p   = tid & 127;                                  // px-pair
    const int cog = __builtin_amdgcn_readfirstlane(tid >> 7);   // 0..3
    const int a   = p >> 5;                // px row in block (0..3)
    const int c0  = (p & 31) * 2;          // px col base (0,2,..,62)

    const int n0   = blockIdx.x * 256;
    const int b    = n0 >> 12;
    const int row0 = (n0 & 4095) >> 6;     // 4 rows of 64
    const float* __restrict__ inb = in + (size_t)b * 64 * 4096;

    // ---- staging: 3456 float4 per 32-ch half; 7 per thread (guarded).
    float4 pf4[7];
    auto stage_issue = [&](int half) {
#pragma unroll
        for (int m = 0; m < 7; m++) {
            const int f4 = m * 512 + tid;
            float4 v = make_float4(0.f, 0.f, 0.f, 0.f);
            if (f4 < 3456) {
                const int ci  = f4 / 108;            // 0..31
                const int rem = f4 - ci * 108;
                const int r6  = rem / 18;            // 0..5
                const int c4  = rem - r6 * 18;       // 0..17
                const int ih  = row0 + r6 - 1;
                if (ih >= 0 && ih < 64 && c4 >= 1 && c4 <= 16)
                    v = *(const float4*)(inb + (size_t)(half * 32 + ci) * 4096
                                         + ih * 64 + (c4 * 4 - 4));
            }
            pf4[m] = v;
        }
    };
    auto stage_commit = [&]() {
#pragma unroll
        for (int m = 0; m < 7; m++) {
            const int f4 = m * 512 + tid;
            if (f4 < 3456) {
                float4 v = pf4[m];
                v.x = fmaxf(v.x, 0.f); v.y = fmaxf(v.y, 0.f);
                v.z = fmaxf(v.z, 0.f); v.w = fmaxf(v.w, 0.f);
                *(float4*)(S + f4 * 4) = v;
            }
        }
    };

    const int co1 = cog * 8;
    float acc1[8][2];
#pragma unroll
    for (int c = 0; c < 8; c++) { acc1[c][0] = 0.0f; acc1[c][1] = 0.0f; }

    // conv1 over one 32-channel half; chain per output: ci asc, kh asc, kw asc.
    auto conv1_half = [&](int h) {
#pragma unroll 2
        for (int c = 0; c < 32; c++) {
            const float* __restrict__ wb =
                wr1 + (size_t)((h * 32 + c) * 9) * 32 + co1;
#pragma unroll
            for (int kh = 0; kh < 3; kh++) {
                const float* __restrict__ tp =
                    S + c * 432 + (a + kh) * 72 + 4 + c0;
                const float2 L = *(const float2*)(tp - 2);
                const float2 M = *(const float2*)(tp);
                const float2 R = *(const float2*)(tp + 2);
                const float xm = L.y;            // col c0-1
                const float x0 = M.x;            // col c0
                const float x1 = M.y;            // col c0+1
                const float x2 = R.x;            // col c0+2
                const float* __restrict__ wk = wb + (size_t)(kh * 3) * 32;
#pragma unroll
                for (int cc = 0; cc < 8; cc++) {     // kw = 0
                    const float w = wk[cc];
                    acc1[cc][0] = fmaf(xm, w, acc1[cc][0]);
                    acc1[cc][1] = fmaf(x0, w, acc1[cc][1]);
                }
#pragma unroll
                for (int cc = 0; cc < 8; cc++) {     // kw = 1
                    const float w = wk[32 + cc];
                    acc1[cc][0] = fmaf(x0, w, acc1[cc][0]);
                    acc1[cc][1] = fmaf(x1, w, acc1[cc][1]);
                }
#pragma unroll
                for (int cc = 0; cc < 8; cc++) {     // kw = 2
                    const float w = wk[64 + cc];
                    acc1[cc][0] = fmaf(x1, w, acc1[cc][0]);
                    acc1[cc][1] = fmaf(x2, w, acc1[cc][1]);
                }
            }
        }
    };

    stage_issue(0);
    stage_commit();
    __syncthreads();
    stage_issue(1);          // prefetch half 1; lands during half-0 compute
    conv1_half(0);
    __syncthreads();         // all half-0 reads done
    stage_commit();
    __syncthreads();         // half-1 tile visible
    conv1_half(1);
    __syncthreads();         // all half-1 reads done; S free for mid overlay

    // mid[co][px] (32x256 = 32KB) overlays tile region.
#pragma unroll
    for (int cc = 0; cc < 8; cc++)
        *(float2*)(S + (co1 + cc) * 256 + p * 2) =
            make_float2(acc1[cc][0], acc1[cc][1]);
    __syncthreads();

    const int co2 = cog * 16;
    float acc2[16][2];
#pragma unroll
    for (int c = 0; c < 16; c++) { acc2[c][0] = 0.0f; acc2[c][1] = 0.0f; }

#pragma unroll 4
    for (int k = 0; k < 32; k++) {
        float2 m2 = *(const float2*)(S + k * 256 + p * 2);
        m2.x = fmaxf(m2.x, 0.f);
        m2.y = fmaxf(m2.y, 0.f);
        const float* __restrict__ wk = wr2 + (size_t)k * 64 + co2;
#pragma unroll
        for (int cc = 0; cc < 16; cc++) {
            const float w = wk[cc];
            acc2[cc][0] = fmaf(m2.x, w, acc2[cc][0]);
            acc2[cc][1] = fmaf(m2.y, w, acc2[cc][1]);
        }
    }

    const int hw = (n0 & 4095) + p * 2;
    const float* __restrict__ rp = inb + hw;
    float* __restrict__ op = out + (size_t)b * 64 * 4096 + hw;
#pragma unroll
    for (int cc = 0; cc < 16; cc++) {
        const size_t off = (size_t)(co2 + cc) * 4096;
        const float2 rv = *(const float2*)(rp + off);
        *(float2*)(op + off) =
            make_float2(acc2[cc][0] + rv.x, acc2[cc][1] + rv.y);
    }
}

// t1 pc-merged GEMM, R15: cout-split (grid.y = 2pr x 2 cout-groups) +
// double-buffered staging (1 barrier/chunk). Wave owns 4 couts.
// FMA order per output: ci asc, ta asc, tb asc — identical to R12/R14.
__global__ __launch_bounds__(256) void convt_gemm2(
    const float* __restrict__ in, const float* __restrict__ wr,
    const float* __restrict__ bias, float* __restrict__ out)
{
    constexpr int NT = 256;
    __shared__ __align__(16) float As[2][12 * NT];   // 24 KB

    const int tid = threadIdx.x;
    const int tpx = tid & 63;
    const int tco = __builtin_amdgcn_readfirstlane(tid >> 6);
    const int pr = blockIdx.y & 1;
    const int cg = blockIdx.y >> 1;
    const int co0 = cg * 16 + tco * 4;

    const int n_st = blockIdx.x * NT + tid;
    const int b = n_st >> 12;
    const int i_st = (n_st & 4095) >> 6;
    const int j_st = n_st & 63;
    const float* __restrict__ inb = in + (size_t)b * 64 * 4096;

    float acc[4][4][2];
#pragma unroll
    for (int c = 0; c < 4; c++) {
        const float bz = bias[co0 + c];
#pragma unroll
        for (int p = 0; p < 4; p++) {
            acc[c][p][0] = bz;
            acc[c][p][1] = bz;
        }
    }

    const float* __restrict__ wpr = wr + (size_t)pr * 128 * 4 * 32;

    float pf[12];
    auto stage_load = [&](int ch) {
#pragma unroll
        for (int t = 0; t < 4; t++) {
            const int k2 = ch * 4 + t;
            const int ci = k2 >> 1;
            const int ta = k2 & 1;
            const int ih = i_st + pr - ta;
            const bool rok = (ih >= 0) && (ih < 64);
            const float* __restrict__ row = inb + (size_t)ci * 4096 + ih * 64;
#pragma unroll
            for (int m = 0; m < 3; m++) {
                const int iw = j_st + m - 1;
                float v = 0.0f;
                if (rok && iw >= 0 && iw < 64) v = row[iw];
                pf[t * 3 + m] = v;
            }
        }
    };

    stage_load(0);
#pragma unroll
    for (int t = 0; t < 12; t++) As[0][t * NT + tid] = pf[t];
    __syncthreads();

#pragma unroll 2
    for (int ch = 0; ch < 32; ch++) {
        const int cur = ch & 1;
        if (ch + 1 < 32) stage_load(ch + 1);

#pragma unroll
        for (int t = 0; t < 4; t++) {
            float4 a[3];
#pragma unroll
            for (int m = 0; m < 3; m++)
                a[m] = *(const float4*)(As[cur] + (t * 3 + m) * NT + tpx * 4);
            const float* __restrict__ wk =
                wpr + (size_t)(ch * 4 + t) * 4 * 32 + co0;
#pragma unroll
            for (int tb = 0; tb < 2; tb++) {
#pragma unroll
                for (int pc = 0; pc < 2; pc++) {
                    const int q = pc * 2 + tb;
                    const int m = pc - tb + 1;
                    const float* __restrict__ wt = wk + q * 32;
                    const float vx = a[m].x, vy = a[m].y,
                                vz = a[m].z, vw = a[m].w;
#pragma unroll
                    for (int c = 0; c < 4; c++) {
                        const float w = wt[c];
                        acc[c][0][pc] = fmaf(vx, w, acc[c][0][pc]);
                        acc[c][1][pc] = fmaf(vy, w, acc[c][1][pc]);
                        acc[c][2][pc] = fmaf(vz, w, acc[c][2][pc]);
                        acc[c][3][pc] = fmaf(vw, w, acc[c][3][pc]);
                    }
                }
            }
        }

        if (ch + 1 < 32) {
#pragma unroll
            for (int t = 0; t < 12; t++) As[1 - cur][t * NT + tid] = pf[t];
        }
        __syncthreads();
    }

    const int n_c = blockIdx.x * NT + tpx * 4;
    const int i_c = (n_c & 4095) >> 6;
    const int j_c = n_c & 63;
    const int oh = 2 * i_c + pr;
    float* __restrict__ ob =
        out + (size_t)b * 32 * 16384 + (size_t)oh * 128 + 2 * j_c;
#pragma unroll
    for (int c = 0; c < 4; c++) {
        float* __restrict__ o = ob + (size_t)(co0 + c) * 16384;
        const float4 v0 = make_float4(
            fmaxf(acc[c][0][0], 0.f), fmaxf(acc[c][0][1], 0.f),
            fmaxf(acc[c][1][0], 0.f), fmaxf(acc[c][1][1], 0.f));
        const float4 v1 = make_float4(
            fmaxf(acc[c][2][0], 0.f), fmaxf(acc[c][2][1], 0.f),
            fmaxf(acc[c][3][0], 0.f), fmaxf(acc[c][3][1], 0.f));
        *(float4*)o = v0;
        *(float4*)(o + 4) = v1;
    }
}

// Final transposed conv (32 -> 1). (validated)
__global__ __launch_bounds__(256) void convt2_quad(
    const float* __restrict__ in, const float* __restrict__ w,
    const float* __restrict__ bias, float* __restrict__ out, int B)
{
    const int IH = 128, IW = 128, CIN = 32, OW = 256;
    const int j = threadIdx.x & 127;
    const int i = (blockIdx.x << 1) + (threadIdx.x >> 7);
    const int b = blockIdx.y;

    const float* __restrict__ inb = in + (size_t)b * CIN * IH * IW;
    const float bz = bias[0];
    float a00 = bz, a01 = bz, a10 = bz, a11 = bz;

    const bool okm = (i > 0);
    const bool okp = (i < IH - 1);
    const bool olm = (j > 0);
    const bool olp = (j < IW - 1);

#pragma unroll 4
    for (int ci = 0; ci < CIN; ci++) {
        const float* __restrict__ p = inb + ((size_t)ci * IH + i) * IW + j;
        const float* __restrict__ wp = w + ci * 16;
        const float vmm = (okm && olm) ? p[-IW - 1] : 0.f;
        const float vm0 = okm ? p[-IW] : 0.f;
        const float vmp = (okm && olp) ? p[-IW + 1] : 0.f;
        const float v0m = olm ? p[-1] : 0.f;
        const float v00 = p[0];
        const float v0p = olp ? p[1] : 0.f;
        const float vpm = (okp && olm) ? p[IW - 1] : 0.f;
        const float vp0 = okp ? p[IW] : 0.f;
        const float vpp = (okp && olp) ? p[IW + 1] : 0.f;
        a00 = fmaf(v00, wp[1 * 4 + 1], a00);
        a00 = fmaf(v0m, wp[1 * 4 + 3], a00);
        a00 = fmaf(vm0, wp[3 * 4 + 1], a00);
        a00 = fmaf(vmm, wp[3 * 4 + 3], a00);
        a01 = fmaf(v0p, wp[1 * 4 + 0], a01);
        a01 = fmaf(v00, wp[1 * 4 + 2], a01);
        a01 = fmaf(vmp, wp[3 * 4 + 0], a01);
        a01 = fmaf(vm0, wp[3 * 4 + 2], a01);
        a10 = fmaf(vp0, wp[0 * 4 + 1], a10);
        a10 = fmaf(vpm, wp[0 * 4 + 3], a10);
        a10 = fmaf(v00, wp[2 * 4 + 1], a10);
        a10 = fmaf(v0m, wp[2 * 4 + 3], a10);
        a11 = fmaf(vpp, wp[0 * 4 + 0], a11);
        a11 = fmaf(vp0, wp[0 * 4 + 2], a11);
        a11 = fmaf(v0p, wp[2 * 4 + 0], a11);
        a11 = fmaf(v00, wp[2 * 4 + 2], a11);
    }

    float* __restrict__ outb = out + (size_t)b * 256 * 256;
    ((float2*)(outb + (size_t)(2 * i) * OW))[j] = make_float2(a00, a01);
    ((float2*)(outb + (size_t)(2 * i + 1) * OW))[j] = make_float2(a10, a11);
}

// VQ-GEMM (validated R9). DO NOT reorder any fmaf chain (R3).
__global__ __launch_bounds__(256) void vq_gemm(
    const float* __restrict__ h,    // (32,64,4096)
    const float* __restrict__ cb,   // (512,64) row-major (gather)
    const float* __restrict__ cbT,  // (64,512) dim-major (matmul)
    const float* __restrict__ ee,   // (512)
    float* __restrict__ q)          // (32,64,4096)
{
    __shared__ __align__(16) float As[64 * 128];
    __shared__ float xx_sh[128];
    __shared__ float pd[4 * 128];
    __shared__ int   pk[4 * 128];
    __shared__ int   bidx_sh[128];

    const int tid = threadIdx.x;
    const int tpx = tid & 63;
    const int w = __builtin_amdgcn_readfirstlane(tid >> 6);
    const int n0 = blockIdx.x * 128;
    const int b  = n0 >> 12;
    const int hw0 = n0 & 4095;

    const float* __restrict__ hb = h + (size_t)b * 64 * 4096 + hw0;
#pragma unroll
    for (int m = 0; m < 32; m++) {
        const int idx = m * 256 + tid;
        const int k = idx >> 7, p = idx & 127;
        As[idx] = hb[(size_t)k * 4096 + p];
    }
    __syncthreads();

    if (tid < 128) {
        float s = 0.0f;
#pragma unroll
        for (int i = 0; i < 64; i++) {
            const float v = As[i * 128 + tid];
            s = fmaf(v, v, s);
        }
        xx_sh[tid] = s;
    }
    __syncthreads();

    const float xx0 = xx_sh[tpx * 2];
    const float xx1 = xx_sh[tpx * 2 + 1];
    const int cwave = w * 128;

    float best0 = 3.402823466e+38f, best1 = 3.402823466e+38f;
    int bk0 = 0, bk1 = 0;

#pragma unroll 1
    for (int ch = 0; ch < 16; ch++) {
        const int cbase = cwave + ch * 8;
        float acc[8][2];
#pragma unroll
        for (int c = 0; c < 8; c++) { acc[c][0] = 0.0f; acc[c][1] = 0.0f; }

#pragma unroll 8
        for (int k = 0; k < 64; k++) {
            const float2 a2 = *(const float2*)(As + k * 128 + tpx * 2);
            const float* __restrict__ wk = cbT + (size_t)k * 512 + cbase;
#pragma unroll
            for (int c = 0; c < 8; c++) {
                const float wv = wk[c];
                acc[c][0] = fmaf(a2.x, wv, acc[c][0]);
                acc[c][1] = fmaf(a2.y, wv, acc[c][1]);
            }
        }
        const float* __restrict__ eep = ee + cbase;
#pragma unroll
        for (int c = 0; c < 8; c++) {
            const float eec = eep[c];
            const float d0 = xx0 - 2.0f * acc[c][0] + eec;
            const float d1 = xx1 - 2.0f * acc[c][1] + eec;
            if (d0 < best0) { best0 = d0; bk0 = cbase + c; }
            if (d1 < best1) { best1 = d1; bk1 = cbase + c; }
        }
    }

    pd[w * 128 + tpx * 2]     = best0;
    pd[w * 128 + tpx * 2 + 1] = best1;
    pk[w * 128 + tpx * 2]     = bk0;
    pk[w * 128 + tpx * 2 + 1] = bk1;
    __syncthreads();

    if (tid < 128) {
        float bd = pd[tid]; int bk = pk[tid];
#pragma unroll
        for (int ww = 1; ww < 4; ww++) {
            const float od = pd[ww * 128 + tid];
            if (od < bd) { bd = od; bk = pk[ww * 128 + tid]; }
        }
        bidx_sh[tid] = bk;
    }
    __syncthreads();

    {
        const int p  = tid & 127;
        const int d0 = (tid >> 7) * 32;
        const int bk = bidx_sh[p];
        const float4* __restrict__ cp4 = (const float4*)(cb + (size_t)bk * 64 + d0);
        float* __restrict__ qb = q + ((size_t)b * 64 + d0) * 4096 + hw0 + p;
#pragma unroll
        for (int i = 0; i < 8; i++) {
            const float4 v = cp4[i];
            qb[(size_t)(4 * i + 0) * 4096] = v.x;
            qb[(size_t)(4 * i + 1) * 4096] = v.y;
            qb[(size_t)(4 * i + 2) * 4096] = v.z;
            qb[(size_t)(4 * i + 3) * 4096] = v.w;
        }
    }
}

extern "C" void kernel_launch(void* const* d_in, const int* in_sizes, int n_in,
                              void* d_out, int out_size, void* d_ws, size_t ws_size,
                              hipStream_t stream) {
    const float* x      = (const float*)d_in[0];
    const float* w_e1   = (const float*)d_in[1];
    const float* b_e1   = (const float*)d_in[2];
    const float* w_e2   = (const float*)d_in[3];
    const float* b_e2   = (const float*)d_in[4];
    const float* w_er1a = (const float*)d_in[5];
    const float* w_er1b = (const float*)d_in[6];
    const float* w_er2a = (const float*)d_in[7];
    const float* w_er2b = (const float*)d_in[8];
    const float* w_pre  = (const float*)d_in[9];
    const float* b_pre  = (const float*)d_in[10];
    const float* cbk    = (const float*)d_in[11];
    const float* w_d1   = (const float*)d_in[12];
    const float* b_d1   = (const float*)d_in[13];
    const float* w_dr1a = (const float*)d_in[14];
    const float* w_dr1b = (const float*)d_in[15];
    const float* w_dr2a = (const float*)d_in[16];
    const float* w_dr2b = (const float*)d_in[17];
    const float* w_t1   = (const float*)d_in[18];
    const float* b_t1   = (const float*)d_in[19];
    const float* w_t2   = (const float*)d_in[20];
    const float* b_t2   = (const float*)d_in[21];
    float* out = (float*)d_out;

    float* A  = (float*)d_ws;            // 16777216 floats (scratch + t1 out)
    float* Bb = A  + 16777216;           // (32,64,64,64) = 8388608
    float* C  = Bb + 8388608;            // 4194304 (unused after fusion)
    float* D  = C  + 4194304;            // (32,64,64,64) = 8388608
    float* WR = D  + 8388608;            // repacked weights + cbT (221696)
    float* EE = WR + 221696;             // ee (512)

    float* r_e1  = WR;
    float* r_e2  = WR + 512;
    float* r_er1a = WR + 33280;
    float* r_er1b = WR + 51712;
    float* r_er2a = WR + 53760;
    float* r_er2b = WR + 72192;
    float* r_pre = WR + 74240;
    float* r_d1  = WR + 78336;
    float* r_dr1a = WR + 115200;
    float* r_dr1b = WR + 133632;
    float* r_dr2a = WR + 135680;
    float* r_dr2b = WR + 154112;
    float* r_t1  = WR + 156160;
    float* r_cbT = WR + 188928;

    const dim3 blk(256);
    const dim3 blk512(512);

    repack_all<<<dim3(866), blk, 0, stream>>>(
        w_e1, w_e2, w_er1a, w_er1b, w_er2a, w_er2b, w_pre, w_d1,
        w_dr1a, w_dr1b, w_dr2a, w_dr2b, w_t1, cbk, WR);
    vq_prep_ee<<<dim3(2), blk, 0, stream>>>(cbk, EE);

    // Encoder
    conv_gemm<32, 32, 1, 4, 2, 1, false, true, false, true>
        <<<dim3(2048, 1), blk, 0, stream>>>(x, r_e1, b_e1, nullptr, A,
                                            256, 256, 128, 128);
    conv_gemm<64, 16, 32, 4, 2, 1, false, true, false, false>
        <<<dim3(512, 4), blk, 0, stream>>>(A, r_e2, b_e2, nullptr, Bb,
                                           128, 128, 64, 64);
    // er1: Bb -> A ; er2: A -> Bb (ping-pong avoids in-place halo race)
    res_tile<<<dim3(512), blk512, 0, stream>>>(Bb, r_er1a, r_er1b, A);
    res_tile<<<dim3(512), blk512, 0, stream>>>(A, r_er2a, r_er2b, Bb);
    conv_gemm<64, 16, 64, 1, 1, 0, false, true, false, false>
        <<<dim3(512, 4), blk, 0, stream>>>(Bb, r_pre, b_pre, nullptr, D,
                                           64, 64, 64, 64);
    // VQ
    vq_gemm<<<dim3(1024), blk, 0, stream>>>(D, cbk, r_cbT, EE, Bb);
    // Decoder
    conv_gemm<64, 16, 64, 3, 1, 1, false, true, false, false>
        <<<dim3(512, 4), blk, 0, stream>>>(Bb, r_d1, b_d1, nullptr, D,
                                           64, 64, 64, 64);
    // dr1: D -> A ; dr2: A -> D
    res_tile<<<dim3(512), blk512, 0, stream>>>(D, r_dr1a, r_dr1b, A);
    res_tile<<<dim3(512), blk512, 0, stream>>>(A, r_dr2a, r_dr2b, D);
    // t1 (pc-merged, cout-split): grid (512, 2pr x 2cg)
    convt_gemm2<<<dim3(512, 4), blk, 0, stream>>>(D, r_t1, b_t1, A);
    // t2
    convt2_quad<<<dim3(64, 32), blk, 0, stream>>>(A, w_t2, b_t2, out, 32);
}

// Round 5
// 909.338 us; speedup vs baseline: 1.5349x; 1.1430x over previous
//
#include <hip/hip_runtime.h>
#include <hip/hip_bf16.h>

// ---------------------------------------------------------------------------
// VQ-VAE forward, fp32. NCHW.
// R20: stage-once ported to the two biggest remaining kernels (e2, d1 at
// 166us each, 2.7x their VALU floors, stuck in the 2-barrier-per-chunk
// conv_gemm structure R18 proved pathological).
//   conv3_tile (d1): res_tile-conv1 clone, 64 couts (16 co x 2 px/thread,
//     96 FMA : 3 ds_read_b64), bias, no relu. 3 barriers/block. grid 512.
//   conv4s2_tile (e2): 128 out-px/block, 16ci x 6row x 136col halves (51KB),
//     stride-2 cols via 4 aligned ds_read_b64 -> x0..x5; 64 FMA : 4 reads.
//     grid 1024.
// Both chains (ci asc, kh asc, kw asc from bias) == conv_gemm's linearized
// order; same zero-pad; no staging relu => bit-identical => VQ argmin safe
// (R3). res_tile/e1/pre/vq/t1/t2 byte-identical to R19.
// ---------------------------------------------------------------------------

__device__ __forceinline__ float rp_elem(const float* __restrict__ src,
                                         int i, int COUT, int CIN, int KK)
{
    const int co = i % COUT;
    const int t  = i / COUT;
    const int kk = t % KK;
    const int ci = t / KK;
    return src[(co * CIN + ci) * KK + kk];
}

// One kernel repacks all weights + codebook-transpose into WR.
__global__ __launch_bounds__(256) void repack_all(
    const float* __restrict__ e1,  const float* __restrict__ e2,
    const float* __restrict__ er1a, const float* __restrict__ er1b,
    const float* __restrict__ er2a, const float* __restrict__ er2b,
    const float* __restrict__ pre, const float* __restrict__ d1,
    const float* __restrict__ dr1a, const float* __restrict__ dr1b,
    const float* __restrict__ dr2a, const float* __restrict__ dr2b,
    const float* __restrict__ t1, const float* __restrict__ cb,
    float* __restrict__ WR)
{
    const int idx = blockIdx.x * 256 + threadIdx.x;
    if (idx >= 221696) return;
    float v;
    if      (idx < 512)    v = rp_elem(e1,   idx,          32,  1, 16);
    else if (idx < 33280)  v = rp_elem(e2,   idx - 512,    64, 32, 16);
    else if (idx < 51712)  v = rp_elem(er1a, idx - 33280,  32, 64,  9);
    else if (idx < 53760)  v = rp_elem(er1b, idx - 51712,  64, 32,  1);
    else if (idx < 72192)  v = rp_elem(er2a, idx - 53760,  32, 64,  9);
    else if (idx < 74240)  v = rp_elem(er2b, idx - 72192,  64, 32,  1);
    else if (idx < 78336)  v = rp_elem(pre,  idx - 74240,  64, 64,  1);
    else if (idx < 115200) v = rp_elem(d1,   idx - 78336,  64, 64,  9);
    else if (idx < 133632) v = rp_elem(dr1a, idx - 115200, 32, 64,  9);
    else if (idx < 135680) v = rp_elem(dr1b, idx - 133632, 64, 32,  1);
    else if (idx < 154112) v = rp_elem(dr2a, idx - 135680, 32, 64,  9);
    else if (idx < 156160) v = rp_elem(dr2b, idx - 154112, 64, 32,  1);
    else if (idx < 188928) {
        // t1: [pr][k2=ci*2+ta][q=pc*2+tb][co]
        const int i  = idx - 156160;
        const int co = i & 31;
        const int q  = (i >> 5) & 3;
        const int k2 = (i >> 7) & 127;
        const int pr = i >> 14;
        const int pc = q >> 1, tb = q & 1;
        const int ci = k2 >> 1, ta = k2 & 1;
        const int kh = (1 - pr) + 2 * ta, kw = (1 - pc) + 2 * tb;
        v = t1[((ci * 32 + co) * 4 + kh) * 4 + kw];
    } else {
        const int i = idx - 188928;           // cbT: [dim][code]
        const int code = i & 511;
        const int dim  = i >> 9;
        v = cb[code * 64 + dim];
    }
    WR[idx] = v;
}

// ee[k] = sum_i cb[k][i]^2, exact ascending fmaf chain (matches reference).
__global__ __launch_bounds__(256) void vq_prep_ee(
    const float* __restrict__ cb, float* __restrict__ ee)
{
    const int k = blockIdx.x * 256 + threadIdx.x;  // grid(2) -> k < 512
    const float* __restrict__ cp = cb + (size_t)k * 64;
    float s = 0.0f;
#pragma unroll
    for (int i = 0; i < 64; i++) s = fmaf(cp[i], cp[i], s);
    ee[k] = s;
}

// GEMM-form conv (validated R13) — still used by e1 and pre.
template<int CTOT, int CPB, int CIN, int K, int S, int PAD,
         bool RELU_IN, bool HAS_BIAS, bool RESID, bool RELU_OUT>
__global__ __launch_bounds__(256) void conv_gemm(
    const float* __restrict__ in, const float* __restrict__ wr,
    const float* __restrict__ bias, const float* __restrict__ resid,
    float* __restrict__ out,
    int H, int W, int OH, int OW)
{
    constexpr int KK  = K * K;
    constexpr int CIC = (K == 1) ? 8 : 1;
    constexpr int TS  = (K == 4) ? 2 : 1;
    constexpr int KC  = CIC * KK / TS;
    constexpr int NCH = (CIN * TS) / CIC;
    constexpr int NT  = 256;
    constexpr int CPTHD = CPB / 4;
    __shared__ __align__(16) float As[2][KC * NT];

    const int tid = threadIdx.x;
    const int tpx = tid & 63;
    const int tco = __builtin_amdgcn_readfirstlane(tid >> 6);
    const int co0 = blockIdx.y * CPB + tco * CPTHD;

    const int ohow = OH * OW;
    const int n_st = blockIdx.x * NT + tid;
    const int b_st = n_st / ohow;
    const int hw_s = n_st % ohow;
    const int ih0 = (hw_s / OW) * S - PAD;
    const int iw0 = (hw_s % OW) * S - PAD;
    const float* __restrict__ inb = in + (size_t)b_st * CIN * H * W;

    float acc[CPTHD][4];
#pragma unroll
    for (int c = 0; c < CPTHD; c++) {
        const float bz = HAS_BIAS ? bias[co0 + c] : 0.0f;
#pragma unroll
        for (int q = 0; q < 4; q++) acc[c][q] = bz;
    }

    float pf[KC];
    auto stage_load = [&](int ch) {
#pragma unroll
        for (int t = 0; t < KC; t++) {
            int ci, kh, kw;
            if constexpr (K == 1) {
                ci = ch * 8 + t; kh = 0; kw = 0;
            } else if constexpr (K == 3) {
                ci = ch; kh = t / 3; kw = t % 3;
            } else {                                 // K == 4, TS = 2
                ci = ch >> 1;
                const int kk = ((ch & 1) << 3) + t;
                kh = kk >> 2; kw = kk & 3;
            }
            const int ih = ih0 + kh, iw = iw0 + kw;
            float v = 0.0f;
            if (ih >= 0 && ih < H && iw >= 0 && iw < W)
                v = inb[(size_t)ci * H * W + ih * W + iw];
            if (RELU_IN) v = fmaxf(v, 0.0f);
            pf[t] = v;
        }
    };

    stage_load(0);
#pragma unroll
    for (int t = 0; t < KC; t++) As[0][t * NT + tid] = pf[t];
    __syncthreads();

#pragma unroll 2
    for (int c = 0; c < NCH; c++) {
        const int cur = c & 1;
        if (c + 1 < NCH) stage_load(c + 1);

#pragma unroll
        for (int t = 0; t < KC; t++) {
            const float4 a4 = *(const float4*)(As[cur] + t * NT + tpx * 4);
            const float* __restrict__ wk =
                wr + (size_t)(c * KC + t) * CTOT + co0;
#pragma unroll
            for (int cc = 0; cc < CPTHD; cc++) {
                const float w = wk[cc];
                acc[cc][0] = fmaf(a4.x, w, acc[cc][0]);
                acc[cc][1] = fmaf(a4.y, w, acc[cc][1]);
                acc[cc][2] = fmaf(a4.z, w, acc[cc][2]);
                acc[cc][3] = fmaf(a4.w, w, acc[cc][3]);
            }
        }

        if (c + 1 < NCH) {
#pragma unroll
            for (int t = 0; t < KC; t++) As[1 - cur][t * NT + tid] = pf[t];
        }
        __syncthreads();
    }

    const int n_c  = blockIdx.x * NT + tpx * 4;
    const int b_c  = n_c / ohow;
    const int hw_c = n_c % ohow;
    float* __restrict__ op = out + (size_t)b_c * CTOT * ohow + hw_c;
    const float* __restrict__ rp =
        RESID ? (resid + (size_t)b_c * CTOT * ohow + hw_c) : nullptr;
#pragma unroll
    for (int c = 0; c < CPTHD; c++) {
        const size_t off = (size_t)(co0 + c) * ohow;
        float4 r = make_float4(acc[c][0], acc[c][1], acc[c][2], acc[c][3]);
        if (RESID) {
            const float4 rv = *(const float4*)(rp + off);
            r.x += rv.x; r.y += rv.y; r.z += rv.z; r.w += rv.w;
        }
        if (RELU_OUT) {
            r.x = fmaxf(r.x, 0.f); r.y = fmaxf(r.y, 0.f);
            r.z = fmaxf(r.z, 0.f); r.w = fmaxf(r.w, 0.f);
        }
        *(float4*)(op + off) = r;
    }
}

// Fused residual block, R19 "stage-once" v2 (validated).
__global__ __launch_bounds__(512, 4) void res_tile(
    const float* __restrict__ in, const float* __restrict__ wr1,
    const float* __restrict__ wr2, float* __restrict__ out)
{
    // tile: [ci<32][r6<6][72] floats = 13824 (54KB); mid[32][256] overlays.
    __shared__ __align__(16) float S[13824];

    const int tid = threadIdx.x;
    const int p   = tid & 127;                                  // px-pair
    const int cog = __builtin_amdgcn_readfirstlane(tid >> 7);   // 0..3
    const int a   = p >> 5;                // px row in block (0..3)
    const int c0  = (p & 31) * 2;          // px col base (0,2,..,62)

    const int n0   = blockIdx.x * 256;
    const int b    = n0 >> 12;
    const int row0 = (n0 & 4095) >> 6;     // 4 rows of 64
    const float* __restrict__ inb = in + (size_t)b * 64 * 4096;

    float4 pf4[7];
    auto stage_issue = [&](int half) {
#pragma unroll
        for (int m = 0; m < 7; m++) {
            const int f4 = m * 512 + tid;
            float4 v = make_float4(0.f, 0.f, 0.f, 0.f);
            if (f4 < 3456) {
                const int ci  = f4 / 108;            // 0..31
                const int rem = f4 - ci * 108;
                const int r6  = rem / 18;            // 0..5
                const int c4  = rem - r6 * 18;       // 0..17
                const int ih  = row0 + r6 - 1;
                if (ih >= 0 && ih < 64 && c4 >= 1 && c4 <= 16)
                    v = *(const float4*)(inb + (size_t)(half * 32 + ci) * 4096
                                         + ih * 64 + (c4 * 4 - 4));
            }
            pf4[m] = v;
        }
    };
    auto stage_commit = [&]() {
#pragma unroll
        for (int m = 0; m < 7; m++) {
            const int f4 = m * 512 + tid;
            if (f4 < 3456) {
                float4 v = pf4[m];
                v.x = fmaxf(v.x, 0.f); v.y = fmaxf(v.y, 0.f);
                v.z = fmaxf(v.z, 0.f); v.w = fmaxf(v.w, 0.f);
                *(float4*)(S + f4 * 4) = v;
            }
        }
    };

    const int co1 = cog * 8;
    float acc1[8][2];
#pragma unroll
    for (int c = 0; c < 8; c++) { acc1[c][0] = 0.0f; acc1[c][1] = 0.0f; }

    auto conv1_half = [&](int h) {
#pragma unroll 2
        for (int c = 0; c < 32; c++) {
            const float* __restrict__ wb =
                wr1 + (size_t)((h * 32 + c) * 9) * 32 + co1;
#pragma unroll
            for (int kh = 0; kh < 3; kh++) {
                const float* __restrict__ tp =
                    S + c * 432 + (a + kh) * 72 + 4 + c0;
                const float2 L = *(const float2*)(tp - 2);
                const float2 M = *(const float2*)(tp);
                const float2 R = *(const float2*)(tp + 2);
                const float xm = L.y;
                const float x0 = M.x;
                const float x1 = M.y;
                const float x2 = R.x;
                const float* __restrict__ wk = wb + (size_t)(kh * 3) * 32;
#pragma unroll
                for (int cc = 0; cc < 8; cc++) {     // kw = 0
                    const float w = wk[cc];
                    acc1[cc][0] = fmaf(xm, w, acc1[cc][0]);
                    acc1[cc][1] = fmaf(x0, w, acc1[cc][1]);
                }
#pragma unroll
                for (int cc = 0; cc < 8; cc++) {     // kw = 1
                    const float w = wk[32 + cc];
                    acc1[cc][0] = fmaf(x0, w, acc1[cc][0]);
                    acc1[cc][1] = fmaf(x1, w, acc1[cc][1]);
                }
#pragma unroll
                for (int cc = 0; cc < 8; cc++) {     // kw = 2
                    const float w = wk[64 + cc];
                    acc1[cc][0] = fmaf(x1, w, acc1[cc][0]);
                    acc1[cc][1] = fmaf(x2, w, acc1[cc][1]);
                }
            }
        }
    };

    stage_issue(0);
    stage_commit();
    __syncthreads();
    stage_issue(1);
    conv1_half(0);
    __syncthreads();
    stage_commit();
    __syncthreads();
    conv1_half(1);
    __syncthreads();

#pragma unroll
    for (int cc = 0; cc < 8; cc++)
        *(float2*)(S + (co1 + cc) * 256 + p * 2) =
            make_float2(acc1[cc][0], acc1[cc][1]);
    __syncthreads();

    const int co2 = cog * 16;
    float acc2[16][2];
#pragma unroll
    for (int c = 0; c < 16; c++) { acc2[c][0] = 0.0f; acc2[c][1] = 0.0f; }

#pragma unroll 4
    for (int k = 0; k < 32; k++) {
        float2 m2 = *(const float2*)(S + k * 256 + p * 2);
        m2.x = fmaxf(m2.x, 0.f);
        m2.y = fmaxf(m2.y, 0.f);
        const float* __restrict__ wk = wr2 + (size_t)k * 64 + co2;
#pragma unroll
        for (int cc = 0; cc < 16; cc++) {
            const float w = wk[cc];
            acc2[cc][0] = fmaf(m2.x, w, acc2[cc][0]);
            acc2[cc][1] = fmaf(m2.y, w, acc2[cc][1]);
        }
    }

    const int hw = (n0 & 4095) + p * 2;
    const float* __restrict__ rp = inb + hw;
    float* __restrict__ op = out + (size_t)b * 64 * 4096 + hw;
#pragma unroll
    for (int cc = 0; cc < 16; cc++) {
        const size_t off = (size_t)(co2 + cc) * 4096;
        const float2 rv = *(const float2*)(rp + off);
        *(float2*)(op + off) =
            make_float2(acc2[cc][0] + rv.x, acc2[cc][1] + rv.y);
    }
}

// R20: stage-once 3x3 conv 64ci->64co (d1). Structure = res_tile conv1 with
// 16 couts x 2 px/thread, bias init, no relu. Chain: bias, (ci,kh,kw) asc
// == conv_gemm<...,64,3,...> exactly. 3 barriers/block. grid 512.
__global__ __launch_bounds__(512, 4) void conv3_tile(
    const float* __restrict__ in, const float* __restrict__ wr,
    const float* __restrict__ bias, float* __restrict__ out)
{
    __shared__ __align__(16) float S[13824];   // [ci<32][6][72], 54KB

    const int tid = threadIdx.x;
    const int p   = tid & 127;
    const int cog = __builtin_amdgcn_readfirstlane(tid >> 7);   // 0..3
    const int a   = p >> 5;
    const int c0  = (p & 31) * 2;

    const int n0   = blockIdx.x * 256;
    const int b    = n0 >> 12;
    const int row0 = (n0 & 4095) >> 6;
    const float* __restrict__ inb = in + (size_t)b * 64 * 4096;

    float4 pf4[7];
    auto stage_issue = [&](int half) {
#pragma unroll
        for (int m = 0; m < 7; m++) {
            const int f4 = m * 512 + tid;
            float4 v = make_float4(0.f, 0.f, 0.f, 0.f);
            if (f4 < 3456) {
                const int ci  = f4 / 108;
                const int rem = f4 - ci * 108;
                const int r6  = rem / 18;
                const int c4  = rem - r6 * 18;
                const int ih  = row0 + r6 - 1;
                if (ih >= 0 && ih < 64 && c4 >= 1 && c4 <= 16)
                    v = *(const float4*)(inb + (size_t)(half * 32 + ci) * 4096
                                         + ih * 64 + (c4 * 4 - 4));
            }
            pf4[m] = v;
        }
    };
    auto stage_commit = [&]() {
#pragma unroll
        for (int m = 0; m < 7; m++) {
            const int f4 = m * 512 + tid;
            if (f4 < 3456) *(float4*)(S + f4 * 4) = pf4[m];   // no relu
        }
    };

    const int co1 = cog * 16;
    float acc[16][2];
#pragma unroll
    for (int cc = 0; cc < 16; cc++) {
        const float bz = bias[co1 + cc];
        acc[cc][0] = bz; acc[cc][1] = bz;
    }

    auto conv_half = [&](int h) {
#pragma unroll 2
        for (int c = 0; c < 32; c++) {
            const float* __restrict__ wb =
                wr + (size_t)((h * 32 + c) * 9) * 64 + co1;
#pragma unroll
            for (int kh = 0; kh < 3; kh++) {
                const float* __restrict__ tp =
                    S + c * 432 + (a + kh) * 72 + 4 + c0;
                const float2 L = *(const float2*)(tp - 2);
                const float2 M = *(const float2*)(tp);
                const float2 R = *(const float2*)(tp + 2);
                const float xm = L.y;
                const float x0 = M.x;
                const float x1 = M.y;
                const float x2 = R.x;
                const float* __restrict__ wk = wb + (size_t)(kh * 3) * 64;
#pragma unroll
                for (int cc = 0; cc < 16; cc++) {    // kw = 0
                    const float w = wk[cc];
                    acc[cc][0] = fmaf(xm, w, acc[cc][0]);
                    acc[cc][1] = fmaf(x0, w, acc[cc][1]);
                }
#pragma unroll
                for (int cc = 0; cc < 16; cc++) {    // kw = 1
                    const float w = wk[64 + cc];
                    acc[cc][0] = fmaf(x0, w, acc[cc][0]);
                    acc[cc][1] = fmaf(x1, w, acc[cc][1]);
                }
#pragma unroll
                for (int cc = 0; cc < 16; cc++) {    // kw = 2
                    const float w = wk[128 + cc];
                    acc[cc][0] = fmaf(x1, w, acc[cc][0]);
                    acc[cc][1] = fmaf(x2, w, acc[cc][1]);
                }
            }
        }
    };

    stage_issue(0);
    stage_commit();
    __syncthreads();
    stage_issue(1);
    conv_half(0);
    __syncthreads();
    stage_commit();
    __syncthreads();
    conv_half(1);

    const int hw = (n0 & 4095) + p * 2;
    float* __restrict__ op = out + (size_t)b * 64 * 4096 + hw;
#pragma unroll
    for (int cc = 0; cc < 16; cc++)
        *(float2*)(op + (size_t)(co1 + cc) * 4096) =
            make_float2(acc[cc][0], acc[cc][1]);
}

// R20: stage-once stride-2 4x4 conv 32ci->64co (e2), in 128x128 -> out 64x64.
// 128 out-px/block (2 rows x 64 cols); tile half = 16ci x 6rows x 136cols
// (51KB), idx = iw+4 (4-col zero pad each side), two halves with register
// prefetch. Thread: 8 couts x 2 px; per (ci,kh): 4 aligned ds_read_b64 ->
// x0..x5; out0 uses x[kw], out1 uses x[kw+2]. Chain: bias, (ci,kh,kw) asc
// == conv_gemm<...,32,4,2,1,...> exactly. grid 1024.
__global__ __launch_bounds__(512, 4) void conv4s2_tile(
    const float* __restrict__ in, const float* __restrict__ wr,
    const float* __restrict__ bias, float* __restrict__ out)
{
    __shared__ __align__(16) float S[13056];   // [ci<16][6][136], 51KB

    const int tid = threadIdx.x;
    const int p   = tid & 63;                                   // px-pair
    const int cog = __builtin_amdgcn_readfirstlane(tid >> 6);   // 0..7
    const int a   = p >> 5;                 // out row (0..1)
    const int c0  = (p & 31) * 2;           // out col base

    const int n0   = blockIdx.x * 128;
    const int b    = n0 >> 12;
    const int row0 = (n0 & 4095) >> 6;      // 2 out rows of 64
    const float* __restrict__ inb = in + (size_t)b * 32 * 16384;

    // staging: 16ci x 6r x 34 f4-slots = 3264 f4 per half; 7/thread guarded.
    // slot s: s in [1,32] loads global iw = (s-1)*4 (16B aligned); s=0/33 zero.
    float4 pf4[7];
    auto stage_issue = [&](int half) {
#pragma unroll
        for (int m = 0; m < 7; m++) {
            const int f4 = m * 512 + tid;
            float4 v = make_float4(0.f, 0.f, 0.f, 0.f);
            if (f4 < 3264) {
                const int ci  = f4 / 204;
                const int rem = f4 - ci * 204;
                const int r6  = rem / 34;
                const int s   = rem - r6 * 34;
                const int ih  = 2 * row0 - 1 + r6;
                if (ih >= 0 && ih < 128 && s >= 1 && s <= 32)
                    v = *(const float4*)(inb + (size_t)(half * 16 + ci) * 16384
                                         + ih * 128 + (s - 1) * 4);
            }
            pf4[m] = v;
        }
    };
    auto stage_commit = [&]() {
#pragma unroll
        for (int m = 0; m < 7; m++) {
            const int f4 = m * 512 + tid;
            if (f4 < 3264) *(float4*)(S + f4 * 4) = pf4[m];   // no relu
        }
    };

    const int co1 = cog * 8;
    float acc[8][2];
#pragma unroll
    for (int cc = 0; cc < 8; cc++) {
        const float bz = bias[co1 + cc];
        acc[cc][0] = bz; acc[cc][1] = bz;
    }

    auto conv_half = [&](int h) {
#pragma unroll 2
        for (int c = 0; c < 16; c++) {
            const float* __restrict__ wb =
                wr + (size_t)((h * 16 + c) * 16) * 64 + co1;
#pragma unroll
            for (int kh = 0; kh < 4; kh++) {
                // tile row r = 2a + kh (ih = 2(row0+a)-1+kh)
                const float* __restrict__ tp =
                    S + c * 816 + (2 * a + kh) * 136 + 2 * c0 + 2;
                const float2 E0 = *(const float2*)(tp);
                const float2 E1 = *(const float2*)(tp + 2);
                const float2 E2 = *(const float2*)(tp + 4);
                const float2 E3 = *(const float2*)(tp + 6);
                // idx = iw+4; x_j = word (2c0+3+j): out0 tap kw=j -> x_j,
                // out1 -> x_{j+2}
                const float x0 = E0.y, x1 = E1.x, x2 = E1.y;
                const float x3 = E2.x, x4 = E2.y, x5 = E3.x;
                const float* __restrict__ wk = wb + (size_t)(kh * 4) * 64;
#pragma unroll
                for (int cc = 0; cc < 8; cc++) {     // kw = 0
                    const float w = wk[cc];
                    acc[cc][0] = fmaf(x0, w, acc[cc][0]);
                    acc[cc][1] = fmaf(x2, w, acc[cc][1]);
                }
#pragma unroll
                for (int cc = 0; cc < 8; cc++) {     // kw = 1
                    const float w = wk[64 + cc];
                    acc[cc][0] = fmaf(x1, w, acc[cc][0]);
                    acc[cc][1] = fmaf(x3, w, acc[cc][1]);
                }
#pragma unroll
                for (int cc = 0; cc < 8; cc++) {     // kw = 2
                    const float w = wk[128 + cc];
                    acc[cc][0] = fmaf(x2, w, acc[cc][0]);
                    acc[cc][1] = fmaf(x4, w, acc[cc][1]);
                }
#pragma unroll
                for (int cc = 0; cc < 8; cc++) {     // kw = 3
                    const float w = wk[192 + cc];
                    acc[cc][0] = fmaf(x3, w, acc[cc][0]);
                    acc[cc][1] = fmaf(x5, w, acc[cc][1]);
                }
            }
        }
    };

    stage_issue(0);
    stage_commit();
    __syncthreads();
    stage_issue(1);
    conv_half(0);
    __syncthreads();
    stage_commit();
    __syncthreads();
    conv_half(1);

    const int hw = (n0 & 4095) + p * 2;
    float* __restrict__ op = out + (size_t)b * 64 * 4096 + hw;
#pragma unroll
    for (int cc = 0; cc < 8; cc++)
        *(float2*)(op + (size_t)(co1 + cc) * 4096) =
            make_float2(acc[cc][0], acc[cc][1]);
}

// t1 pc-merged GEMM (validated R15).
__global__ __launch_bounds__(256) void convt_gemm2(
    const float* __restrict__ in, const float* __restrict__ wr,
    const float* __restrict__ bias, float* __restrict__ out)
{
    constexpr int NT = 256;
    __shared__ __align__(16) float As[2][12 * NT];   // 24 KB

    const int tid = threadIdx.x;
    const int tpx = tid & 63;
    const int tco = __builtin_amdgcn_readfirstlane(tid >> 6);
    const int pr = blockIdx.y & 1;
    const int cg = blockIdx.y >> 1;
    const int co0 = cg * 16 + tco * 4;

    const int n_st = blockIdx.x * NT + tid;
    const int b = n_st >> 12;
    const int i_st = (n_st & 4095) >> 6;
    const int j_st = n_st & 63;
    const float* __restrict__ inb = in + (size_t)b * 64 * 4096;

    float acc[4][4][2];
#pragma unroll
    for (int c = 0; c < 4; c++) {
        const float bz = bias[co0 + c];
#pragma unroll
        for (int p = 0; p < 4; p++) {
            acc[c][p][0] = bz;
            acc[c][p][1] = bz;
        }
    }

    const float* __restrict__ wpr = wr + (size_t)pr * 128 * 4 * 32;

    float pf[12];
    auto stage_load = [&](int ch) {
#pragma unroll
        for (int t = 0; t < 4; t++) {
            const int k2 = ch * 4 + t;
            const int ci = k2 >> 1;
            const int ta = k2 & 1;
            const int ih = i_st + pr - ta;
            const bool rok = (ih >= 0) && (ih < 64);
            const float* __restrict__ row = inb + (size_t)ci * 4096 + ih * 64;
#pragma unroll
            for (int m = 0; m < 3; m++) {
                const int iw = j_st + m - 1;
                float v = 0.0f;
                if (rok && iw >= 0 && iw < 64) v = row[iw];
                pf[t * 3 + m] = v;
            }
        }
    };

    stage_load(0);
#pragma unroll
    for (int t = 0; t < 12; t++) As[0][t * NT + tid] = pf[t];
    __syncthreads();

#pragma unroll 2
    for (int ch = 0; ch < 32; ch++) {
        const int cur = ch & 1;
        if (ch + 1 < 32) stage_load(ch + 1);

#pragma unroll
        for (int t = 0; t < 4; t++) {
            float4 a[3];
#pragma unroll
            for (int m = 0; m < 3; m++)
                a[m] = *(const float4*)(As[cur] + (t * 3 + m) * NT + tpx * 4);
            const float* __restrict__ wk =
                wpr + (size_t)(ch * 4 + t) * 4 * 32 + co0;
#pragma unroll
            for (int tb = 0; tb < 2; tb++) {
#pragma unroll
                for (int pc = 0; pc < 2; pc++) {
                    const int q = pc * 2 + tb;
                    const int m = pc - tb + 1;
                    const float* __restrict__ wt = wk + q * 32;
                    const float vx = a[m].x, vy = a[m].y,
                                vz = a[m].z, vw = a[m].w;
#pragma unroll
                    for (int c = 0; c < 4; c++) {
                        const float w = wt[c];
                        acc[c][0][pc] = fmaf(vx, w, acc[c][0][pc]);
                        acc[c][1][pc] = fmaf(vy, w, acc[c][1][pc]);
                        acc[c][2][pc] = fmaf(vz, w, acc[c][2][pc]);
                        acc[c][3][pc] = fmaf(vw, w, acc[c][3][pc]);
                    }
                }
            }
        }

        if (ch + 1 < 32) {
#pragma unroll
            for (int t = 0; t < 12; t++) As[1 - cur][t * NT + tid] = pf[t];
        }
        __syncthreads();
    }

    const int n_c = blockIdx.x * NT + tpx * 4;
    const int i_c = (n_c & 4095) >> 6;
    const int j_c = n_c & 63;
    const int oh = 2 * i_c + pr;
    float* __restrict__ ob =
        out + (size_t)b * 32 * 16384 + (size_t)oh * 128 + 2 * j_c;
#pragma unroll
    for (int c = 0; c < 4; c++) {
        float* __restrict__ o = ob + (size_t)(co0 + c) * 16384;
        const float4 v0 = make_float4(
            fmaxf(acc[c][0][0], 0.f), fmaxf(acc[c][0][1], 0.f),
            fmaxf(acc[c][1][0], 0.f), fmaxf(acc[c][1][1], 0.f));
        const float4 v1 = make_float4(
            fmaxf(acc[c][2][0], 0.f), fmaxf(acc[c][2][1], 0.f),
            fmaxf(acc[c][3][0], 0.f), fmaxf(acc[c][3][1], 0.f));
        *(float4*)o = v0;
        *(float4*)(o + 4) = v1;
    }
}

// Final transposed conv (32 -> 1). (validated)
__global__ __launch_bounds__(256) void convt2_quad(
    const float* __restrict__ in, const float* __restrict__ w,
    const float* __restrict__ bias, float* __restrict__ out, int B)
{
    const int IH = 128, IW = 128, CIN = 32, OW = 256;
    const int j = threadIdx.x & 127;
    const int i = (blockIdx.x << 1) + (threadIdx.x >> 7);
    const int b = blockIdx.y;

    const float* __restrict__ inb = in + (size_t)b * CIN * IH * IW;
    const float bz = bias[0];
    float a00 = bz, a01 = bz, a10 = bz, a11 = bz;

    const bool okm = (i > 0);
    const bool okp = (i < IH - 1);
    const bool olm = (j > 0);
    const bool olp = (j < IW - 1);

#pragma unroll 4
    for (int ci = 0; ci < CIN; ci++) {
        const float* __restrict__ p = inb + ((size_t)ci * IH + i) * IW + j;
        const float* __restrict__ wp = w + ci * 16;
        const float vmm = (okm && olm) ? p[-IW - 1] : 0.f;
        const float vm0 = okm ? p[-IW] : 0.f;
        const float vmp = (okm && olp) ? p[-IW + 1] : 0.f;
        const float v0m = olm ? p[-1] : 0.f;
        const float v00 = p[0];
        const float v0p = olp ? p[1] : 0.f;
        const float vpm = (okp && olm) ? p[IW - 1] : 0.f;
        const float vp0 = okp ? p[IW] : 0.f;
        const float vpp = (okp && olp) ? p[IW + 1] : 0.f;
        a00 = fmaf(v00, wp[1 * 4 + 1], a00);
        a00 = fmaf(v0m, wp[1 * 4 + 3], a00);
        a00 = fmaf(vm0, wp[3 * 4 + 1], a00);
        a00 = fmaf(vmm, wp[3 * 4 + 3], a00);
        a01 = fmaf(v0p, wp[1 * 4 + 0], a01);
        a01 = fmaf(v00, wp[1 * 4 + 2], a01);
        a01 = fmaf(vmp, wp[3 * 4 + 0], a01);
        a01 = fmaf(vm0, wp[3 * 4 + 2], a01);
        a10 = fmaf(vp0, wp[0 * 4 + 1], a10);
        a10 = fmaf(vpm, wp[0 * 4 + 3], a10);
        a10 = fmaf(v00, wp[2 * 4 + 1], a10);
        a10 = fmaf(v0m, wp[2 * 4 + 3], a10);
        a11 = fmaf(vpp, wp[0 * 4 + 0], a11);
        a11 = fmaf(vp0, wp[0 * 4 + 2], a11);
        a11 = fmaf(v0p, wp[2 * 4 + 0], a11);
        a11 = fmaf(v00, wp[2 * 4 + 2], a11);
    }

    float* __restrict__ outb = out + (size_t)b * 256 * 256;
    ((float2*)(outb + (size_t)(2 * i) * OW))[j] = make_float2(a00, a01);
    ((float2*)(outb + (size_t)(2 * i + 1) * OW))[j] = make_float2(a10, a11);
}

// VQ-GEMM (validated R9). DO NOT reorder any fmaf chain (R3).
__global__ __launch_bounds__(256) void vq_gemm(
    const float* __restrict__ h,    // (32,64,4096)
    const float* __restrict__ cb,   // (512,64) row-major (gather)
    const float* __restrict__ cbT,  // (64,512) dim-major (matmul)
    const float* __restrict__ ee,   // (512)
    float* __restrict__ q)          // (32,64,4096)
{
    __shared__ __align__(16) float As[64 * 128];
    __shared__ float xx_sh[128];
    __shared__ float pd[4 * 128];
    __shared__ int   pk[4 * 128];
    __shared__ int   bidx_sh[128];

    const int tid = threadIdx.x;
    const int tpx = tid & 63;
    const int w = __builtin_amdgcn_readfirstlane(tid >> 6);
    const int n0 = blockIdx.x * 128;
    const int b  = n0 >> 12;
    const int hw0 = n0 & 4095;

    const float* __restrict__ hb = h + (size_t)b * 64 * 4096 + hw0;
#pragma unroll
    for (int m = 0; m < 32; m++) {
        const int idx = m * 256 + tid;
        const int k = idx >> 7, p = idx & 127;
        As[idx] = hb[(size_t)k * 4096 + p];
    }
    __syncthreads();

    if (tid < 128) {
        float s = 0.0f;
#pragma unroll
        for (int i = 0; i < 64; i++) {
            const float v = As[i * 128 + tid];
            s = fmaf(v, v, s);
        }
        xx_sh[tid] = s;
    }
    __syncthreads();

    const float xx0 = xx_sh[tpx * 2];
    const float xx1 = xx_sh[tpx * 2 + 1];
    const int cwave = w * 128;

    float best0 = 3.402823466e+38f, best1 = 3.402823466e+38f;
    int bk0 = 0, bk1 = 0;

#pragma unroll 1
    for (int ch = 0; ch < 16; ch++) {
        const int cbase = cwave + ch * 8;
        float acc[8][2];
#pragma unroll
        for (int c = 0; c < 8; c++) { acc[c][0] = 0.0f; acc[c][1] = 0.0f; }

#pragma unroll 8
        for (int k = 0; k < 64; k++) {
            const float2 a2 = *(const float2*)(As + k * 128 + tpx * 2);
            const float* __restrict__ wk = cbT + (size_t)k * 512 + cbase;
#pragma unroll
            for (int c = 0; c < 8; c++) {
                const float wv = wk[c];
                acc[c][0] = fmaf(a2.x, wv, acc[c][0]);
                acc[c][1] = fmaf(a2.y, wv, acc[c][1]);
            }
        }
        const float* __restrict__ eep = ee + cbase;
#pragma unroll
        for (int c = 0; c < 8; c++) {
            const float eec = eep[c];
            const float d0 = xx0 - 2.0f * acc[c][0] + eec;
            const float d1 = xx1 - 2.0f * acc[c][1] + eec;
            if (d0 < best0) { best0 = d0; bk0 = cbase + c; }
            if (d1 < best1) { best1 = d1; bk1 = cbase + c; }
        }
    }

    pd[w * 128 + tpx * 2]     = best0;
    pd[w * 128 + tpx * 2 + 1] = best1;
    pk[w * 128 + tpx * 2]     = bk0;
    pk[w * 128 + tpx * 2 + 1] = bk1;
    __syncthreads();

    if (tid < 128) {
        float bd = pd[tid]; int bk = pk[tid];
#pragma unroll
        for (int ww = 1; ww < 4; ww++) {
            const float od = pd[ww * 128 + tid];
            if (od < bd) { bd = od; bk = pk[ww * 128 + tid]; }
        }
        bidx_sh[tid] = bk;
    }
    __syncthreads();

    {
        const int p  = tid & 127;
        const int d0 = (tid >> 7) * 32;
        const int bk = bidx_sh[p];
        const float4* __restrict__ cp4 = (const float4*)(cb + (size_t)bk * 64 + d0);
        float* __restrict__ qb = q + ((size_t)b * 64 + d0) * 4096 + hw0 + p;
#pragma unroll
        for (int i = 0; i < 8; i++) {
            const float4 v = cp4[i];
            qb[(size_t)(4 * i + 0) * 4096] = v.x;
            qb[(size_t)(4 * i + 1) * 4096] = v.y;
            qb[(size_t)(4 * i + 2) * 4096] = v.z;
            qb[(size_t)(4 * i + 3) * 4096] = v.w;
        }
    }
}

extern "C" void kernel_launch(void* const* d_in, const int* in_sizes, int n_in,
                              void* d_out, int out_size, void* d_ws, size_t ws_size,
                              hipStream_t stream) {
    const float* x      = (const float*)d_in[0];
    const float* w_e1   = (const float*)d_in[1];
    const float* b_e1   = (const float*)d_in[2];
    const float* w_e2   = (const float*)d_in[3];
    const float* b_e2   = (const float*)d_in[4];
    const float* w_er1a = (const float*)d_in[5];
    const float* w_er1b = (const float*)d_in[6];
    const float* w_er2a = (const float*)d_in[7];
    const float* w_er2b = (const float*)d_in[8];
    const float* w_pre  = (const float*)d_in[9];
    const float* b_pre  = (const float*)d_in[10];
    const float* cbk    = (const float*)d_in[11];
    const float* w_d1   = (const float*)d_in[12];
    const float* b_d1   = (const float*)d_in[13];
    const float* w_dr1a = (const float*)d_in[14];
    const float* w_dr1b = (const float*)d_in[15];
    const float* w_dr2a = (const float*)d_in[16];
    const float* w_dr2b = (const float*)d_in[17];
    const float* w_t1   = (const float*)d_in[18];
    const float* b_t1   = (const float*)d_in[19];
    const float* w_t2   = (const float*)d_in[20];
    const float* b_t2   = (const float*)d_in[21];
    float* out = (float*)d_out;

    float* A  = (float*)d_ws;            // 16777216 floats (scratch + t1 out)
    float* Bb = A  + 16777216;           // (32,64,64,64) = 8388608
    float* C  = Bb + 8388608;            // 4194304 (unused after fusion)
    float* D  = C  + 4194304;            // (32,64,64,64) = 8388608
    float* WR = D  + 8388608;            // repacked weights + cbT (221696)
    float* EE = WR + 221696;             // ee (512)

    float* r_e1  = WR;
    float* r_e2  = WR + 512;
    float* r_er1a = WR + 33280;
    float* r_er1b = WR + 51712;
    float* r_er2a = WR + 53760;
    float* r_er2b = WR + 72192;
    float* r_pre = WR + 74240;
    float* r_d1  = WR + 78336;
    float* r_dr1a = WR + 115200;
    float* r_dr1b = WR + 133632;
    float* r_dr2a = WR + 135680;
    float* r_dr2b = WR + 154112;
    float* r_t1  = WR + 156160;
    float* r_cbT = WR + 188928;

    const dim3 blk(256);
    const dim3 blk512(512);

    repack_all<<<dim3(866), blk, 0, stream>>>(
        w_e1, w_e2, w_er1a, w_er1b, w_er2a, w_er2b, w_pre, w_d1,
        w_dr1a, w_dr1b, w_dr2a, w_dr2b, w_t1, cbk, WR);
    vq_prep_ee<<<dim3(2), blk, 0, stream>>>(cbk, EE);

    // Encoder
    conv_gemm<32, 32, 1, 4, 2, 1, false, true, false, true>
        <<<dim3(2048, 1), blk, 0, stream>>>(x, r_e1, b_e1, nullptr, A,
                                            256, 256, 128, 128);
    conv4s2_tile<<<dim3(1024), blk512, 0, stream>>>(A, r_e2, b_e2, Bb);
    // er1: Bb -> A ; er2: A -> Bb (ping-pong avoids in-place halo race)
    res_tile<<<dim3(512), blk512, 0, stream>>>(Bb, r_er1a, r_er1b, A);
    res_tile<<<dim3(512), blk512, 0, stream>>>(A, r_er2a, r_er2b, Bb);
    conv_gemm<64, 16, 64, 1, 1, 0, false, true, false, false>
        <<<dim3(512, 4), blk, 0, stream>>>(Bb, r_pre, b_pre, nullptr, D,
                                           64, 64, 64, 64);
    // VQ
    vq_gemm<<<dim3(1024), blk, 0, stream>>>(D, cbk, r_cbT, EE, Bb);
    // Decoder
    conv3_tile<<<dim3(512), blk512, 0, stream>>>(Bb, r_d1, b_d1, D);
    // dr1: D -> A ; dr2: A -> D
    res_tile<<<dim3(512), blk512, 0, stream>>>(D, r_dr1a, r_dr1b, A);
    res_tile<<<dim3(512), blk512, 0, stream>>>(A, r_dr2a, r_dr2b, D);
    // t1 (pc-merged, cout-split): grid (512, 2pr x 2cg)
    convt_gemm2<<<dim3(512, 4), blk, 0, stream>>>(D, r_t1, b_t1, A);
    // t2
    convt2_quad<<<dim3(64, 32), blk, 0, stream>>>(A, w_t2, b_t2, out, 32);
}

// Round 6
// 896.678 us; speedup vs baseline: 1.5566x; 1.0141x over previous
//
#include <hip/hip_runtime.h>
#include <hip/hip_bf16.h>

// ---------------------------------------------------------------------------
// VQ-VAE forward, fp32. NCHW.
// R21: stage-once ported to t1 (the last 2-barrier-per-chunk holdout,
// 150us at 2.7x its 54.6us FMA floor).
//   convt_tile: conv3_tile's staging verbatim (64ci x 6row x 72col, two
//   32-ch halves, register prefetch, 3 barriers, no relu). pr folded into
//   the block (both output-row parities per thread): per ci, 3 overlapping
//   4-float row-windows (9 ds_read_b64) feed 256 FMA. Thread tile
//   8co x 2px x 2pc x 2pr = 64 acc; __launch_bounds__(512,4) caps VGPR 128.
// Chain per output: bias, then (ci,ta,tb) lexicographic asc == convt_gemm2's
// k2-sweep exactly; same staged zeros; relu at write => bit-identical =>
// VQ-safe (R3). All other kernels byte-identical to R20.
// ---------------------------------------------------------------------------

__device__ __forceinline__ float rp_elem(const float* __restrict__ src,
                                         int i, int COUT, int CIN, int KK)
{
    const int co = i % COUT;
    const int t  = i / COUT;
    const int kk = t % KK;
    const int ci = t / KK;
    return src[(co * CIN + ci) * KK + kk];
}

// One kernel repacks all weights + codebook-transpose into WR.
__global__ __launch_bounds__(256) void repack_all(
    const float* __restrict__ e1,  const float* __restrict__ e2,
    const float* __restrict__ er1a, const float* __restrict__ er1b,
    const float* __restrict__ er2a, const float* __restrict__ er2b,
    const float* __restrict__ pre, const float* __restrict__ d1,
    const float* __restrict__ dr1a, const float* __restrict__ dr1b,
    const float* __restrict__ dr2a, const float* __restrict__ dr2b,
    const float* __restrict__ t1, const float* __restrict__ cb,
    float* __restrict__ WR)
{
    const int idx = blockIdx.x * 256 + threadIdx.x;
    if (idx >= 221696) return;
    float v;
    if      (idx < 512)    v = rp_elem(e1,   idx,          32,  1, 16);
    else if (idx < 33280)  v = rp_elem(e2,   idx - 512,    64, 32, 16);
    else if (idx < 51712)  v = rp_elem(er1a, idx - 33280,  32, 64,  9);
    else if (idx < 53760)  v = rp_elem(er1b, idx - 51712,  64, 32,  1);
    else if (idx < 72192)  v = rp_elem(er2a, idx - 53760,  32, 64,  9);
    else if (idx < 74240)  v = rp_elem(er2b, idx - 72192,  64, 32,  1);
    else if (idx < 78336)  v = rp_elem(pre,  idx - 74240,  64, 64,  1);
    else if (idx < 115200) v = rp_elem(d1,   idx - 78336,  64, 64,  9);
    else if (idx < 133632) v = rp_elem(dr1a, idx - 115200, 32, 64,  9);
    else if (idx < 135680) v = rp_elem(dr1b, idx - 133632, 64, 32,  1);
    else if (idx < 154112) v = rp_elem(dr2a, idx - 135680, 32, 64,  9);
    else if (idx < 156160) v = rp_elem(dr2b, idx - 154112, 64, 32,  1);
    else if (idx < 188928) {
        // t1: [pr][k2=ci*2+ta][q=pc*2+tb][co]
        const int i  = idx - 156160;
        const int co = i & 31;
        const int q  = (i >> 5) & 3;
        const int k2 = (i >> 7) & 127;
        const int pr = i >> 14;
        const int pc = q >> 1, tb = q & 1;
        const int ci = k2 >> 1, ta = k2 & 1;
        const int kh = (1 - pr) + 2 * ta, kw = (1 - pc) + 2 * tb;
        v = t1[((ci * 32 + co) * 4 + kh) * 4 + kw];
    } else {
        const int i = idx - 188928;           // cbT: [dim][code]
        const int code = i & 511;
        const int dim  = i >> 9;
        v = cb[code * 64 + dim];
    }
    WR[idx] = v;
}

// ee[k] = sum_i cb[k][i]^2, exact ascending fmaf chain (matches reference).
__global__ __launch_bounds__(256) void vq_prep_ee(
    const float* __restrict__ cb, float* __restrict__ ee)
{
    const int k = blockIdx.x * 256 + threadIdx.x;  // grid(2) -> k < 512
    const float* __restrict__ cp = cb + (size_t)k * 64;
    float s = 0.0f;
#pragma unroll
    for (int i = 0; i < 64; i++) s = fmaf(cp[i], cp[i], s);
    ee[k] = s;
}

// GEMM-form conv (validated R13) — still used by e1 and pre.
template<int CTOT, int CPB, int CIN, int K, int S, int PAD,
         bool RELU_IN, bool HAS_BIAS, bool RESID, bool RELU_OUT>
__global__ __launch_bounds__(256) void conv_gemm(
    const float* __restrict__ in, const float* __restrict__ wr,
    const float* __restrict__ bias, const float* __restrict__ resid,
    float* __restrict__ out,
    int H, int W, int OH, int OW)
{
    constexpr int KK  = K * K;
    constexpr int CIC = (K == 1) ? 8 : 1;
    constexpr int TS  = (K == 4) ? 2 : 1;
    constexpr int KC  = CIC * KK / TS;
    constexpr int NCH = (CIN * TS) / CIC;
    constexpr int NT  = 256;
    constexpr int CPTHD = CPB / 4;
    __shared__ __align__(16) float As[2][KC * NT];

    const int tid = threadIdx.x;
    const int tpx = tid & 63;
    const int tco = __builtin_amdgcn_readfirstlane(tid >> 6);
    const int co0 = blockIdx.y * CPB + tco * CPTHD;

    const int ohow = OH * OW;
    const int n_st = blockIdx.x * NT + tid;
    const int b_st = n_st / ohow;
    const int hw_s = n_st % ohow;
    const int ih0 = (hw_s / OW) * S - PAD;
    const int iw0 = (hw_s % OW) * S - PAD;
    const float* __restrict__ inb = in + (size_t)b_st * CIN * H * W;

    float acc[CPTHD][4];
#pragma unroll
    for (int c = 0; c < CPTHD; c++) {
        const float bz = HAS_BIAS ? bias[co0 + c] : 0.0f;
#pragma unroll
        for (int q = 0; q < 4; q++) acc[c][q] = bz;
    }

    float pf[KC];
    auto stage_load = [&](int ch) {
#pragma unroll
        for (int t = 0; t < KC; t++) {
            int ci, kh, kw;
            if constexpr (K == 1) {
                ci = ch * 8 + t; kh = 0; kw = 0;
            } else if constexpr (K == 3) {
                ci = ch; kh = t / 3; kw = t % 3;
            } else {                                 // K == 4, TS = 2
                ci = ch >> 1;
                const int kk = ((ch & 1) << 3) + t;
                kh = kk >> 2; kw = kk & 3;
            }
            const int ih = ih0 + kh, iw = iw0 + kw;
            float v = 0.0f;
            if (ih >= 0 && ih < H && iw >= 0 && iw < W)
                v = inb[(size_t)ci * H * W + ih * W + iw];
            if (RELU_IN) v = fmaxf(v, 0.0f);
            pf[t] = v;
        }
    };

    stage_load(0);
#pragma unroll
    for (int t = 0; t < KC; t++) As[0][t * NT + tid] = pf[t];
    __syncthreads();

#pragma unroll 2
    for (int c = 0; c < NCH; c++) {
        const int cur = c & 1;
        if (c + 1 < NCH) stage_load(c + 1);

#pragma unroll
        for (int t = 0; t < KC; t++) {
            const float4 a4 = *(const float4*)(As[cur] + t * NT + tpx * 4);
            const float* __restrict__ wk =
                wr + (size_t)(c * KC + t) * CTOT + co0;
#pragma unroll
            for (int cc = 0; cc < CPTHD; cc++) {
                const float w = wk[cc];
                acc[cc][0] = fmaf(a4.x, w, acc[cc][0]);
                acc[cc][1] = fmaf(a4.y, w, acc[cc][1]);
                acc[cc][2] = fmaf(a4.z, w, acc[cc][2]);
                acc[cc][3] = fmaf(a4.w, w, acc[cc][3]);
            }
        }

        if (c + 1 < NCH) {
#pragma unroll
            for (int t = 0; t < KC; t++) As[1 - cur][t * NT + tid] = pf[t];
        }
        __syncthreads();
    }

    const int n_c  = blockIdx.x * NT + tpx * 4;
    const int b_c  = n_c / ohow;
    const int hw_c = n_c % ohow;
    float* __restrict__ op = out + (size_t)b_c * CTOT * ohow + hw_c;
    const float* __restrict__ rp =
        RESID ? (resid + (size_t)b_c * CTOT * ohow + hw_c) : nullptr;
#pragma unroll
    for (int c = 0; c < CPTHD; c++) {
        const size_t off = (size_t)(co0 + c) * ohow;
        float4 r = make_float4(acc[c][0], acc[c][1], acc[c][2], acc[c][3]);
        if (RESID) {
            const float4 rv = *(const float4*)(rp + off);
            r.x += rv.x; r.y += rv.y; r.z += rv.z; r.w += rv.w;
        }
        if (RELU_OUT) {
            r.x = fmaxf(r.x, 0.f); r.y = fmaxf(r.y, 0.f);
            r.z = fmaxf(r.z, 0.f); r.w = fmaxf(r.w, 0.f);
        }
        *(float4*)(op + off) = r;
    }
}

// Fused residual block, R19 "stage-once" v2 (validated).
__global__ __launch_bounds__(512, 4) void res_tile(
    const float* __restrict__ in, const float* __restrict__ wr1,
    const float* __restrict__ wr2, float* __restrict__ out)
{
    // tile: [ci<32][r6<6][72] floats = 13824 (54KB); mid[32][256] overlays.
    __shared__ __align__(16) float S[13824];

    const int tid = threadIdx.x;
    const int p   = tid & 127;                                  // px-pair
    const int cog = __builtin_amdgcn_readfirstlane(tid >> 7);   // 0..3
    const int a   = p >> 5;                // px row in block (0..3)
    const int c0  = (p & 31) * 2;          // px col base (0,2,..,62)

    const int n0   = blockIdx.x * 256;
    const int b    = n0 >> 12;
    const int row0 = (n0 & 4095) >> 6;     // 4 rows of 64
    const float* __restrict__ inb = in + (size_t)b * 64 * 4096;

    float4 pf4[7];
    auto stage_issue = [&](int half) {
#pragma unroll
        for (int m = 0; m < 7; m++) {
            const int f4 = m * 512 + tid;
            float4 v = make_float4(0.f, 0.f, 0.f, 0.f);
            if (f4 < 3456) {
                const int ci  = f4 / 108;            // 0..31
                const int rem = f4 - ci * 108;
                const int r6  = rem / 18;            // 0..5
                const int c4  = rem - r6 * 18;       // 0..17
                const int ih  = row0 + r6 - 1;
                if (ih >= 0 && ih < 64 && c4 >= 1 && c4 <= 16)
                    v = *(const float4*)(inb + (size_t)(half * 32 + ci) * 4096
                                         + ih * 64 + (c4 * 4 - 4));
            }
            pf4[m] = v;
        }
    };
    auto stage_commit = [&]() {
#pragma unroll
        for (int m = 0; m < 7; m++) {
            const int f4 = m * 512 + tid;
            if (f4 < 3456) {
                float4 v = pf4[m];
                v.x = fmaxf(v.x, 0.f); v.y = fmaxf(v.y, 0.f);
                v.z = fmaxf(v.z, 0.f); v.w = fmaxf(v.w, 0.f);
                *(float4*)(S + f4 * 4) = v;
            }
        }
    };

    const int co1 = cog * 8;
    float acc1[8][2];
#pragma unroll
    for (int c = 0; c < 8; c++) { acc1[c][0] = 0.0f; acc1[c][1] = 0.0f; }

    auto conv1_half = [&](int h) {
#pragma unroll 2
        for (int c = 0; c < 32; c++) {
            const float* __restrict__ wb =
                wr1 + (size_t)((h * 32 + c) * 9) * 32 + co1;
#pragma unroll
            for (int kh = 0; kh < 3; kh++) {
                const float* __restrict__ tp =
                    S + c * 432 + (a + kh) * 72 + 4 + c0;
                const float2 L = *(const float2*)(tp - 2);
                const float2 M = *(const float2*)(tp);
                const float2 R = *(const float2*)(tp + 2);
                const float xm = L.y;
                const float x0 = M.x;
                const float x1 = M.y;
                const float x2 = R.x;
                const float* __restrict__ wk = wb + (size_t)(kh * 3) * 32;
#pragma unroll
                for (int cc = 0; cc < 8; cc++) {     // kw = 0
                    const float w = wk[cc];
                    acc1[cc][0] = fmaf(xm, w, acc1[cc][0]);
                    acc1[cc][1] = fmaf(x0, w, acc1[cc][1]);
                }
#pragma unroll
                for (int cc = 0; cc < 8; cc++) {     // kw = 1
                    const float w = wk[32 + cc];
                    acc1[cc][0] = fmaf(x0, w, acc1[cc][0]);
                    acc1[cc][1] = fmaf(x1, w, acc1[cc][1]);
                }
#pragma unroll
                for (int cc = 0; cc < 8; cc++) {     // kw = 2
                    const float w = wk[64 + cc];
                    acc1[cc][0] = fmaf(x1, w, acc1[cc][0]);
                    acc1[cc][1] = fmaf(x2, w, acc1[cc][1]);
                }
            }
        }
    };

    stage_issue(0);
    stage_commit();
    __syncthreads();
    stage_issue(1);
    conv1_half(0);
    __syncthreads();
    stage_commit();
    __syncthreads();
    conv1_half(1);
    __syncthreads();

#pragma unroll
    for (int cc = 0; cc < 8; cc++)
        *(float2*)(S + (co1 + cc) * 256 + p * 2) =
            make_float2(acc1[cc][0], acc1[cc][1]);
    __syncthreads();

    const int co2 = cog * 16;
    float acc2[16][2];
#pragma unroll
    for (int c = 0; c < 16; c++) { acc2[c][0] = 0.0f; acc2[c][1] = 0.0f; }

#pragma unroll 4
    for (int k = 0; k < 32; k++) {
        float2 m2 = *(const float2*)(S + k * 256 + p * 2);
        m2.x = fmaxf(m2.x, 0.f);
        m2.y = fmaxf(m2.y, 0.f);
        const float* __restrict__ wk = wr2 + (size_t)k * 64 + co2;
#pragma unroll
        for (int cc = 0; cc < 16; cc++) {
            const float w = wk[cc];
            acc2[cc][0] = fmaf(m2.x, w, acc2[cc][0]);
            acc2[cc][1] = fmaf(m2.y, w, acc2[cc][1]);
        }
    }

    const int hw = (n0 & 4095) + p * 2;
    const float* __restrict__ rp = inb + hw;
    float* __restrict__ op = out + (size_t)b * 64 * 4096 + hw;
#pragma unroll
    for (int cc = 0; cc < 16; cc++) {
        const size_t off = (size_t)(co2 + cc) * 4096;
        const float2 rv = *(const float2*)(rp + off);
        *(float2*)(op + off) =
            make_float2(acc2[cc][0] + rv.x, acc2[cc][1] + rv.y);
    }
}

// R20: stage-once 3x3 conv 64ci->64co (d1). (validated)
__global__ __launch_bounds__(512, 4) void conv3_tile(
    const float* __restrict__ in, const float* __restrict__ wr,
    const float* __restrict__ bias, float* __restrict__ out)
{
    __shared__ __align__(16) float S[13824];   // [ci<32][6][72], 54KB

    const int tid = threadIdx.x;
    const int p   = tid & 127;
    const int cog = __builtin_amdgcn_readfirstlane(tid >> 7);   // 0..3
    const int a   = p >> 5;
    const int c0  = (p & 31) * 2;

    const int n0   = blockIdx.x * 256;
    const int b    = n0 >> 12;
    const int row0 = (n0 & 4095) >> 6;
    const float* __restrict__ inb = in + (size_t)b * 64 * 4096;

    float4 pf4[7];
    auto stage_issue = [&](int half) {
#pragma unroll
        for (int m = 0; m < 7; m++) {
            const int f4 = m * 512 + tid;
            float4 v = make_float4(0.f, 0.f, 0.f, 0.f);
            if (f4 < 3456) {
                const int ci  = f4 / 108;
                const int rem = f4 - ci * 108;
                const int r6  = rem / 18;
                const int c4  = rem - r6 * 18;
                const int ih  = row0 + r6 - 1;
                if (ih >= 0 && ih < 64 && c4 >= 1 && c4 <= 16)
                    v = *(const float4*)(inb + (size_t)(half * 32 + ci) * 4096
                                         + ih * 64 + (c4 * 4 - 4));
            }
            pf4[m] = v;
        }
    };
    auto stage_commit = [&]() {
#pragma unroll
        for (int m = 0; m < 7; m++) {
            const int f4 = m * 512 + tid;
            if (f4 < 3456) *(float4*)(S + f4 * 4) = pf4[m];   // no relu
        }
    };

    const int co1 = cog * 16;
    float acc[16][2];
#pragma unroll
    for (int cc = 0; cc < 16; cc++) {
        const float bz = bias[co1 + cc];
        acc[cc][0] = bz; acc[cc][1] = bz;
    }

    auto conv_half = [&](int h) {
#pragma unroll 2
        for (int c = 0; c < 32; c++) {
            const float* __restrict__ wb =
                wr + (size_t)((h * 32 + c) * 9) * 64 + co1;
#pragma unroll
            for (int kh = 0; kh < 3; kh++) {
                const float* __restrict__ tp =
                    S + c * 432 + (a + kh) * 72 + 4 + c0;
                const float2 L = *(const float2*)(tp - 2);
                const float2 M = *(const float2*)(tp);
                const float2 R = *(const float2*)(tp + 2);
                const float xm = L.y;
                const float x0 = M.x;
                const float x1 = M.y;
                const float x2 = R.x;
                const float* __restrict__ wk = wb + (size_t)(kh * 3) * 64;
#pragma unroll
                for (int cc = 0; cc < 16; cc++) {    // kw = 0
                    const float w = wk[cc];
                    acc[cc][0] = fmaf(xm, w, acc[cc][0]);
                    acc[cc][1] = fmaf(x0, w, acc[cc][1]);
                }
#pragma unroll
                for (int cc = 0; cc < 16; cc++) {    // kw = 1
                    const float w = wk[64 + cc];
                    acc[cc][0] = fmaf(x0, w, acc[cc][0]);
                    acc[cc][1] = fmaf(x1, w, acc[cc][1]);
                }
#pragma unroll
                for (int cc = 0; cc < 16; cc++) {    // kw = 2
                    const float w = wk[128 + cc];
                    acc[cc][0] = fmaf(x1, w, acc[cc][0]);
                    acc[cc][1] = fmaf(x2, w, acc[cc][1]);
                }
            }
        }
    };

    stage_issue(0);
    stage_commit();
    __syncthreads();
    stage_issue(1);
    conv_half(0);
    __syncthreads();
    stage_commit();
    __syncthreads();
    conv_half(1);

    const int hw = (n0 & 4095) + p * 2;
    float* __restrict__ op = out + (size_t)b * 64 * 4096 + hw;
#pragma unroll
    for (int cc = 0; cc < 16; cc++)
        *(float2*)(op + (size_t)(co1 + cc) * 4096) =
            make_float2(acc[cc][0], acc[cc][1]);
}

// R20: stage-once stride-2 4x4 conv 32ci->64co (e2). (validated)
__global__ __launch_bounds__(512, 4) void conv4s2_tile(
    const float* __restrict__ in, const float* __restrict__ wr,
    const float* __restrict__ bias, float* __restrict__ out)
{
    __shared__ __align__(16) float S[13056];   // [ci<16][6][136], 51KB

    const int tid = threadIdx.x;
    const int p   = tid & 63;                                   // px-pair
    const int cog = __builtin_amdgcn_readfirstlane(tid >> 6);   // 0..7
    const int a   = p >> 5;                 // out row (0..1)
    const int c0  = (p & 31) * 2;           // out col base

    const int n0   = blockIdx.x * 128;
    const int b    = n0 >> 12;
    const int row0 = (n0 & 4095) >> 6;      // 2 out rows of 64
    const float* __restrict__ inb = in + (size_t)b * 32 * 16384;

    float4 pf4[7];
    auto stage_issue = [&](int half) {
#pragma unroll
        for (int m = 0; m < 7; m++) {
            const int f4 = m * 512 + tid;
            float4 v = make_float4(0.f, 0.f, 0.f, 0.f);
            if (f4 < 3264) {
                const int ci  = f4 / 204;
                const int rem = f4 - ci * 204;
                const int r6  = rem / 34;
                const int s   = rem - r6 * 34;
                const int ih  = 2 * row0 - 1 + r6;
                if (ih >= 0 && ih < 128 && s >= 1 && s <= 32)
                    v = *(const float4*)(inb + (size_t)(half * 16 + ci) * 16384
                                         + ih * 128 + (s - 1) * 4);
            }
            pf4[m] = v;
        }
    };
    auto stage_commit = [&]() {
#pragma unroll
        for (int m = 0; m < 7; m++) {
            const int f4 = m * 512 + tid;
            if (f4 < 3264) *(float4*)(S + f4 * 4) = pf4[m];   // no relu
        }
    };

    const int co1 = cog * 8;
    float acc[8][2];
#pragma unroll
    for (int cc = 0; cc < 8; cc++) {
        const float bz = bias[co1 + cc];
        acc[cc][0] = bz; acc[cc][1] = bz;
    }

    auto conv_half = [&](int h) {
#pragma unroll 2
        for (int c = 0; c < 16; c++) {
            const float* __restrict__ wb =
                wr + (size_t)((h * 16 + c) * 16) * 64 + co1;
#pragma unroll
            for (int kh = 0; kh < 4; kh++) {
                const float* __restrict__ tp =
                    S + c * 816 + (2 * a + kh) * 136 + 2 * c0 + 2;
                const float2 E0 = *(const float2*)(tp);
                const float2 E1 = *(const float2*)(tp + 2);
                const float2 E2 = *(const float2*)(tp + 4);
                const float2 E3 = *(const float2*)(tp + 6);
                const float x0 = E0.y, x1 = E1.x, x2 = E1.y;
                const float x3 = E2.x, x4 = E2.y, x5 = E3.x;
                const float* __restrict__ wk = wb + (size_t)(kh * 4) * 64;
#pragma unroll
                for (int cc = 0; cc < 8; cc++) {     // kw = 0
                    const float w = wk[cc];
                    acc[cc][0] = fmaf(x0, w, acc[cc][0]);
                    acc[cc][1] = fmaf(x2, w, acc[cc][1]);
                }
#pragma unroll
                for (int cc = 0; cc < 8; cc++) {     // kw = 1
                    const float w = wk[64 + cc];
                    acc[cc][0] = fmaf(x1, w, acc[cc][0]);
                    acc[cc][1] = fmaf(x3, w, acc[cc][1]);
                }
#pragma unroll
                for (int cc = 0; cc < 8; cc++) {     // kw = 2
                    const float w = wk[128 + cc];
                    acc[cc][0] = fmaf(x2, w, acc[cc][0]);
                    acc[cc][1] = fmaf(x4, w, acc[cc][1]);
                }
#pragma unroll
                for (int cc = 0; cc < 8; cc++) {     // kw = 3
                    const float w = wk[192 + cc];
                    acc[cc][0] = fmaf(x3, w, acc[cc][0]);
                    acc[cc][1] = fmaf(x5, w, acc[cc][1]);
                }
            }
        }
    };

    stage_issue(0);
    stage_commit();
    __syncthreads();
    stage_issue(1);
    conv_half(0);
    __syncthreads();
    stage_commit();
    __syncthreads();
    conv_half(1);

    const int hw = (n0 & 4095) + p * 2;
    float* __restrict__ op = out + (size_t)b * 64 * 4096 + hw;
#pragma unroll
    for (int cc = 0; cc < 8; cc++)
        *(float2*)(op + (size_t)(co1 + cc) * 4096) =
            make_float2(acc[cc][0], acc[cc][1]);
}

// R21: stage-once transposed conv t1 (64ci -> 32co, k4 s2), in (64,64,64)
// -> out (32,128,128). Staging == conv3_tile (64ci x 6row x 72col, no relu).
// Both output-row parities (pr) computed in-block. Thread: 8co x 2px x
// 2pc x 2pr = 64 acc. Per ci: 3 overlapping 4-float row-windows (9 b64)
// -> 256 FMA. Chain per output: bias, (ci,ta,tb) asc == convt_gemm2.
__global__ __launch_bounds__(512, 4) void convt_tile(
    const float* __restrict__ in, const float* __restrict__ wr,
    const float* __restrict__ bias, float* __restrict__ out)
{
    __shared__ __align__(16) float S[13824];   // [ci<32][6][72], 54KB

    const int tid = threadIdx.x;
    const int p   = tid & 127;                                  // px-pair
    const int cog = __builtin_amdgcn_readfirstlane(tid >> 7);   // 0..3
    const int a   = p >> 5;                 // input row in block (0..3)
    const int c0  = (p & 31) * 2;           // input col base (0,2,..,62)

    const int n0   = blockIdx.x * 256;      // 256 input px = 4 rows
    const int b    = n0 >> 12;
    const int row0 = (n0 & 4095) >> 6;
    const float* __restrict__ inb = in + (size_t)b * 64 * 4096;

    float4 pf4[7];
    auto stage_issue = [&](int half) {
#pragma unroll
        for (int m = 0; m < 7; m++) {
            const int f4 = m * 512 + tid;
            float4 v = make_float4(0.f, 0.f, 0.f, 0.f);
            if (f4 < 3456) {
                const int ci  = f4 / 108;
                const int rem = f4 - ci * 108;
                const int r6  = rem / 18;
                const int c4  = rem - r6 * 18;
                const int ih  = row0 + r6 - 1;
                if (ih >= 0 && ih < 64 && c4 >= 1 && c4 <= 16)
                    v = *(const float4*)(inb + (size_t)(half * 32 + ci) * 4096
                                         + ih * 64 + (c4 * 4 - 4));
            }
            pf4[m] = v;
        }
    };
    auto stage_commit = [&]() {
#pragma unroll
        for (int m = 0; m < 7; m++) {
            const int f4 = m * 512 + tid;
            if (f4 < 3456) *(float4*)(S + f4 * 4) = pf4[m];   // no relu
        }
    };

    const int co1 = cog * 8;
    // acc[co][px][pc][pr]
    float acc[8][2][2][2];
#pragma unroll
    for (int cc = 0; cc < 8; cc++) {
        const float bz = bias[co1 + cc];
#pragma unroll
        for (int px = 0; px < 2; px++)
#pragma unroll
            for (int pc = 0; pc < 2; pc++) {
                acc[cc][px][pc][0] = bz;
                acc[cc][px][pc][1] = bz;
            }
    }

    auto conv_half = [&](int h) {
#pragma unroll 2
        for (int c = 0; c < 32; c++) {
            const int ci = h * 32 + c;
            // 3 row-windows: X[r] = cols (c0-1..c0+2) of tile row (a+r)
            float X[3][4];
#pragma unroll
            for (int r = 0; r < 3; r++) {
                const float* __restrict__ tp =
                    S + c * 432 + (a + r) * 72 + 4 + c0;
                const float2 L = *(const float2*)(tp - 2);
                const float2 M = *(const float2*)(tp);
                const float2 R = *(const float2*)(tp + 2);
                X[r][0] = L.y; X[r][1] = M.x; X[r][2] = M.y; X[r][3] = R.x;
            }
            const float* __restrict__ wb = wr + (size_t)(ci * 2) * 128 + co1;
#pragma unroll
            for (int ta = 0; ta < 2; ta++) {
                // pr=0 reads input row i-ta   -> tile row a+1-ta -> X[1-ta]
                // pr=1 reads input row i+1-ta -> tile row a+2-ta -> X[2-ta]
                const float* X0 = X[1 - ta];
                const float* X1 = X[2 - ta];
                const float* __restrict__ wt = wb + ta * 128;
#pragma unroll
                for (int tb = 0; tb < 2; tb++) {
#pragma unroll
                    for (int pc = 0; pc < 2; pc++) {
                        const int m = pc - tb + 1;   // 0..2
                        const float* __restrict__ w0 = wt + (pc * 2 + tb) * 32;
                        const float* __restrict__ w1 = w0 + 16384;
#pragma unroll
                        for (int cc = 0; cc < 8; cc++) {
                            const float wv0 = w0[cc];
                            const float wv1 = w1[cc];
                            acc[cc][0][pc][0] =
                                fmaf(X0[m],     wv0, acc[cc][0][pc][0]);
                            acc[cc][1][pc][0] =
                                fmaf(X0[m + 1], wv0, acc[cc][1][pc][0]);
                            acc[cc][0][pc][1] =
                                fmaf(X1[m],     wv1, acc[cc][0][pc][1]);
                            acc[cc][1][pc][1] =
                                fmaf(X1[m + 1], wv1, acc[cc][1][pc][1]);
                        }
                    }
                }
            }
        }
    };

    stage_issue(0);
    stage_commit();
    __syncthreads();
    stage_issue(1);
    conv_half(0);
    __syncthreads();
    stage_commit();
    __syncthreads();
    conv_half(1);

    // write: oh = 2*(row0+a)+pr, ow = 2*c0 .. 2*c0+3 (px0pc0,px0pc1,px1pc0,px1pc1)
    const int i = row0 + a;
    float* __restrict__ ob =
        out + (size_t)b * 32 * 16384 + (size_t)(2 * i) * 128 + 2 * c0;
#pragma unroll
    for (int cc = 0; cc < 8; cc++) {
        float* __restrict__ o = ob + (size_t)(co1 + cc) * 16384;
#pragma unroll
        for (int pr = 0; pr < 2; pr++) {
            const float4 v = make_float4(
                fmaxf(acc[cc][0][0][pr], 0.f), fmaxf(acc[cc][0][1][pr], 0.f),
                fmaxf(acc[cc][1][0][pr], 0.f), fmaxf(acc[cc][1][1][pr], 0.f));
            *(float4*)(o + (size_t)pr * 128) = v;
        }
    }
}

// Final transposed conv (32 -> 1). (validated)
__global__ __launch_bounds__(256) void convt2_quad(
    const float* __restrict__ in, const float* __restrict__ w,
    const float* __restrict__ bias, float* __restrict__ out, int B)
{
    const int IH = 128, IW = 128, CIN = 32, OW = 256;
    const int j = threadIdx.x & 127;
    const int i = (blockIdx.x << 1) + (threadIdx.x >> 7);
    const int b = blockIdx.y;

    const float* __restrict__ inb = in + (size_t)b * CIN * IH * IW;
    const float bz = bias[0];
    float a00 = bz, a01 = bz, a10 = bz, a11 = bz;

    const bool okm = (i > 0);
    const bool okp = (i < IH - 1);
    const bool olm = (j > 0);
    const bool olp = (j < IW - 1);

#pragma unroll 4
    for (int ci = 0; ci < CIN; ci++) {
        const float* __restrict__ p = inb + ((size_t)ci * IH + i) * IW + j;
        const float* __restrict__ wp = w + ci * 16;
        const float vmm = (okm && olm) ? p[-IW - 1] : 0.f;
        const float vm0 = okm ? p[-IW] : 0.f;
        const float vmp = (okm && olp) ? p[-IW + 1] : 0.f;
        const float v0m = olm ? p[-1] : 0.f;
        const float v00 = p[0];
        const float v0p = olp ? p[1] : 0.f;
        const float vpm = (okp && olm) ? p[IW - 1] : 0.f;
        const float vp0 = okp ? p[IW] : 0.f;
        const float vpp = (okp && olp) ? p[IW + 1] : 0.f;
        a00 = fmaf(v00, wp[1 * 4 + 1], a00);
        a00 = fmaf(v0m, wp[1 * 4 + 3], a00);
        a00 = fmaf(vm0, wp[3 * 4 + 1], a00);
        a00 = fmaf(vmm, wp[3 * 4 + 3], a00);
        a01 = fmaf(v0p, wp[1 * 4 + 0], a01);
        a01 = fmaf(v00, wp[1 * 4 + 2], a01);
        a01 = fmaf(vmp, wp[3 * 4 + 0], a01);
        a01 = fmaf(vm0, wp[3 * 4 + 2], a01);
        a10 = fmaf(vp0, wp[0 * 4 + 1], a10);
        a10 = fmaf(vpm, wp[0 * 4 + 3], a10);
        a10 = fmaf(v00, wp[2 * 4 + 1], a10);
        a10 = fmaf(v0m, wp[2 * 4 + 3], a10);
        a11 = fmaf(vpp, wp[0 * 4 + 0], a11);
        a11 = fmaf(vp0, wp[0 * 4 + 2], a11);
        a11 = fmaf(v0p, wp[2 * 4 + 0], a11);
        a11 = fmaf(v00, wp[2 * 4 + 2], a11);
    }

    float* __restrict__ outb = out + (size_t)b * 256 * 256;
    ((float2*)(outb + (size_t)(2 * i) * OW))[j] = make_float2(a00, a01);
    ((float2*)(outb + (size_t)(2 * i + 1) * OW))[j] = make_float2(a10, a11);
}

// VQ-GEMM (validated R9). DO NOT reorder any fmaf chain (R3).
__global__ __launch_bounds__(256) void vq_gemm(
    const float* __restrict__ h,    // (32,64,4096)
    const float* __restrict__ cb,   // (512,64) row-major (gather)
    const float* __restrict__ cbT,  // (64,512) dim-major (matmul)
    const float* __restrict__ ee,   // (512)
    float* __restrict__ q)          // (32,64,4096)
{
    __shared__ __align__(16) float As[64 * 128];
    __shared__ float xx_sh[128];
    __shared__ float pd[4 * 128];
    __shared__ int   pk[4 * 128];
    __shared__ int   bidx_sh[128];

    const int tid = threadIdx.x;
    const int tpx = tid & 63;
    const int w = __builtin_amdgcn_readfirstlane(tid >> 6);
    const int n0 = blockIdx.x * 128;
    const int b  = n0 >> 12;
    const int hw0 = n0 & 4095;

    const float* __restrict__ hb = h + (size_t)b * 64 * 4096 + hw0;
#pragma unroll
    for (int m = 0; m < 32; m++) {
        const int idx = m * 256 + tid;
        const int k = idx >> 7, p = idx & 127;
        As[idx] = hb[(size_t)k * 4096 + p];
    }
    __syncthreads();

    if (tid < 128) {
        float s = 0.0f;
#pragma unroll
        for (int i = 0; i < 64; i++) {
            const float v = As[i * 128 + tid];
            s = fmaf(v, v, s);
        }
        xx_sh[tid] = s;
    }
    __syncthreads();

    const float xx0 = xx_sh[tpx * 2];
    const float xx1 = xx_sh[tpx * 2 + 1];
    const int cwave = w * 128;

    float best0 = 3.402823466e+38f, best1 = 3.402823466e+38f;
    int bk0 = 0, bk1 = 0;

#pragma unroll 1
    for (int ch = 0; ch < 16; ch++) {
        const int cbase = cwave + ch * 8;
        float acc[8][2];
#pragma unroll
        for (int c = 0; c < 8; c++) { acc[c][0] = 0.0f; acc[c][1] = 0.0f; }

#pragma unroll 8
        for (int k = 0; k < 64; k++) {
            const float2 a2 = *(const float2*)(As + k * 128 + tpx * 2);
            const float* __restrict__ wk = cbT + (size_t)k * 512 + cbase;
#pragma unroll
            for (int c = 0; c < 8; c++) {
                const float wv = wk[c];
                acc[c][0] = fmaf(a2.x, wv, acc[c][0]);
                acc[c][1] = fmaf(a2.y, wv, acc[c][1]);
            }
        }
        const float* __restrict__ eep = ee + cbase;
#pragma unroll
        for (int c = 0; c < 8; c++) {
            const float eec = eep[c];
            const float d0 = xx0 - 2.0f * acc[c][0] + eec;
            const float d1 = xx1 - 2.0f * acc[c][1] + eec;
            if (d0 < best0) { best0 = d0; bk0 = cbase + c; }
            if (d1 < best1) { best1 = d1; bk1 = cbase + c; }
        }
    }

    pd[w * 128 + tpx * 2]     = best0;
    pd[w * 128 + tpx * 2 + 1] = best1;
    pk[w * 128 + tpx * 2]     = bk0;
    pk[w * 128 + tpx * 2 + 1] = bk1;
    __syncthreads();

    if (tid < 128) {
        float bd = pd[tid]; int bk = pk[tid];
#pragma unroll
        for (int ww = 1; ww < 4; ww++) {
            const float od = pd[ww * 128 + tid];
            if (od < bd) { bd = od; bk = pk[ww * 128 + tid]; }
        }
        bidx_sh[tid] = bk;
    }
    __syncthreads();

    {
        const int p  = tid & 127;
        const int d0 = (tid >> 7) * 32;
        const int bk = bidx_sh[p];
        const float4* __restrict__ cp4 = (const float4*)(cb + (size_t)bk * 64 + d0);
        float* __restrict__ qb = q + ((size_t)b * 64 + d0) * 4096 + hw0 + p;
#pragma unroll
        for (int i = 0; i < 8; i++) {
            const float4 v = cp4[i];
            qb[(size_t)(4 * i + 0) * 4096] = v.x;
            qb[(size_t)(4 * i + 1) * 4096] = v.y;
            qb[(size_t)(4 * i + 2) * 4096] = v.z;
            qb[(size_t)(4 * i + 3) * 4096] = v.w;
        }
    }
}

extern "C" void kernel_launch(void* const* d_in, const int* in_sizes, int n_in,
                              void* d_out, int out_size, void* d_ws, size_t ws_size,
                              hipStream_t stream) {
    const float* x      = (const float*)d_in[0];
    const float* w_e1   = (const float*)d_in[1];
    const float* b_e1   = (const float*)d_in[2];
    const float* w_e2   = (const float*)d_in[3];
    const float* b_e2   = (const float*)d_in[4];
    const float* w_er1a = (const float*)d_in[5];
    const float* w_er1b = (const float*)d_in[6];
    const float* w_er2a = (const float*)d_in[7];
    const float* w_er2b = (const float*)d_in[8];
    const float* w_pre  = (const float*)d_in[9];
    const float* b_pre  = (const float*)d_in[10];
    const float* cbk    = (const float*)d_in[11];
    const float* w_d1   = (const float*)d_in[12];
    const float* b_d1   = (const float*)d_in[13];
    const float* w_dr1a = (const float*)d_in[14];
    const float* w_dr1b = (const float*)d_in[15];
    const float* w_dr2a = (const float*)d_in[16];
    const float* w_dr2b = (const float*)d_in[17];
    const float* w_t1   = (const float*)d_in[18];
    const float* b_t1   = (const float*)d_in[19];
    const float* w_t2   = (const float*)d_in[20];
    const float* b_t2   = (const float*)d_in[21];
    float* out = (float*)d_out;

    float* A  = (float*)d_ws;            // 16777216 floats (scratch + t1 out)
    float* Bb = A  + 16777216;           // (32,64,64,64) = 8388608
    float* C  = Bb + 8388608;            // 4194304 (unused after fusion)
    float* D  = C  + 4194304;            // (32,64,64,64) = 8388608
    float* WR = D  + 8388608;            // repacked weights + cbT (221696)
    float* EE = WR + 221696;             // ee (512)

    float* r_e1  = WR;
    float* r_e2  = WR + 512;
    float* r_er1a = WR + 33280;
    float* r_er1b = WR + 51712;
    float* r_er2a = WR + 53760;
    float* r_er2b = WR + 72192;
    float* r_pre = WR + 74240;
    float* r_d1  = WR + 78336;
    float* r_dr1a = WR + 115200;
    float* r_dr1b = WR + 133632;
    float* r_dr2a = WR + 135680;
    float* r_dr2b = WR + 154112;
    float* r_t1  = WR + 156160;
    float* r_cbT = WR + 188928;

    const dim3 blk(256);
    const dim3 blk512(512);

    repack_all<<<dim3(866), blk, 0, stream>>>(
        w_e1, w_e2, w_er1a, w_er1b, w_er2a, w_er2b, w_pre, w_d1,
        w_dr1a, w_dr1b, w_dr2a, w_dr2b, w_t1, cbk, WR);
    vq_prep_ee<<<dim3(2), blk, 0, stream>>>(cbk, EE);

    // Encoder
    conv_gemm<32, 32, 1, 4, 2, 1, false, true, false, true>
        <<<dim3(2048, 1), blk, 0, stream>>>(x, r_e1, b_e1, nullptr, A,
                                            256, 256, 128, 128);
    conv4s2_tile<<<dim3(1024), blk512, 0, stream>>>(A, r_e2, b_e2, Bb);
    // er1: Bb -> A ; er2: A -> Bb (ping-pong avoids in-place halo race)
    res_tile<<<dim3(512), blk512, 0, stream>>>(Bb, r_er1a, r_er1b, A);
    res_tile<<<dim3(512), blk512, 0, stream>>>(A, r_er2a, r_er2b, Bb);
    conv_gemm<64, 16, 64, 1, 1, 0, false, true, false, false>
        <<<dim3(512, 4), blk, 0, stream>>>(Bb, r_pre, b_pre, nullptr, D,
                                           64, 64, 64, 64);
    // VQ
    vq_gemm<<<dim3(1024), blk, 0, stream>>>(D, cbk, r_cbT, EE, Bb);
    // Decoder
    conv3_tile<<<dim3(512), blk512, 0, stream>>>(Bb, r_d1, b_d1, D);
    // dr1: D -> A ; dr2: A -> D
    res_tile<<<dim3(512), blk512, 0, stream>>>(D, r_dr1a, r_dr1b, A);
    res_tile<<<dim3(512), blk512, 0, stream>>>(A, r_dr2a, r_dr2b, D);
    // t1 stage-once: grid 512, both pr per block
    convt_tile<<<dim3(512), blk512, 0, stream>>>(D, r_t1, b_t1, A);
    // t2
    convt2_quad<<<dim3(64, 32), blk, 0, stream>>>(A, w_t2, b_t2, out, 32);
}

// Round 8
// 895.844 us; speedup vs baseline: 1.5580x; 1.0009x over previous
//
#include <hip/hip_runtime.h>
#include <hip/hip_bf16.h>

// ---------------------------------------------------------------------------
// VQ-VAE forward, fp32. NCHW.
// R23 = R22 resubmitted verbatim (R22 bench failed on container acquisition,
// not kernel error; diff audited for crash candidates - none).
//  (1) conv4s2_tile (e2, 140us, SQ_LDS_BANK_CONFLICT=3.15e7): the stride-2
//      conv makes lane col-stride 4 floats -> all 4 ds_read_b64 4-way
//      conflicted (50 LDS clk/step vs 128 VALU cyc -> LDS-bound). Fix:
//      1 aligned ds_read_b128 (16B/lane contiguous, conflict-free, x1..x4)
//      + 2 scalar b32 edge reads (x0,x5). Same floats -> chain identical.
//  (2) pre ported to stage-once conv1x1_tile (last old-structure conv,
//      ~75us vs 27us floor): [32ci][256px] 32KB halves, reg prefetch;
//      per ci: 1 free b64 -> 32 FMA. Chain = bias + ci asc == conv_gemm's
//      ch*8+t linearization -> bit-exact (R3: pre feeds VQ directly).
// All other kernels byte-identical to R21.
// ---------------------------------------------------------------------------

__device__ __forceinline__ float rp_elem(const float* __restrict__ src,
                                         int i, int COUT, int CIN, int KK)
{
    const int co = i % COUT;
    const int t  = i / COUT;
    const int kk = t % KK;
    const int ci = t / KK;
    return src[(co * CIN + ci) * KK + kk];
}

// One kernel repacks all weights + codebook-transpose into WR.
__global__ __launch_bounds__(256) void repack_all(
    const float* __restrict__ e1,  const float* __restrict__ e2,
    const float* __restrict__ er1a, const float* __restrict__ er1b,
    const float* __restrict__ er2a, const float* __restrict__ er2b,
    const float* __restrict__ pre, const float* __restrict__ d1,
    const float* __restrict__ dr1a, const float* __restrict__ dr1b,
    const float* __restrict__ dr2a, const float* __restrict__ dr2b,
    const float* __restrict__ t1, const float* __restrict__ cb,
    float* __restrict__ WR)
{
    const int idx = blockIdx.x * 256 + threadIdx.x;
    if (idx >= 221696) return;
    float v;
    if      (idx < 512)    v = rp_elem(e1,   idx,          32,  1, 16);
    else if (idx < 33280)  v = rp_elem(e2,   idx - 512,    64, 32, 16);
    else if (idx < 51712)  v = rp_elem(er1a, idx - 33280,  32, 64,  9);
    else if (idx < 53760)  v = rp_elem(er1b, idx - 51712,  64, 32,  1);
    else if (idx < 72192)  v = rp_elem(er2a, idx - 53760,  32, 64,  9);
    else if (idx < 74240)  v = rp_elem(er2b, idx - 72192,  64, 32,  1);
    else if (idx < 78336)  v = rp_elem(pre,  idx - 74240,  64, 64,  1);
    else if (idx < 115200) v = rp_elem(d1,   idx - 78336,  64, 64,  9);
    else if (idx < 133632) v = rp_elem(dr1a, idx - 115200, 32, 64,  9);
    else if (idx < 135680) v = rp_elem(dr1b, idx - 133632, 64, 32,  1);
    else if (idx < 154112) v = rp_elem(dr2a, idx - 135680, 32, 64,  9);
    else if (idx < 156160) v = rp_elem(dr2b, idx - 154112, 64, 32,  1);
    else if (idx < 188928) {
        // t1: [pr][k2=ci*2+ta][q=pc*2+tb][co]
        const int i  = idx - 156160;
        const int co = i & 31;
        const int q  = (i >> 5) & 3;
        const int k2 = (i >> 7) & 127;
        const int pr = i >> 14;
        const int pc = q >> 1, tb = q & 1;
        const int ci = k2 >> 1, ta = k2 & 1;
        const int kh = (1 - pr) + 2 * ta, kw = (1 - pc) + 2 * tb;
        v = t1[((ci * 32 + co) * 4 + kh) * 4 + kw];
    } else {
        const int i = idx - 188928;           // cbT: [dim][code]
        const int code = i & 511;
        const int dim  = i >> 9;
        v = cb[code * 64 + dim];
    }
    WR[idx] = v;
}

// ee[k] = sum_i cb[k][i]^2, exact ascending fmaf chain (matches reference).
__global__ __launch_bounds__(256) void vq_prep_ee(
    const float* __restrict__ cb, float* __restrict__ ee)
{
    const int k = blockIdx.x * 256 + threadIdx.x;  // grid(2) -> k < 512
    const float* __restrict__ cp = cb + (size_t)k * 64;
    float s = 0.0f;
#pragma unroll
    for (int i = 0; i < 64; i++) s = fmaf(cp[i], cp[i], s);
    ee[k] = s;
}

// GEMM-form conv (validated R13) — still used by e1.
template<int CTOT, int CPB, int CIN, int K, int S, int PAD,
         bool RELU_IN, bool HAS_BIAS, bool RESID, bool RELU_OUT>
__global__ __launch_bounds__(256) void conv_gemm(
    const float* __restrict__ in, const float* __restrict__ wr,
    const float* __restrict__ bias, const float* __restrict__ resid,
    float* __restrict__ out,
    int H, int W, int OH, int OW)
{
    constexpr int KK  = K * K;
    constexpr int CIC = (K == 1) ? 8 : 1;
    constexpr int TS  = (K == 4) ? 2 : 1;
    constexpr int KC  = CIC * KK / TS;
    constexpr int NCH = (CIN * TS) / CIC;
    constexpr int NT  = 256;
    constexpr int CPTHD = CPB / 4;
    __shared__ __align__(16) float As[2][KC * NT];

    const int tid = threadIdx.x;
    const int tpx = tid & 63;
    const int tco = __builtin_amdgcn_readfirstlane(tid >> 6);
    const int co0 = blockIdx.y * CPB + tco * CPTHD;

    const int ohow = OH * OW;
    const int n_st = blockIdx.x * NT + tid;
    const int b_st = n_st / ohow;
    const int hw_s = n_st % ohow;
    const int ih0 = (hw_s / OW) * S - PAD;
    const int iw0 = (hw_s % OW) * S - PAD;
    const float* __restrict__ inb = in + (size_t)b_st * CIN * H * W;

    float acc[CPTHD][4];
#pragma unroll
    for (int c = 0; c < CPTHD; c++) {
        const float bz = HAS_BIAS ? bias[co0 + c] : 0.0f;
#pragma unroll
        for (int q = 0; q < 4; q++) acc[c][q] = bz;
    }

    float pf[KC];
    auto stage_load = [&](int ch) {
#pragma unroll
        for (int t = 0; t < KC; t++) {
            int ci, kh, kw;
            if constexpr (K == 1) {
                ci = ch * 8 + t; kh = 0; kw = 0;
            } else if constexpr (K == 3) {
                ci = ch; kh = t / 3; kw = t % 3;
            } else {                                 // K == 4, TS = 2
                ci = ch >> 1;
                const int kk = ((ch & 1) << 3) + t;
                kh = kk >> 2; kw = kk & 3;
            }
            const int ih = ih0 + kh, iw = iw0 + kw;
            float v = 0.0f;
            if (ih >= 0 && ih < H && iw >= 0 && iw < W)
                v = inb[(size_t)ci * H * W + ih * W + iw];
            if (RELU_IN) v = fmaxf(v, 0.0f);
            pf[t] = v;
        }
    };

    stage_load(0);
#pragma unroll
    for (int t = 0; t < KC; t++) As[0][t * NT + tid] = pf[t];
    __syncthreads();

#pragma unroll 2
    for (int c = 0; c < NCH; c++) {
        const int cur = c & 1;
        if (c + 1 < NCH) stage_load(c + 1);

#pragma unroll
        for (int t = 0; t < KC; t++) {
            const float4 a4 = *(const float4*)(As[cur] + t * NT + tpx * 4);
            const float* __restrict__ wk =
                wr + (size_t)(c * KC + t) * CTOT + co0;
#pragma unroll
            for (int cc = 0; cc < CPTHD; cc++) {
                const float w = wk[cc];
                acc[cc][0] = fmaf(a4.x, w, acc[cc][0]);
                acc[cc][1] = fmaf(a4.y, w, acc[cc][1]);
                acc[cc][2] = fmaf(a4.z, w, acc[cc][2]);
                acc[cc][3] = fmaf(a4.w, w, acc[cc][3]);
            }
        }

        if (c + 1 < NCH) {
#pragma unroll
            for (int t = 0; t < KC; t++) As[1 - cur][t * NT + tid] = pf[t];
        }
        __syncthreads();
    }

    const int n_c  = blockIdx.x * NT + tpx * 4;
    const int b_c  = n_c / ohow;
    const int hw_c = n_c % ohow;
    float* __restrict__ op = out + (size_t)b_c * CTOT * ohow + hw_c;
    const float* __restrict__ rp =
        RESID ? (resid + (size_t)b_c * CTOT * ohow + hw_c) : nullptr;
#pragma unroll
    for (int c = 0; c < CPTHD; c++) {
        const size_t off = (size_t)(co0 + c) * ohow;
        float4 r = make_float4(acc[c][0], acc[c][1], acc[c][2], acc[c][3]);
        if (RESID) {
            const float4 rv = *(const float4*)(rp + off);
            r.x += rv.x; r.y += rv.y; r.z += rv.z; r.w += rv.w;
        }
        if (RELU_OUT) {
            r.x = fmaxf(r.x, 0.f); r.y = fmaxf(r.y, 0.f);
            r.z = fmaxf(r.z, 0.f); r.w = fmaxf(r.w, 0.f);
        }
        *(float4*)(op + off) = r;
    }
}

// Fused residual block, R19 "stage-once" v2 (validated).
__global__ __launch_bounds__(512, 4) void res_tile(
    const float* __restrict__ in, const float* __restrict__ wr1,
    const float* __restrict__ wr2, float* __restrict__ out)
{
    // tile: [ci<32][r6<6][72] floats = 13824 (54KB); mid[32][256] overlays.
    __shared__ __align__(16) float S[13824];

    const int tid = threadIdx.x;
    const int p   = tid & 127;                                  // px-pair
    const int cog = __builtin_amdgcn_readfirstlane(tid >> 7);   // 0..3
    const int a   = p >> 5;                // px row in block (0..3)
    const int c0  = (p & 31) * 2;          // px col base (0,2,..,62)

    const int n0   = blockIdx.x * 256;
    const int b    = n0 >> 12;
    const int row0 = (n0 & 4095) >> 6;     // 4 rows of 64
    const float* __restrict__ inb = in + (size_t)b * 64 * 4096;

    float4 pf4[7];
    auto stage_issue = [&](int half) {
#pragma unroll
        for (int m = 0; m < 7; m++) {
            const int f4 = m * 512 + tid;
            float4 v = make_float4(0.f, 0.f, 0.f, 0.f);
            if (f4 < 3456) {
                const int ci  = f4 / 108;            // 0..31
                const int rem = f4 - ci * 108;
                const int r6  = rem / 18;            // 0..5
                const int c4  = rem - r6 * 18;       // 0..17
                const int ih  = row0 + r6 - 1;
                if (ih >= 0 && ih < 64 && c4 >= 1 && c4 <= 16)
                    v = *(const float4*)(inb + (size_t)(half * 32 + ci) * 4096
                                         + ih * 64 + (c4 * 4 - 4));
            }
            pf4[m] = v;
        }
    };
    auto stage_commit = [&]() {
#pragma unroll
        for (int m = 0; m < 7; m++) {
            const int f4 = m * 512 + tid;
            if (f4 < 3456) {
                float4 v = pf4[m];
                v.x = fmaxf(v.x, 0.f); v.y = fmaxf(v.y, 0.f);
                v.z = fmaxf(v.z, 0.f); v.w = fmaxf(v.w, 0.f);
                *(float4*)(S + f4 * 4) = v;
            }
        }
    };

    const int co1 = cog * 8;
    float acc1[8][2];
#pragma unroll
    for (int c = 0; c < 8; c++) { acc1[c][0] = 0.0f; acc1[c][1] = 0.0f; }

    auto conv1_half = [&](int h) {
#pragma unroll 2
        for (int c = 0; c < 32; c++) {
            const float* __restrict__ wb =
                wr1 + (size_t)((h * 32 + c) * 9) * 32 + co1;
#pragma unroll
            for (int kh = 0; kh < 3; kh++) {
                const float* __restrict__ tp =
                    S + c * 432 + (a + kh) * 72 + 4 + c0;
                const float2 L = *(const float2*)(tp - 2);
                const float2 M = *(const float2*)(tp);
                const float2 R = *(const float2*)(tp + 2);
                const float xm = L.y;
                const float x0 = M.x;
                const float x1 = M.y;
                const float x2 = R.x;
                const float* __restrict__ wk = wb + (size_t)(kh * 3) * 32;
#pragma unroll
                for (int cc = 0; cc < 8; cc++) {     // kw = 0
                    const float w = wk[cc];
                    acc1[cc][0] = fmaf(xm, w, acc1[cc][0]);
                    acc1[cc][1] = fmaf(x0, w, acc1[cc][1]);
                }
#pragma unroll
                for (int cc = 0; cc < 8; cc++) {     // kw = 1
                    const float w = wk[32 + cc];
                    acc1[cc][0] = fmaf(x0, w, acc1[cc][0]);
                    acc1[cc][1] = fmaf(x1, w, acc1[cc][1]);
                }
#pragma unroll
                for (int cc = 0; cc < 8; cc++) {     // kw = 2
                    const float w = wk[64 + cc];
                    acc1[cc][0] = fmaf(x1, w, acc1[cc][0]);
                    acc1[cc][1] = fmaf(x2, w, acc1[cc][1]);
                }
            }
        }
    };

    stage_issue(0);
    stage_commit();
    __syncthreads();
    stage_issue(1);
    conv1_half(0);
    __syncthreads();
    stage_commit();
    __syncthreads();
    conv1_half(1);
    __syncthreads();

#pragma unroll
    for (int cc = 0; cc < 8; cc++)
        *(float2*)(S + (co1 + cc) * 256 + p * 2) =
            make_float2(acc1[cc][0], acc1[cc][1]);
    __syncthreads();

    const int co2 = cog * 16;
    float acc2[16][2];
#pragma unroll
    for (int c = 0; c < 16; c++) { acc2[c][0] = 0.0f; acc2[c][1] = 0.0f; }

#pragma unroll 4
    for (int k = 0; k < 32; k++) {
        float2 m2 = *(const float2*)(S + k * 256 + p * 2);
        m2.x = fmaxf(m2.x, 0.f);
        m2.y = fmaxf(m2.y, 0.f);
        const float* __restrict__ wk = wr2 + (size_t)k * 64 + co2;
#pragma unroll
        for (int cc = 0; cc < 16; cc++) {
            const float w = wk[cc];
            acc2[cc][0] = fmaf(m2.x, w, acc2[cc][0]);
            acc2[cc][1] = fmaf(m2.y, w, acc2[cc][1]);
        }
    }

    const int hw = (n0 & 4095) + p * 2;
    const float* __restrict__ rp = inb + hw;
    float* __restrict__ op = out + (size_t)b * 64 * 4096 + hw;
#pragma unroll
    for (int cc = 0; cc < 16; cc++) {
        const size_t off = (size_t)(co2 + cc) * 4096;
        const float2 rv = *(const float2*)(rp + off);
        *(float2*)(op + off) =
            make_float2(acc2[cc][0] + rv.x, acc2[cc][1] + rv.y);
    }
}

// R20: stage-once 3x3 conv 64ci->64co (d1). (validated)
__global__ __launch_bounds__(512, 4) void conv3_tile(
    const float* __restrict__ in, const float* __restrict__ wr,
    const float* __restrict__ bias, float* __restrict__ out)
{
    __shared__ __align__(16) float S[13824];   // [ci<32][6][72], 54KB

    const int tid = threadIdx.x;
    const int p   = tid & 127;
    const int cog = __builtin_amdgcn_readfirstlane(tid >> 7);   // 0..3
    const int a   = p >> 5;
    const int c0  = (p & 31) * 2;

    const int n0   = blockIdx.x * 256;
    const int b    = n0 >> 12;
    const int row0 = (n0 & 4095) >> 6;
    const float* __restrict__ inb = in + (size_t)b * 64 * 4096;

    float4 pf4[7];
    auto stage_issue = [&](int half) {
#pragma unroll
        for (int m = 0; m < 7; m++) {
            const int f4 = m * 512 + tid;
            float4 v = make_float4(0.f, 0.f, 0.f, 0.f);
            if (f4 < 3456) {
                const int ci  = f4 / 108;
                const int rem = f4 - ci * 108;
                const int r6  = rem / 18;
                const int c4  = rem - r6 * 18;
                const int ih  = row0 + r6 - 1;
                if (ih >= 0 && ih < 64 && c4 >= 1 && c4 <= 16)
                    v = *(const float4*)(inb + (size_t)(half * 32 + ci) * 4096
                                         + ih * 64 + (c4 * 4 - 4));
            }
            pf4[m] = v;
        }
    };
    auto stage_commit = [&]() {
#pragma unroll
        for (int m = 0; m < 7; m++) {
            const int f4 = m * 512 + tid;
            if (f4 < 3456) *(float4*)(S + f4 * 4) = pf4[m];   // no relu
        }
    };

    const int co1 = cog * 16;
    float acc[16][2];
#pragma unroll
    for (int cc = 0; cc < 16; cc++) {
        const float bz = bias[co1 + cc];
        acc[cc][0] = bz; acc[cc][1] = bz;
    }

    auto conv_half = [&](int h) {
#pragma unroll 2
        for (int c = 0; c < 32; c++) {
            const float* __restrict__ wb =
                wr + (size_t)((h * 32 + c) * 9) * 64 + co1;
#pragma unroll
            for (int kh = 0; kh < 3; kh++) {
                const float* __restrict__ tp =
                    S + c * 432 + (a + kh) * 72 + 4 + c0;
                const float2 L = *(const float2*)(tp - 2);
                const float2 M = *(const float2*)(tp);
                const float2 R = *(const float2*)(tp + 2);
                const float xm = L.y;
                const float x0 = M.x;
                const float x1 = M.y;
                const float x2 = R.x;
                const float* __restrict__ wk = wb + (size_t)(kh * 3) * 64;
#pragma unroll
                for (int cc = 0; cc < 16; cc++) {    // kw = 0
                    const float w = wk[cc];
                    acc[cc][0] = fmaf(xm, w, acc[cc][0]);
                    acc[cc][1] = fmaf(x0, w, acc[cc][1]);
                }
#pragma unroll
                for (int cc = 0; cc < 16; cc++) {    // kw = 1
                    const float w = wk[64 + cc];
                    acc[cc][0] = fmaf(x0, w, acc[cc][0]);
                    acc[cc][1] = fmaf(x1, w, acc[cc][1]);
                }
#pragma unroll
                for (int cc = 0; cc < 16; cc++) {    // kw = 2
                    const float w = wk[128 + cc];
                    acc[cc][0] = fmaf(x1, w, acc[cc][0]);
                    acc[cc][1] = fmaf(x2, w, acc[cc][1]);
                }
            }
        }
    };

    stage_issue(0);
    stage_commit();
    __syncthreads();
    stage_issue(1);
    conv_half(0);
    __syncthreads();
    stage_commit();
    __syncthreads();
    conv_half(1);

    const int hw = (n0 & 4095) + p * 2;
    float* __restrict__ op = out + (size_t)b * 64 * 4096 + hw;
#pragma unroll
    for (int cc = 0; cc < 16; cc++)
        *(float2*)(op + (size_t)(co1 + cc) * 4096) =
            make_float2(acc[cc][0], acc[cc][1]);
}

// R22: stage-once stride-2 4x4 conv 32ci->64co (e2). Read pattern fixed:
// 1 aligned ds_read_b128 (lane-contiguous 16B, conflict-free: x1..x4)
// + 2 scalar b32 edge reads (x0 at base+3, x5 at base+8). Same values as
// R20/R21's 4x b64 -> FMA chain bit-identical.
__global__ __launch_bounds__(512, 4) void conv4s2_tile(
    const float* __restrict__ in, const float* __restrict__ wr,
    const float* __restrict__ bias, float* __restrict__ out)
{
    __shared__ __align__(16) float S[13056];   // [ci<16][6][136], 51KB

    const int tid = threadIdx.x;
    const int p   = tid & 63;                                   // px-pair
    const int cog = __builtin_amdgcn_readfirstlane(tid >> 6);   // 0..7
    const int a   = p >> 5;                 // out row (0..1)
    const int c0  = (p & 31) * 2;           // out col base

    const int n0   = blockIdx.x * 128;
    const int b    = n0 >> 12;
    const int row0 = (n0 & 4095) >> 6;      // 2 out rows of 64
    const float* __restrict__ inb = in + (size_t)b * 32 * 16384;

    float4 pf4[7];
    auto stage_issue = [&](int half) {
#pragma unroll
        for (int m = 0; m < 7; m++) {
            const int f4 = m * 512 + tid;
            float4 v = make_float4(0.f, 0.f, 0.f, 0.f);
            if (f4 < 3264) {
                const int ci  = f4 / 204;
                const int rem = f4 - ci * 204;
                const int r6  = rem / 34;
                const int s   = rem - r6 * 34;
                const int ih  = 2 * row0 - 1 + r6;
                if (ih >= 0 && ih < 128 && s >= 1 && s <= 32)
                    v = *(const float4*)(inb + (size_t)(half * 16 + ci) * 16384
                                         + ih * 128 + (s - 1) * 4);
            }
            pf4[m] = v;
        }
    };
    auto stage_commit = [&]() {
#pragma unroll
        for (int m = 0; m < 7; m++) {
            const int f4 = m * 512 + tid;
            if (f4 < 3264) *(float4*)(S + f4 * 4) = pf4[m];   // no relu
        }
    };

    const int co1 = cog * 8;
    float acc[8][2];
#pragma unroll
    for (int cc = 0; cc < 8; cc++) {
        const float bz = bias[co1 + cc];
        acc[cc][0] = bz; acc[cc][1] = bz;
    }

    auto conv_half = [&](int h) {
#pragma unroll 2
        for (int c = 0; c < 16; c++) {
            const float* __restrict__ wb =
                wr + (size_t)((h * 16 + c) * 16) * 64 + co1;
#pragma unroll
            for (int kh = 0; kh < 4; kh++) {
                // base idx = 2*c0 (4-aligned); needed cols 2c0+3..2c0+8
                const float* __restrict__ base =
                    S + c * 816 + (2 * a + kh) * 136 + 2 * c0;
                const float4 Q = *(const float4*)(base + 4);  // x1..x4
                const float x0 = base[3];
                const float x5 = base[8];
                const float x1 = Q.x, x2 = Q.y, x3 = Q.z, x4 = Q.w;
                const float* __restrict__ wk = wb + (size_t)(kh * 4) * 64;
#pragma unroll
                for (int cc = 0; cc < 8; cc++) {     // kw = 0
                    const float w = wk[cc];
                    acc[cc][0] = fmaf(x0, w, acc[cc][0]);
                    acc[cc][1] = fmaf(x2, w, acc[cc][1]);
                }
#pragma unroll
                for (int cc = 0; cc < 8; cc++) {     // kw = 1
                    const float w = wk[64 + cc];
                    acc[cc][0] = fmaf(x1, w, acc[cc][0]);
                    acc[cc][1] = fmaf(x3, w, acc[cc][1]);
                }
#pragma unroll
                for (int cc = 0; cc < 8; cc++) {     // kw = 2
                    const float w = wk[128 + cc];
                    acc[cc][0] = fmaf(x2, w, acc[cc][0]);
                    acc[cc][1] = fmaf(x4, w, acc[cc][1]);
                }
#pragma unroll
                for (int cc = 0; cc < 8; cc++) {     // kw = 3
                    const float w = wk[192 + cc];
                    acc[cc][0] = fmaf(x3, w, acc[cc][0]);
                    acc[cc][1] = fmaf(x5, w, acc[cc][1]);
                }
            }
        }
    };

    stage_issue(0);
    stage_commit();
    __syncthreads();
    stage_issue(1);
    conv_half(0);
    __syncthreads();
    stage_commit();
    __syncthreads();
    conv_half(1);

    const int hw = (n0 & 4095) + p * 2;
    float* __restrict__ op = out + (size_t)b * 64 * 4096 + hw;
#pragma unroll
    for (int cc = 0; cc < 8; cc++)
        *(float2*)(op + (size_t)(co1 + cc) * 4096) =
            make_float2(acc[cc][0], acc[cc][1]);
}

// R22: stage-once 1x1 conv 64ci->64co (pre). No halo. [32ci][256px] 32KB
// halves, register prefetch. Thread: 16co x 2px; per ci: 1 free b64 read
// -> 32 FMA. Chain: bias, ci 0..63 asc == conv_gemm<...,64,1,...>'s
// ch*8+t linearization exactly => bit-identical (feeds VQ; R3).
__global__ __launch_bounds__(512, 4) void conv1x1_tile(
    const float* __restrict__ in, const float* __restrict__ wr,
    const float* __restrict__ bias, float* __restrict__ out)
{
    __shared__ __align__(16) float S[8192];    // [ci<32][256px], 32KB

    const int tid = threadIdx.x;
    const int p   = tid & 127;                                  // px-pair
    const int cog = __builtin_amdgcn_readfirstlane(tid >> 7);   // 0..3

    const int n0  = blockIdx.x * 256;
    const int b   = n0 >> 12;
    const int hw0 = n0 & 4095;
    const float* __restrict__ inb = in + (size_t)b * 64 * 4096 + hw0;

    float4 pf4[4];
    auto stage_issue = [&](int half) {
#pragma unroll
        for (int m = 0; m < 4; m++) {
            const int f4 = m * 512 + tid;        // 0..2047
            const int ci = f4 >> 6;
            const int c4 = f4 & 63;
            pf4[m] = *(const float4*)(inb + (size_t)(half * 32 + ci) * 4096
                                      + c4 * 4);
        }
    };
    auto stage_commit = [&]() {
#pragma unroll
        for (int m = 0; m < 4; m++) {
            const int f4 = m * 512 + tid;
            *(float4*)(S + f4 * 4) = pf4[m];
        }
    };

    const int co1 = cog * 16;
    float acc[16][2];
#pragma unroll
    for (int cc = 0; cc < 16; cc++) {
        const float bz = bias[co1 + cc];
        acc[cc][0] = bz; acc[cc][1] = bz;
    }

    auto conv_half = [&](int h) {
#pragma unroll 4
        for (int c = 0; c < 32; c++) {
            const float2 x = *(const float2*)(S + c * 256 + p * 2);
            const float* __restrict__ wk =
                wr + (size_t)(h * 32 + c) * 64 + co1;
#pragma unroll
            for (int cc = 0; cc < 16; cc++) {
                const float w = wk[cc];
                acc[cc][0] = fmaf(x.x, w, acc[cc][0]);
                acc[cc][1] = fmaf(x.y, w, acc[cc][1]);
            }
        }
    };

    stage_issue(0);
    stage_commit();
    __syncthreads();
    stage_issue(1);
    conv_half(0);
    __syncthreads();
    stage_commit();
    __syncthreads();
    conv_half(1);

    float* __restrict__ op = out + (size_t)b * 64 * 4096 + hw0 + p * 2;
#pragma unroll
    for (int cc = 0; cc < 16; cc++)
        *(float2*)(op + (size_t)(co1 + cc) * 4096) =
            make_float2(acc[cc][0], acc[cc][1]);
}

// R21: stage-once transposed conv t1 (validated).
__global__ __launch_bounds__(512, 4) void convt_tile(
    const float* __restrict__ in, const float* __restrict__ wr,
    const float* __restrict__ bias, float* __restrict__ out)
{
    __shared__ __align__(16) float S[13824];   // [ci<32][6][72], 54KB

    const int tid = threadIdx.x;
    const int p   = tid & 127;                                  // px-pair
    const int cog = __builtin_amdgcn_readfirstlane(tid >> 7);   // 0..3
    const int a   = p >> 5;                 // input row in block (0..3)
    const int c0  = (p & 31) * 2;           // input col base (0,2,..,62)

    const int n0   = blockIdx.x * 256;      // 256 input px = 4 rows
    const int b    = n0 >> 12;
    const int row0 = (n0 & 4095) >> 6;
    const float* __restrict__ inb = in + (size_t)b * 64 * 4096;

    float4 pf4[7];
    auto stage_issue = [&](int half) {
#pragma unroll
        for (int m = 0; m < 7; m++) {
            const int f4 = m * 512 + tid;
            float4 v = make_float4(0.f, 0.f, 0.f, 0.f);
            if (f4 < 3456) {
                const int ci  = f4 / 108;
                const int rem = f4 - ci * 108;
                const int r6  = rem / 18;
                const int c4  = rem - r6 * 18;
                const int ih  = row0 + r6 - 1;
                if (ih >= 0 && ih < 64 && c4 >= 1 && c4 <= 16)
                    v = *(const float4*)(inb + (size_t)(half * 32 + ci) * 4096
                                         + ih * 64 + (c4 * 4 - 4));
            }
            pf4[m] = v;
        }
    };
    auto stage_commit = [&]() {
#pragma unroll
        for (int m = 0; m < 7; m++) {
            const int f4 = m * 512 + tid;
            if (f4 < 3456) *(float4*)(S + f4 * 4) = pf4[m];   // no relu
        }
    };

    const int co1 = cog * 8;
    // acc[co][px][pc][pr]
    float acc[8][2][2][2];
#pragma unroll
    for (int cc = 0; cc < 8; cc++) {
        const float bz = bias[co1 + cc];
#pragma unroll
        for (int px = 0; px < 2; px++)
#pragma unroll
            for (int pc = 0; pc < 2; pc++) {
                acc[cc][px][pc][0] = bz;
                acc[cc][px][pc][1] = bz;
            }
    }

    auto conv_half = [&](int h) {
#pragma unroll 2
        for (int c = 0; c < 32; c++) {
            const int ci = h * 32 + c;
            float X[3][4];
#pragma unroll
            for (int r = 0; r < 3; r++) {
                const float* __restrict__ tp =
                    S + c * 432 + (a + r) * 72 + 4 + c0;
                const float2 L = *(const float2*)(tp - 2);
                const float2 M = *(const float2*)(tp);
                const float2 R = *(const float2*)(tp + 2);
                X[r][0] = L.y; X[r][1] = M.x; X[r][2] = M.y; X[r][3] = R.x;
            }
            const float* __restrict__ wb = wr + (size_t)(ci * 2) * 128 + co1;
#pragma unroll
            for (int ta = 0; ta < 2; ta++) {
                const float* X0 = X[1 - ta];
                const float* X1 = X[2 - ta];
                const float* __restrict__ wt = wb + ta * 128;
#pragma unroll
                for (int tb = 0; tb < 2; tb++) {
#pragma unroll
                    for (int pc = 0; pc < 2; pc++) {
                        const int m = pc - tb + 1;   // 0..2
                        const float* __restrict__ w0 = wt + (pc * 2 + tb) * 32;
                        const float* __restrict__ w1 = w0 + 16384;
#pragma unroll
                        for (int cc = 0; cc < 8; cc++) {
                            const float wv0 = w0[cc];
                            const float wv1 = w1[cc];
                            acc[cc][0][pc][0] =
                                fmaf(X0[m],     wv0, acc[cc][0][pc][0]);
                            acc[cc][1][pc][0] =
                                fmaf(X0[m + 1], wv0, acc[cc][1][pc][0]);
                            acc[cc][0][pc][1] =
                                fmaf(X1[m],     wv1, acc[cc][0][pc][1]);
                            acc[cc][1][pc][1] =
                                fmaf(X1[m + 1], wv1, acc[cc][1][pc][1]);
                        }
                    }
                }
            }
        }
    };

    stage_issue(0);
    stage_commit();
    __syncthreads();
    stage_issue(1);
    conv_half(0);
    __syncthreads();
    stage_commit();
    __syncthreads();
    conv_half(1);

    const int i = row0 + a;
    float* __restrict__ ob =
        out + (size_t)b * 32 * 16384 + (size_t)(2 * i) * 128 + 2 * c0;
#pragma unroll
    for (int cc = 0; cc < 8; cc++) {
        float* __restrict__ o = ob + (size_t)(co1 + cc) * 16384;
#pragma unroll
        for (int pr = 0; pr < 2; pr++) {
            const float4 v = make_float4(
                fmaxf(acc[cc][0][0][pr], 0.f), fmaxf(acc[cc][0][1][pr], 0.f),
                fmaxf(acc[cc][1][0][pr], 0.f), fmaxf(acc[cc][1][1][pr], 0.f));
            *(float4*)(o + (size_t)pr * 128) = v;
        }
    }
}

// Final transposed conv (32 -> 1). (validated)
__global__ __launch_bounds__(256) void convt2_quad(
    const float* __restrict__ in, const float* __restrict__ w,
    const float* __restrict__ bias, float* __restrict__ out, int B)
{
    const int IH = 128, IW = 128, CIN = 32, OW = 256;
    const int j = threadIdx.x & 127;
    const int i = (blockIdx.x << 1) + (threadIdx.x >> 7);
    const int b = blockIdx.y;

    const float* __restrict__ inb = in + (size_t)b * CIN * IH * IW;
    const float bz = bias[0];
    float a00 = bz, a01 = bz, a10 = bz, a11 = bz;

    const bool okm = (i > 0);
    const bool okp = (i < IH - 1);
    const bool olm = (j > 0);
    const bool olp = (j < IW - 1);

#pragma unroll 4
    for (int ci = 0; ci < CIN; ci++) {
        const float* __restrict__ p = inb + ((size_t)ci * IH + i) * IW + j;
        const float* __restrict__ wp = w + ci * 16;
        const float vmm = (okm && olm) ? p[-IW - 1] : 0.f;
        const float vm0 = okm ? p[-IW] : 0.f;
        const float vmp = (okm && olp) ? p[-IW + 1] : 0.f;
        const float v0m = olm ? p[-1] : 0.f;
        const float v00 = p[0];
        const float v0p = olp ? p[1] : 0.f;
        const float vpm = (okp && olm) ? p[IW - 1] : 0.f;
        const float vp0 = okp ? p[IW] : 0.f;
        const float vpp = (okp && olp) ? p[IW + 1] : 0.f;
        a00 = fmaf(v00, wp[1 * 4 + 1], a00);
        a00 = fmaf(v0m, wp[1 * 4 + 3], a00);
        a00 = fmaf(vm0, wp[3 * 4 + 1], a00);
        a00 = fmaf(vmm, wp[3 * 4 + 3], a00);
        a01 = fmaf(v0p, wp[1 * 4 + 0], a01);
        a01 = fmaf(v00, wp[1 * 4 + 2], a01);
        a01 = fmaf(vmp, wp[3 * 4 + 0], a01);
        a01 = fmaf(vm0, wp[3 * 4 + 2], a01);
        a10 = fmaf(vp0, wp[0 * 4 + 1], a10);
        a10 = fmaf(vpm, wp[0 * 4 + 3], a10);
        a10 = fmaf(v00, wp[2 * 4 + 1], a10);
        a10 = fmaf(v0m, wp[2 * 4 + 3], a10);
        a11 = fmaf(vpp, wp[0 * 4 + 0], a11);
        a11 = fmaf(vp0, wp[0 * 4 + 2], a11);
        a11 = fmaf(v0p, wp[2 * 4 + 0], a11);
        a11 = fmaf(v00, wp[2 * 4 + 2], a11);
    }

    float* __restrict__ outb = out + (size_t)b * 256 * 256;
    ((float2*)(outb + (size_t)(2 * i) * OW))[j] = make_float2(a00, a01);
    ((float2*)(outb + (size_t)(2 * i + 1) * OW))[j] = make_float2(a10, a11);
}

// VQ-GEMM (validated R9). DO NOT reorder any fmaf chain (R3).
__global__ __launch_bounds__(256) void vq_gemm(
    const float* __restrict__ h,    // (32,64,4096)
    const float* __restrict__ cb,   // (512,64) row-major (gather)
    const float* __restrict__ cbT,  // (64,512) dim-major (matmul)
    const float* __restrict__ ee,   // (512)
    float* __restrict__ q)          // (32,64,4096)
{
    __shared__ __align__(16) float As[64 * 128];
    __shared__ float xx_sh[128];
    __shared__ float pd[4 * 128];
    __shared__ int   pk[4 * 128];
    __shared__ int   bidx_sh[128];

    const int tid = threadIdx.x;
    const int tpx = tid & 63;
    const int w = __builtin_amdgcn_readfirstlane(tid >> 6);
    const int n0 = blockIdx.x * 128;
    const int b  = n0 >> 12;
    const int hw0 = n0 & 4095;

    const float* __restrict__ hb = h + (size_t)b * 64 * 4096 + hw0;
#pragma unroll
    for (int m = 0; m < 32; m++) {
        const int idx = m * 256 + tid;
        const int k = idx >> 7, p = idx & 127;
        As[idx] = hb[(size_t)k * 4096 + p];
    }
    __syncthreads();

    if (tid < 128) {
        float s = 0.0f;
#pragma unroll
        for (int i = 0; i < 64; i++) {
            const float v = As[i * 128 + tid];
            s = fmaf(v, v, s);
        }
        xx_sh[tid] = s;
    }
    __syncthreads();

    const float xx0 = xx_sh[tpx * 2];
    const float xx1 = xx_sh[tpx * 2 + 1];
    const int cwave = w * 128;

    float best0 = 3.402823466e+38f, best1 = 3.402823466e+38f;
    int bk0 = 0, bk1 = 0;

#pragma unroll 1
    for (int ch = 0; ch < 16; ch++) {
        const int cbase = cwave + ch * 8;
        float acc[8][2];
#pragma unroll
        for (int c = 0; c < 8; c++) { acc[c][0] = 0.0f; acc[c][1] = 0.0f; }

#pragma unroll 8
        for (int k = 0; k < 64; k++) {
            const float2 a2 = *(const float2*)(As + k * 128 + tpx * 2);
            const float* __restrict__ wk = cbT + (size_t)k * 512 + cbase;
#pragma unroll
            for (int c = 0; c < 8; c++) {
                const float wv = wk[c];
                acc[c][0] = fmaf(a2.x, wv, acc[c][0]);
                acc[c][1] = fmaf(a2.y, wv, acc[c][1]);
            }
        }
        const float* __restrict__ eep = ee + cbase;
#pragma unroll
        for (int c = 0; c < 8; c++) {
            const float eec = eep[c];
            const float d0 = xx0 - 2.0f * acc[c][0] + eec;
            const float d1 = xx1 - 2.0f * acc[c][1] + eec;
            if (d0 < best0) { best0 = d0; bk0 = cbase + c; }
            if (d1 < best1) { best1 = d1; bk1 = cbase + c; }
        }
    }

    pd[w * 128 + tpx * 2]     = best0;
    pd[w * 128 + tpx * 2 + 1] = best1;
    pk[w * 128 + tpx * 2]     = bk0;
    pk[w * 128 + tpx * 2 + 1] = bk1;
    __syncthreads();

    if (tid < 128) {
        float bd = pd[tid]; int bk = pk[tid];
#pragma unroll
        for (int ww = 1; ww < 4; ww++) {
            const float od = pd[ww * 128 + tid];
            if (od < bd) { bd = od; bk = pk[ww * 128 + tid]; }
        }
        bidx_sh[tid] = bk;
    }
    __syncthreads();

    {
        const int p  = tid & 127;
        const int d0 = (tid >> 7) * 32;
        const int bk = bidx_sh[p];
        const float4* __restrict__ cp4 = (const float4*)(cb + (size_t)bk * 64 + d0);
        float* __restrict__ qb = q + ((size_t)b * 64 + d0) * 4096 + hw0 + p;
#pragma unroll
        for (int i = 0; i < 8; i++) {
            const float4 v = cp4[i];
            qb[(size_t)(4 * i + 0) * 4096] = v.x;
            qb[(size_t)(4 * i + 1) * 4096] = v.y;
            qb[(size_t)(4 * i + 2) * 4096] = v.z;
            qb[(size_t)(4 * i + 3) * 4096] = v.w;
        }
    }
}

extern "C" void kernel_launch(void* const* d_in, const int* in_sizes, int n_in,
                              void* d_out, int out_size, void* d_ws, size_t ws_size,
                              hipStream_t stream) {
    const float* x      = (const float*)d_in[0];
    const float* w_e1   = (const float*)d_in[1];
    const float* b_e1   = (const float*)d_in[2];
    const float* w_e2   = (const float*)d_in[3];
    const float* b_e2   = (const float*)d_in[4];
    const float* w_er1a = (const float*)d_in[5];
    const float* w_er1b = (const float*)d_in[6];
    const float* w_er2a = (const float*)d_in[7];
    const float* w_er2b = (const float*)d_in[8];
    const float* w_pre  = (const float*)d_in[9];
    const float* b_pre  = (const float*)d_in[10];
    const float* cbk    = (const float*)d_in[11];
    const float* w_d1   = (const float*)d_in[12];
    const float* b_d1   = (const float*)d_in[13];
    const float* w_dr1a = (const float*)d_in[14];
    const float* w_dr1b = (const float*)d_in[15];
    const float* w_dr2a = (const float*)d_in[16];
    const float* w_dr2b = (const float*)d_in[17];
    const float* w_t1   = (const float*)d_in[18];
    const float* b_t1   = (const float*)d_in[19];
    const float* w_t2   = (const float*)d_in[20];
    const float* b_t2   = (const float*)d_in[21];
    float* out = (float*)d_out;

    float* A  = (float*)d_ws;            // 16777216 floats (scratch + t1 out)
    float* Bb = A  + 16777216;           // (32,64,64,64) = 8388608
    float* C  = Bb + 8388608;            // 4194304 (unused after fusion)
    float* D  = C  + 4194304;            // (32,64,64,64) = 8388608
    float* WR = D  + 8388608;            // repacked weights + cbT (221696)
    float* EE = WR + 221696;             // ee (512)

    float* r_e1  = WR;
    float* r_e2  = WR + 512;
    float* r_er1a = WR + 33280;
    float* r_er1b = WR + 51712;
    float* r_er2a = WR + 53760;
    float* r_er2b = WR + 72192;
    float* r_pre = WR + 74240;
    float* r_d1  = WR + 78336;
    float* r_dr1a = WR + 115200;
    float* r_dr1b = WR + 133632;
    float* r_dr2a = WR + 135680;
    float* r_dr2b = WR + 154112;
    float* r_t1  = WR + 156160;
    float* r_cbT = WR + 188928;

    const dim3 blk(256);
    const dim3 blk512(512);

    repack_all<<<dim3(866), blk, 0, stream>>>(
        w_e1, w_e2, w_er1a, w_er1b, w_er2a, w_er2b, w_pre, w_d1,
        w_dr1a, w_dr1b, w_dr2a, w_dr2b, w_t1, cbk, WR);
    vq_prep_ee<<<dim3(2), blk, 0, stream>>>(cbk, EE);

    // Encoder
    conv_gemm<32, 32, 1, 4, 2, 1, false, true, false, true>
        <<<dim3(2048, 1), blk, 0, stream>>>(x, r_e1, b_e1, nullptr, A,
                                            256, 256, 128, 128);
    conv4s2_tile<<<dim3(1024), blk512, 0, stream>>>(A, r_e2, b_e2, Bb);
    // er1: Bb -> A ; er2: A -> Bb (ping-pong avoids in-place halo race)
    res_tile<<<dim3(512), blk512, 0, stream>>>(Bb, r_er1a, r_er1b, A);
    res_tile<<<dim3(512), blk512, 0, stream>>>(A, r_er2a, r_er2b, Bb);
    // pre: stage-once 1x1
    conv1x1_tile<<<dim3(512), blk512, 0, stream>>>(Bb, r_pre, b_pre, D);
    // VQ
    vq_gemm<<<dim3(1024), blk, 0, stream>>>(D, cbk, r_cbT, EE, Bb);
    // Decoder
    conv3_tile<<<dim3(512), blk512, 0, stream>>>(Bb, r_d1, b_d1, D);
    // dr1: D -> A ; dr2: A -> D
    res_tile<<<dim3(512), blk512, 0, stream>>>(D, r_dr1a, r_dr1b, A);
    res_tile<<<dim3(512), blk512, 0, stream>>>(A, r_dr2a, r_dr2b, D);
    // t1 stage-once: grid 512, both pr per block
    convt_tile<<<dim3(512), blk512, 0, stream>>>(D, r_t1, b_t1, A);
    // t2
    convt2_quad<<<dim3(64, 32), blk, 0, stream>>>(A, w_t2, b_t2, out, 32);
}

// Round 9
// 887.491 us; speedup vs baseline: 1.5727x; 1.0094x over previous
//
#include <hip/hip_runtime.h>
#include <hip/hip_bf16.h>

// ---------------------------------------------------------------------------
// VQ-VAE forward, fp32. NCHW.
// R24: e2 lane-stride fix. R22/R23 falsified the "b128 is conflict-free"
// model: SQ_LDS_BANK_CONFLICT identical (3.146e7) for 4xb64 vs b128+2xb32
// at 16B lane stride. Revised model: LDS serves wide reads in per-dword
// passes; conflict set by LANE STRIDE alone (16B -> 4-way every pass;
// 8B -> 2-way = free, m136; matches res_tile/conv3_tile profile).
// conv4s2_tile now assigns each lane a SPLIT px pair {j, j+32} (input
// window stride 8B/lane): per (ci,kh) 6 aligned ds_read_b64 -> 64 FMA.
// Staging/barriers untouched; per-output chain (bias; ci,kh,kw asc; same
// zero-pads) unchanged => bit-exact => VQ argmin safe (R3).
// All other kernels byte-identical to R23.
// ---------------------------------------------------------------------------

__device__ __forceinline__ float rp_elem(const float* __restrict__ src,
                                         int i, int COUT, int CIN, int KK)
{
    const int co = i % COUT;
    const int t  = i / COUT;
    const int kk = t % KK;
    const int ci = t / KK;
    return src[(co * CIN + ci) * KK + kk];
}

// One kernel repacks all weights + codebook-transpose into WR.
__global__ __launch_bounds__(256) void repack_all(
    const float* __restrict__ e1,  const float* __restrict__ e2,
    const float* __restrict__ er1a, const float* __restrict__ er1b,
    const float* __restrict__ er2a, const float* __restrict__ er2b,
    const float* __restrict__ pre, const float* __restrict__ d1,
    const float* __restrict__ dr1a, const float* __restrict__ dr1b,
    const float* __restrict__ dr2a, const float* __restrict__ dr2b,
    const float* __restrict__ t1, const float* __restrict__ cb,
    float* __restrict__ WR)
{
    const int idx = blockIdx.x * 256 + threadIdx.x;
    if (idx >= 221696) return;
    float v;
    if      (idx < 512)    v = rp_elem(e1,   idx,          32,  1, 16);
    else if (idx < 33280)  v = rp_elem(e2,   idx - 512,    64, 32, 16);
    else if (idx < 51712)  v = rp_elem(er1a, idx - 33280,  32, 64,  9);
    else if (idx < 53760)  v = rp_elem(er1b, idx - 51712,  64, 32,  1);
    else if (idx < 72192)  v = rp_elem(er2a, idx - 53760,  32, 64,  9);
    else if (idx < 74240)  v = rp_elem(er2b, idx - 72192,  64, 32,  1);
    else if (idx < 78336)  v = rp_elem(pre,  idx - 74240,  64, 64,  1);
    else if (idx < 115200) v = rp_elem(d1,   idx - 78336,  64, 64,  9);
    else if (idx < 133632) v = rp_elem(dr1a, idx - 115200, 32, 64,  9);
    else if (idx < 135680) v = rp_elem(dr1b, idx - 133632, 64, 32,  1);
    else if (idx < 154112) v = rp_elem(dr2a, idx - 135680, 32, 64,  9);
    else if (idx < 156160) v = rp_elem(dr2b, idx - 154112, 64, 32,  1);
    else if (idx < 188928) {
        // t1: [pr][k2=ci*2+ta][q=pc*2+tb][co]
        const int i  = idx - 156160;
        const int co = i & 31;
        const int q  = (i >> 5) & 3;
        const int k2 = (i >> 7) & 127;
        const int pr = i >> 14;
        const int pc = q >> 1, tb = q & 1;
        const int ci = k2 >> 1, ta = k2 & 1;
        const int kh = (1 - pr) + 2 * ta, kw = (1 - pc) + 2 * tb;
        v = t1[((ci * 32 + co) * 4 + kh) * 4 + kw];
    } else {
        const int i = idx - 188928;           // cbT: [dim][code]
        const int code = i & 511;
        const int dim  = i >> 9;
        v = cb[code * 64 + dim];
    }
    WR[idx] = v;
}

// ee[k] = sum_i cb[k][i]^2, exact ascending fmaf chain (matches reference).
__global__ __launch_bounds__(256) void vq_prep_ee(
    const float* __restrict__ cb, float* __restrict__ ee)
{
    const int k = blockIdx.x * 256 + threadIdx.x;  // grid(2) -> k < 512
    const float* __restrict__ cp = cb + (size_t)k * 64;
    float s = 0.0f;
#pragma unroll
    for (int i = 0; i < 64; i++) s = fmaf(cp[i], cp[i], s);
    ee[k] = s;
}

// GEMM-form conv (validated R13) — still used by e1.
template<int CTOT, int CPB, int CIN, int K, int S, int PAD,
         bool RELU_IN, bool HAS_BIAS, bool RESID, bool RELU_OUT>
__global__ __launch_bounds__(256) void conv_gemm(
    const float* __restrict__ in, const float* __restrict__ wr,
    const float* __restrict__ bias, const float* __restrict__ resid,
    float* __restrict__ out,
    int H, int W, int OH, int OW)
{
    constexpr int KK  = K * K;
    constexpr int CIC = (K == 1) ? 8 : 1;
    constexpr int TS  = (K == 4) ? 2 : 1;
    constexpr int KC  = CIC * KK / TS;
    constexpr int NCH = (CIN * TS) / CIC;
    constexpr int NT  = 256;
    constexpr int CPTHD = CPB / 4;
    __shared__ __align__(16) float As[2][KC * NT];

    const int tid = threadIdx.x;
    const int tpx = tid & 63;
    const int tco = __builtin_amdgcn_readfirstlane(tid >> 6);
    const int co0 = blockIdx.y * CPB + tco * CPTHD;

    const int ohow = OH * OW;
    const int n_st = blockIdx.x * NT + tid;
    const int b_st = n_st / ohow;
    const int hw_s = n_st % ohow;
    const int ih0 = (hw_s / OW) * S - PAD;
    const int iw0 = (hw_s % OW) * S - PAD;
    const float* __restrict__ inb = in + (size_t)b_st * CIN * H * W;

    float acc[CPTHD][4];
#pragma unroll
    for (int c = 0; c < CPTHD; c++) {
        const float bz = HAS_BIAS ? bias[co0 + c] : 0.0f;
#pragma unroll
        for (int q = 0; q < 4; q++) acc[c][q] = bz;
    }

    float pf[KC];
    auto stage_load = [&](int ch) {
#pragma unroll
        for (int t = 0; t < KC; t++) {
            int ci, kh, kw;
            if constexpr (K == 1) {
                ci = ch * 8 + t; kh = 0; kw = 0;
            } else if constexpr (K == 3) {
                ci = ch; kh = t / 3; kw = t % 3;
            } else {                                 // K == 4, TS = 2
                ci = ch >> 1;
                const int kk = ((ch & 1) << 3) + t;
                kh = kk >> 2; kw = kk & 3;
            }
            const int ih = ih0 + kh, iw = iw0 + kw;
            float v = 0.0f;
            if (ih >= 0 && ih < H && iw >= 0 && iw < W)
                v = inb[(size_t)ci * H * W + ih * W + iw];
            if (RELU_IN) v = fmaxf(v, 0.0f);
            pf[t] = v;
        }
    };

    stage_load(0);
#pragma unroll
    for (int t = 0; t < KC; t++) As[0][t * NT + tid] = pf[t];
    __syncthreads();

#pragma unroll 2
    for (int c = 0; c < NCH; c++) {
        const int cur = c & 1;
        if (c + 1 < NCH) stage_load(c + 1);

#pragma unroll
        for (int t = 0; t < KC; t++) {
            const float4 a4 = *(const float4*)(As[cur] + t * NT + tpx * 4);
            const float* __restrict__ wk =
                wr + (size_t)(c * KC + t) * CTOT + co0;
#pragma unroll
            for (int cc = 0; cc < CPTHD; cc++) {
                const float w = wk[cc];
                acc[cc][0] = fmaf(a4.x, w, acc[cc][0]);
                acc[cc][1] = fmaf(a4.y, w, acc[cc][1]);
                acc[cc][2] = fmaf(a4.z, w, acc[cc][2]);
                acc[cc][3] = fmaf(a4.w, w, acc[cc][3]);
            }
        }

        if (c + 1 < NCH) {
#pragma unroll
            for (int t = 0; t < KC; t++) As[1 - cur][t * NT + tid] = pf[t];
        }
        __syncthreads();
    }

    const int n_c  = blockIdx.x * NT + tpx * 4;
    const int b_c  = n_c / ohow;
    const int hw_c = n_c % ohow;
    float* __restrict__ op = out + (size_t)b_c * CTOT * ohow + hw_c;
    const float* __restrict__ rp =
        RESID ? (resid + (size_t)b_c * CTOT * ohow + hw_c) : nullptr;
#pragma unroll
    for (int c = 0; c < CPTHD; c++) {
        const size_t off = (size_t)(co0 + c) * ohow;
        float4 r = make_float4(acc[c][0], acc[c][1], acc[c][2], acc[c][3]);
        if (RESID) {
            const float4 rv = *(const float4*)(rp + off);
            r.x += rv.x; r.y += rv.y; r.z += rv.z; r.w += rv.w;
        }
        if (RELU_OUT) {
            r.x = fmaxf(r.x, 0.f); r.y = fmaxf(r.y, 0.f);
            r.z = fmaxf(r.z, 0.f); r.w = fmaxf(r.w, 0.f);
        }
        *(float4*)(op + off) = r;
    }
}

// Fused residual block, R19 "stage-once" v2 (validated).
__global__ __launch_bounds__(512, 4) void res_tile(
    const float* __restrict__ in, const float* __restrict__ wr1,
    const float* __restrict__ wr2, float* __restrict__ out)
{
    // tile: [ci<32][r6<6][72] floats = 13824 (54KB); mid[32][256] overlays.
    __shared__ __align__(16) float S[13824];

    const int tid = threadIdx.x;
    const int p   = tid & 127;                                  // px-pair
    const int cog = __builtin_amdgcn_readfirstlane(tid >> 7);   // 0..3
    const int a   = p >> 5;                // px row in block (0..3)
    const int c0  = (p & 31) * 2;          // px col base (0,2,..,62)

    const int n0   = blockIdx.x * 256;
    const int b    = n0 >> 12;
    const int row0 = (n0 & 4095) >> 6;     // 4 rows of 64
    const float* __restrict__ inb = in + (size_t)b * 64 * 4096;

    float4 pf4[7];
    auto stage_issue = [&](int half) {
#pragma unroll
        for (int m = 0; m < 7; m++) {
            const int f4 = m * 512 + tid;
            float4 v = make_float4(0.f, 0.f, 0.f, 0.f);
            if (f4 < 3456) {
                const int ci  = f4 / 108;            // 0..31
                const int rem = f4 - ci * 108;
                const int r6  = rem / 18;            // 0..5
                const int c4  = rem - r6 * 18;       // 0..17
                const int ih  = row0 + r6 - 1;
                if (ih >= 0 && ih < 64 && c4 >= 1 && c4 <= 16)
                    v = *(const float4*)(inb + (size_t)(half * 32 + ci) * 4096
                                         + ih * 64 + (c4 * 4 - 4));
            }
            pf4[m] = v;
        }
    };
    auto stage_commit = [&]() {
#pragma unroll
        for (int m = 0; m < 7; m++) {
            const int f4 = m * 512 + tid;
            if (f4 < 3456) {
                float4 v = pf4[m];
                v.x = fmaxf(v.x, 0.f); v.y = fmaxf(v.y, 0.f);
                v.z = fmaxf(v.z, 0.f); v.w = fmaxf(v.w, 0.f);
                *(float4*)(S + f4 * 4) = v;
            }
        }
    };

    const int co1 = cog * 8;
    float acc1[8][2];
#pragma unroll
    for (int c = 0; c < 8; c++) { acc1[c][0] = 0.0f; acc1[c][1] = 0.0f; }

    auto conv1_half = [&](int h) {
#pragma unroll 2
        for (int c = 0; c < 32; c++) {
            const float* __restrict__ wb =
                wr1 + (size_t)((h * 32 + c) * 9) * 32 + co1;
#pragma unroll
            for (int kh = 0; kh < 3; kh++) {
                const float* __restrict__ tp =
                    S + c * 432 + (a + kh) * 72 + 4 + c0;
                const float2 L = *(const float2*)(tp - 2);
                const float2 M = *(const float2*)(tp);
                const float2 R = *(const float2*)(tp + 2);
                const float xm = L.y;
                const float x0 = M.x;
                const float x1 = M.y;
                const float x2 = R.x;
                const float* __restrict__ wk = wb + (size_t)(kh * 3) * 32;
#pragma unroll
                for (int cc = 0; cc < 8; cc++) {     // kw = 0
                    const float w = wk[cc];
                    acc1[cc][0] = fmaf(xm, w, acc1[cc][0]);
                    acc1[cc][1] = fmaf(x0, w, acc1[cc][1]);
                }
#pragma unroll
                for (int cc = 0; cc < 8; cc++) {     // kw = 1
                    const float w = wk[32 + cc];
                    acc1[cc][0] = fmaf(x0, w, acc1[cc][0]);
                    acc1[cc][1] = fmaf(x1, w, acc1[cc][1]);
                }
#pragma unroll
                for (int cc = 0; cc < 8; cc++) {     // kw = 2
                    const float w = wk[64 + cc];
                    acc1[cc][0] = fmaf(x1, w, acc1[cc][0]);
                    acc1[cc][1] = fmaf(x2, w, acc1[cc][1]);
                }
            }
        }
    };

    stage_issue(0);
    stage_commit();
    __syncthreads();
    stage_issue(1);
    conv1_half(0);
    __syncthreads();
    stage_commit();
    __syncthreads();
    conv1_half(1);
    __syncthreads();

#pragma unroll
    for (int cc = 0; cc < 8; cc++)
        *(float2*)(S + (co1 + cc) * 256 + p * 2) =
            make_float2(acc1[cc][0], acc1[cc][1]);
    __syncthreads();

    const int co2 = cog * 16;
    float acc2[16][2];
#pragma unroll
    for (int c = 0; c < 16; c++) { acc2[c][0] = 0.0f; acc2[c][1] = 0.0f; }

#pragma unroll 4
    for (int k = 0; k < 32; k++) {
        float2 m2 = *(const float2*)(S + k * 256 + p * 2);
        m2.x = fmaxf(m2.x, 0.f);
        m2.y = fmaxf(m2.y, 0.f);
        const float* __restrict__ wk = wr2 + (size_t)k * 64 + co2;
#pragma unroll
        for (int cc = 0; cc < 16; cc++) {
            const float w = wk[cc];
            acc2[cc][0] = fmaf(m2.x, w, acc2[cc][0]);
            acc2[cc][1] = fmaf(m2.y, w, acc2[cc][1]);
        }
    }

    const int hw = (n0 & 4095) + p * 2;
    const float* __restrict__ rp = inb + hw;
    float* __restrict__ op = out + (size_t)b * 64 * 4096 + hw;
#pragma unroll
    for (int cc = 0; cc < 16; cc++) {
        const size_t off = (size_t)(co2 + cc) * 4096;
        const float2 rv = *(const float2*)(rp + off);
        *(float2*)(op + off) =
            make_float2(acc2[cc][0] + rv.x, acc2[cc][1] + rv.y);
    }
}

// R20: stage-once 3x3 conv 64ci->64co (d1). (validated)
__global__ __launch_bounds__(512, 4) void conv3_tile(
    const float* __restrict__ in, const float* __restrict__ wr,
    const float* __restrict__ bias, float* __restrict__ out)
{
    __shared__ __align__(16) float S[13824];   // [ci<32][6][72], 54KB

    const int tid = threadIdx.x;
    const int p   = tid & 127;
    const int cog = __builtin_amdgcn_readfirstlane(tid >> 7);   // 0..3
    const int a   = p >> 5;
    const int c0  = (p & 31) * 2;

    const int n0   = blockIdx.x * 256;
    const int b    = n0 >> 12;
    const int row0 = (n0 & 4095) >> 6;
    const float* __restrict__ inb = in + (size_t)b * 64 * 4096;

    float4 pf4[7];
    auto stage_issue = [&](int half) {
#pragma unroll
        for (int m = 0; m < 7; m++) {
            const int f4 = m * 512 + tid;
            float4 v = make_float4(0.f, 0.f, 0.f, 0.f);
            if (f4 < 3456) {
                const int ci  = f4 / 108;
                const int rem = f4 - ci * 108;
                const int r6  = rem / 18;
                const int c4  = rem - r6 * 18;
                const int ih  = row0 + r6 - 1;
                if (ih >= 0 && ih < 64 && c4 >= 1 && c4 <= 16)
                    v = *(const float4*)(inb + (size_t)(half * 32 + ci) * 4096
                                         + ih * 64 + (c4 * 4 - 4));
            }
            pf4[m] = v;
        }
    };
    auto stage_commit = [&]() {
#pragma unroll
        for (int m = 0; m < 7; m++) {
            const int f4 = m * 512 + tid;
            if (f4 < 3456) *(float4*)(S + f4 * 4) = pf4[m];   // no relu
        }
    };

    const int co1 = cog * 16;
    float acc[16][2];
#pragma unroll
    for (int cc = 0; cc < 16; cc++) {
        const float bz = bias[co1 + cc];
        acc[cc][0] = bz; acc[cc][1] = bz;
    }

    auto conv_half = [&](int h) {
#pragma unroll 2
        for (int c = 0; c < 32; c++) {
            const float* __restrict__ wb =
                wr + (size_t)((h * 32 + c) * 9) * 64 + co1;
#pragma unroll
            for (int kh = 0; kh < 3; kh++) {
                const float* __restrict__ tp =
                    S + c * 432 + (a + kh) * 72 + 4 + c0;
                const float2 L = *(const float2*)(tp - 2);
                const float2 M = *(const float2*)(tp);
                const float2 R = *(const float2*)(tp + 2);
                const float xm = L.y;
                const float x0 = M.x;
                const float x1 = M.y;
                const float x2 = R.x;
                const float* __restrict__ wk = wb + (size_t)(kh * 3) * 64;
#pragma unroll
                for (int cc = 0; cc < 16; cc++) {    // kw = 0
                    const float w = wk[cc];
                    acc[cc][0] = fmaf(xm, w, acc[cc][0]);
                    acc[cc][1] = fmaf(x0, w, acc[cc][1]);
                }
#pragma unroll
                for (int cc = 0; cc < 16; cc++) {    // kw = 1
                    const float w = wk[64 + cc];
                    acc[cc][0] = fmaf(x0, w, acc[cc][0]);
                    acc[cc][1] = fmaf(x1, w, acc[cc][1]);
                }
#pragma unroll
                for (int cc = 0; cc < 16; cc++) {    // kw = 2
                    const float w = wk[128 + cc];
                    acc[cc][0] = fmaf(x1, w, acc[cc][0]);
                    acc[cc][1] = fmaf(x2, w, acc[cc][1]);
                }
            }
        }
    };

    stage_issue(0);
    stage_commit();
    __syncthreads();
    stage_issue(1);
    conv_half(0);
    __syncthreads();
    stage_commit();
    __syncthreads();
    conv_half(1);

    const int hw = (n0 & 4095) + p * 2;
    float* __restrict__ op = out + (size_t)b * 64 * 4096 + hw;
#pragma unroll
    for (int cc = 0; cc < 16; cc++)
        *(float2*)(op + (size_t)(co1 + cc) * 4096) =
            make_float2(acc[cc][0], acc[cc][1]);
}

// R24: stage-once stride-2 4x4 conv 32ci->64co (e2), split-px mapping.
// Lane owns out cols {j, j+32} of one row -> input window base 2j ->
// 8B lane stride -> 6 aligned ds_read_b64/step, conflict-light (res_tile
// pattern). Per step 64 FMA. Chain per output: bias, (ci,kh,kw) asc with
// same zero-pads == all prior versions => bit-exact.
__global__ __launch_bounds__(512, 4) void conv4s2_tile(
    const float* __restrict__ in, const float* __restrict__ wr,
    const float* __restrict__ bias, float* __restrict__ out)
{
    __shared__ __align__(16) float S[13056];   // [ci<16][6][136], 51KB

    const int tid = threadIdx.x;
    const int p   = tid & 63;
    const int cog = __builtin_amdgcn_readfirstlane(tid >> 6);   // 0..7
    const int a   = p >> 5;                 // out row (0..1)
    const int j   = p & 31;                 // out col pair {j, j+32}

    const int n0   = blockIdx.x * 128;
    const int b    = n0 >> 12;
    const int row0 = (n0 & 4095) >> 6;      // 2 out rows of 64
    const float* __restrict__ inb = in + (size_t)b * 32 * 16384;

    float4 pf4[7];
    auto stage_issue = [&](int half) {
#pragma unroll
        for (int m = 0; m < 7; m++) {
            const int f4 = m * 512 + tid;
            float4 v = make_float4(0.f, 0.f, 0.f, 0.f);
            if (f4 < 3264) {
                const int ci  = f4 / 204;
                const int rem = f4 - ci * 204;
                const int r6  = rem / 34;
                const int s   = rem - r6 * 34;
                const int ih  = 2 * row0 - 1 + r6;
                if (ih >= 0 && ih < 128 && s >= 1 && s <= 32)
                    v = *(const float4*)(inb + (size_t)(half * 16 + ci) * 16384
                                         + ih * 128 + (s - 1) * 4);
            }
            pf4[m] = v;
        }
    };
    auto stage_commit = [&]() {
#pragma unroll
        for (int m = 0; m < 7; m++) {
            const int f4 = m * 512 + tid;
            if (f4 < 3264) *(float4*)(S + f4 * 4) = pf4[m];   // no relu
        }
    };

    const int co1 = cog * 8;
    float acc[8][2];
#pragma unroll
    for (int cc = 0; cc < 8; cc++) {
        const float bz = bias[co1 + cc];
        acc[cc][0] = bz; acc[cc][1] = bz;
    }

    auto conv_half = [&](int h) {
#pragma unroll 2
        for (int c = 0; c < 16; c++) {
            const float* __restrict__ wb =
                wr + (size_t)((h * 16 + c) * 16) * 64 + co1;
#pragma unroll
            for (int kh = 0; kh < 4; kh++) {
                // out col j: taps iw=2j-1+kw -> tile t=2j+3+kw
                // out col j+32: t=2j+67+kw.  b64s at even t, 8B lane stride.
                const float* __restrict__ tp =
                    S + c * 816 + (2 * a + kh) * 136 + 2 * j + 2;
                const float2 L  = *(const float2*)(tp);       // t 2j+2,3
                const float2 M  = *(const float2*)(tp + 2);   // t 2j+4,5
                const float2 R  = *(const float2*)(tp + 4);   // t 2j+6,7
                const float2 L2 = *(const float2*)(tp + 64);  // t 2j+66,67
                const float2 M2 = *(const float2*)(tp + 66);
                const float2 R2 = *(const float2*)(tp + 68);
                const float xa0 = L.y,  xa1 = M.x,  xa2 = M.y,  xa3 = R.x;
                const float xb0 = L2.y, xb1 = M2.x, xb2 = M2.y, xb3 = R2.x;
                const float* __restrict__ wk = wb + (size_t)(kh * 4) * 64;
#pragma unroll
                for (int cc = 0; cc < 8; cc++) {     // kw = 0
                    const float w = wk[cc];
                    acc[cc][0] = fmaf(xa0, w, acc[cc][0]);
                    acc[cc][1] = fmaf(xb0, w, acc[cc][1]);
                }
#pragma unroll
                for (int cc = 0; cc < 8; cc++) {     // kw = 1
                    const float w = wk[64 + cc];
                    acc[cc][0] = fmaf(xa1, w, acc[cc][0]);
                    acc[cc][1] = fmaf(xb1, w, acc[cc][1]);
                }
#pragma unroll
                for (int cc = 0; cc < 8; cc++) {     // kw = 2
                    const float w = wk[128 + cc];
                    acc[cc][0] = fmaf(xa2, w, acc[cc][0]);
                    acc[cc][1] = fmaf(xb2, w, acc[cc][1]);
                }
#pragma unroll
                for (int cc = 0; cc < 8; cc++) {     // kw = 3
                    const float w = wk[192 + cc];
                    acc[cc][0] = fmaf(xa3, w, acc[cc][0]);
                    acc[cc][1] = fmaf(xb3, w, acc[cc][1]);
                }
            }
        }
    };

    stage_issue(0);
    stage_commit();
    __syncthreads();
    stage_issue(1);
    conv_half(0);
    __syncthreads();
    stage_commit();
    __syncthreads();
    conv_half(1);

    // out cols j and j+32 of row (row0 + a)
    const int hw = (n0 & 4095) + a * 64 + j;
    float* __restrict__ op = out + (size_t)b * 64 * 4096 + hw;
#pragma unroll
    for (int cc = 0; cc < 8; cc++) {
        float* __restrict__ o = op + (size_t)(co1 + cc) * 4096;
        o[0]  = acc[cc][0];
        o[32] = acc[cc][1];
    }
}

// R22: stage-once 1x1 conv 64ci->64co (pre). (validated)
__global__ __launch_bounds__(512, 4) void conv1x1_tile(
    const float* __restrict__ in, const float* __restrict__ wr,
    const float* __restrict__ bias, float* __restrict__ out)
{
    __shared__ __align__(16) float S[8192];    // [ci<32][256px], 32KB

    const int tid = threadIdx.x;
    const int p   = tid & 127;                                  // px-pair
    const int cog = __builtin_amdgcn_readfirstlane(tid >> 7);   // 0..3

    const int n0  = blockIdx.x * 256;
    const int b   = n0 >> 12;
    const int hw0 = n0 & 4095;
    const float* __restrict__ inb = in + (size_t)b * 64 * 4096 + hw0;

    float4 pf4[4];
    auto stage_issue = [&](int half) {
#pragma unroll
        for (int m = 0; m < 4; m++) {
            const int f4 = m * 512 + tid;        // 0..2047
            const int ci = f4 >> 6;
            const int c4 = f4 & 63;
            pf4[m] = *(const float4*)(inb + (size_t)(half * 32 + ci) * 4096
                                      + c4 * 4);
        }
    };
    auto stage_commit = [&]() {
#pragma unroll
        for (int m = 0; m < 4; m++) {
            const int f4 = m * 512 + tid;
            *(float4*)(S + f4 * 4) = pf4[m];
        }
    };

    const int co1 = cog * 16;
    float acc[16][2];
#pragma unroll
    for (int cc = 0; cc < 16; cc++) {
        const float bz = bias[co1 + cc];
        acc[cc][0] = bz; acc[cc][1] = bz;
    }

    auto conv_half = [&](int h) {
#pragma unroll 4
        for (int c = 0; c < 32; c++) {
            const float2 x = *(const float2*)(S + c * 256 + p * 2);
            const float* __restrict__ wk =
                wr + (size_t)(h * 32 + c) * 64 + co1;
#pragma unroll
            for (int cc = 0; cc < 16; cc++) {
                const float w = wk[cc];
                acc[cc][0] = fmaf(x.x, w, acc[cc][0]);
                acc[cc][1] = fmaf(x.y, w, acc[cc][1]);
            }
        }
    };

    stage_issue(0);
    stage_commit();
    __syncthreads();
    stage_issue(1);
    conv_half(0);
    __syncthreads();
    stage_commit();
    __syncthreads();
    conv_half(1);

    float* __restrict__ op = out + (size_t)b * 64 * 4096 + hw0 + p * 2;
#pragma unroll
    for (int cc = 0; cc < 16; cc++)
        *(float2*)(op + (size_t)(co1 + cc) * 4096) =
            make_float2(acc[cc][0], acc[cc][1]);
}

// R21: stage-once transposed conv t1 (validated).
__global__ __launch_bounds__(512, 4) void convt_tile(
    const float* __restrict__ in, const float* __restrict__ wr,
    const float* __restrict__ bias, float* __restrict__ out)
{
    __shared__ __align__(16) float S[13824];   // [ci<32][6][72], 54KB

    const int tid = threadIdx.x;
    const int p   = tid & 127;                                  // px-pair
    const int cog = __builtin_amdgcn_readfirstlane(tid >> 7);   // 0..3
    const int a   = p >> 5;                 // input row in block (0..3)
    const int c0  = (p & 31) * 2;           // input col base (0,2,..,62)

    const int n0   = blockIdx.x * 256;      // 256 input px = 4 rows
    const int b    = n0 >> 12;
    const int row0 = (n0 & 4095) >> 6;
    const float* __restrict__ inb = in + (size_t)b * 64 * 4096;

    float4 pf4[7];
    auto stage_issue = [&](int half) {
#pragma unroll
        for (int m = 0; m < 7; m++) {
            const int f4 = m * 512 + tid;
            float4 v = make_float4(0.f, 0.f, 0.f, 0.f);
            if (f4 < 3456) {
                const int ci  = f4 / 108;
                const int rem = f4 - ci * 108;
                const int r6  = rem / 18;
                const int c4  = rem - r6 * 18;
                const int ih  = row0 + r6 - 1;
                if (ih >= 0 && ih < 64 && c4 >= 1 && c4 <= 16)
                    v = *(const float4*)(inb + (size_t)(half * 32 + ci) * 4096
                                         + ih * 64 + (c4 * 4 - 4));
            }
            pf4[m] = v;
        }
    };
    auto stage_commit = [&]() {
#pragma unroll
        for (int m = 0; m < 7; m++) {
            const int f4 = m * 512 + tid;
            if (f4 < 3456) *(float4*)(S + f4 * 4) = pf4[m];   // no relu
        }
    };

    const int co1 = cog * 8;
    // acc[co][px][pc][pr]
    float acc[8][2][2][2];
#pragma unroll
    for (int cc = 0; cc < 8; cc++) {
        const float bz = bias[co1 + cc];
#pragma unroll
        for (int px = 0; px < 2; px++)
#pragma unroll
            for (int pc = 0; pc < 2; pc++) {
                acc[cc][px][pc][0] = bz;
                acc[cc][px][pc][1] = bz;
            }
    }

    auto conv_half = [&](int h) {
#pragma unroll 2
        for (int c = 0; c < 32; c++) {
            const int ci = h * 32 + c;
            float X[3][4];
#pragma unroll
            for (int r = 0; r < 3; r++) {
                const float* __restrict__ tp =
                    S + c * 432 + (a + r) * 72 + 4 + c0;
                const float2 L = *(const float2*)(tp - 2);
                const float2 M = *(const float2*)(tp);
                const float2 R = *(const float2*)(tp + 2);
                X[r][0] = L.y; X[r][1] = M.x; X[r][2] = M.y; X[r][3] = R.x;
            }
            const float* __restrict__ wb = wr + (size_t)(ci * 2) * 128 + co1;
#pragma unroll
            for (int ta = 0; ta < 2; ta++) {
                const float* X0 = X[1 - ta];
                const float* X1 = X[2 - ta];
                const float* __restrict__ wt = wb + ta * 128;
#pragma unroll
                for (int tb = 0; tb < 2; tb++) {
#pragma unroll
                    for (int pc = 0; pc < 2; pc++) {
                        const int m = pc - tb + 1;   // 0..2
                        const float* __restrict__ w0 = wt + (pc * 2 + tb) * 32;
                        const float* __restrict__ w1 = w0 + 16384;
#pragma unroll
                        for (int cc = 0; cc < 8; cc++) {
                            const float wv0 = w0[cc];
                            const float wv1 = w1[cc];
                            acc[cc][0][pc][0] =
                                fmaf(X0[m],     wv0, acc[cc][0][pc][0]);
                            acc[cc][1][pc][0] =
                                fmaf(X0[m + 1], wv0, acc[cc][1][pc][0]);
                            acc[cc][0][pc][1] =
                                fmaf(X1[m],     wv1, acc[cc][0][pc][1]);
                            acc[cc][1][pc][1] =
                                fmaf(X1[m + 1], wv1, acc[cc][1][pc][1]);
                        }
                    }
                }
            }
        }
    };

    stage_issue(0);
    stage_commit();
    __syncthreads();
    stage_issue(1);
    conv_half(0);
    __syncthreads();
    stage_commit();
    __syncthreads();
    conv_half(1);

    const int i = row0 + a;
    float* __restrict__ ob =
        out + (size_t)b * 32 * 16384 + (size_t)(2 * i) * 128 + 2 * c0;
#pragma unroll
    for (int cc = 0; cc < 8; cc++) {
        float* __restrict__ o = ob + (size_t)(co1 + cc) * 16384;
#pragma unroll
        for (int pr = 0; pr < 2; pr++) {
            const float4 v = make_float4(
                fmaxf(acc[cc][0][0][pr], 0.f), fmaxf(acc[cc][0][1][pr], 0.f),
                fmaxf(acc[cc][1][0][pr], 0.f), fmaxf(acc[cc][1][1][pr], 0.f));
            *(float4*)(o + (size_t)pr * 128) = v;
        }
    }
}

// Final transposed conv (32 -> 1). (validated)
__global__ __launch_bounds__(256) void convt2_quad(
    const float* __restrict__ in, const float* __restrict__ w,
    const float* __restrict__ bias, float* __restrict__ out, int B)
{
    const int IH = 128, IW = 128, CIN = 32, OW = 256;
    const int j = threadIdx.x & 127;
    const int i = (blockIdx.x << 1) + (threadIdx.x >> 7);
    const int b = blockIdx.y;

    const float* __restrict__ inb = in + (size_t)b * CIN * IH * IW;
    const float bz = bias[0];
    float a00 = bz, a01 = bz, a10 = bz, a11 = bz;

    const bool okm = (i > 0);
    const bool okp = (i < IH - 1);
    const bool olm = (j > 0);
    const bool olp = (j < IW - 1);

#pragma unroll 4
    for (int ci = 0; ci < CIN; ci++) {
        const float* __restrict__ p = inb + ((size_t)ci * IH + i) * IW + j;
        const float* __restrict__ wp = w + ci * 16;
        const float vmm = (okm && olm) ? p[-IW - 1] : 0.f;
        const float vm0 = okm ? p[-IW] : 0.f;
        const float vmp = (okm && olp) ? p[-IW + 1] : 0.f;
        const float v0m = olm ? p[-1] : 0.f;
        const float v00 = p[0];
        const float v0p = olp ? p[1] : 0.f;
        const float vpm = (okp && olm) ? p[IW - 1] : 0.f;
        const float vp0 = okp ? p[IW] : 0.f;
        const float vpp = (okp && olp) ? p[IW + 1] : 0.f;
        a00 = fmaf(v00, wp[1 * 4 + 1], a00);
        a00 = fmaf(v0m, wp[1 * 4 + 3], a00);
        a00 = fmaf(vm0, wp[3 * 4 + 1], a00);
        a00 = fmaf(vmm, wp[3 * 4 + 3], a00);
        a01 = fmaf(v0p, wp[1 * 4 + 0], a01);
        a01 = fmaf(v00, wp[1 * 4 + 2], a01);
        a01 = fmaf(vmp, wp[3 * 4 + 0], a01);
        a01 = fmaf(vm0, wp[3 * 4 + 2], a01);
        a10 = fmaf(vp0, wp[0 * 4 + 1], a10);
        a10 = fmaf(vpm, wp[0 * 4 + 3], a10);
        a10 = fmaf(v00, wp[2 * 4 + 1], a10);
        a10 = fmaf(v0m, wp[2 * 4 + 3], a10);
        a11 = fmaf(vpp, wp[0 * 4 + 0], a11);
        a11 = fmaf(vp0, wp[0 * 4 + 2], a11);
        a11 = fmaf(v0p, wp[2 * 4 + 0], a11);
        a11 = fmaf(v00, wp[2 * 4 + 2], a11);
    }

    float* __restrict__ outb = out + (size_t)b * 256 * 256;
    ((float2*)(outb + (size_t)(2 * i) * OW))[j] = make_float2(a00, a01);
    ((float2*)(outb + (size_t)(2 * i + 1) * OW))[j] = make_float2(a10, a11);
}

// VQ-GEMM (validated R9). DO NOT reorder any fmaf chain (R3).
__global__ __launch_bounds__(256) void vq_gemm(
    const float* __restrict__ h,    // (32,64,4096)
    const float* __restrict__ cb,   // (512,64) row-major (gather)
    const float* __restrict__ cbT,  // (64,512) dim-major (matmul)
    const float* __restrict__ ee,   // (512)
    float* __restrict__ q)          // (32,64,4096)
{
    __shared__ __align__(16) float As[64 * 128];
    __shared__ float xx_sh[128];
    __shared__ float pd[4 * 128];
    __shared__ int   pk[4 * 128];
    __shared__ int   bidx_sh[128];

    const int tid = threadIdx.x;
    const int tpx = tid & 63;
    const int w = __builtin_amdgcn_readfirstlane(tid >> 6);
    const int n0 = blockIdx.x * 128;
    const int b  = n0 >> 12;
    const int hw0 = n0 & 4095;

    const float* __restrict__ hb = h + (size_t)b * 64 * 4096 + hw0;
#pragma unroll
    for (int m = 0; m < 32; m++) {
        const int idx = m * 256 + tid;
        const int k = idx >> 7, p = idx & 127;
        As[idx] = hb[(size_t)k * 4096 + p];
    }
    __syncthreads();

    if (tid < 128) {
        float s = 0.0f;
#pragma unroll
        for (int i = 0; i < 64; i++) {
            const float v = As[i * 128 + tid];
            s = fmaf(v, v, s);
        }
        xx_sh[tid] = s;
    }
    __syncthreads();

    const float xx0 = xx_sh[tpx * 2];
    const float xx1 = xx_sh[tpx * 2 + 1];
    const int cwave = w * 128;

    float best0 = 3.402823466e+38f, best1 = 3.402823466e+38f;
    int bk0 = 0, bk1 = 0;

#pragma unroll 1
    for (int ch = 0; ch < 16; ch++) {
        const int cbase = cwave + ch * 8;
        float acc[8][2];
#pragma unroll
        for (int c = 0; c < 8; c++) { acc[c][0] = 0.0f; acc[c][1] = 0.0f; }

#pragma unroll 8
        for (int k = 0; k < 64; k++) {
            const float2 a2 = *(const float2*)(As + k * 128 + tpx * 2);
            const float* __restrict__ wk = cbT + (size_t)k * 512 + cbase;
#pragma unroll
            for (int c = 0; c < 8; c++) {
                const float wv = wk[c];
                acc[c][0] = fmaf(a2.x, wv, acc[c][0]);
                acc[c][1] = fmaf(a2.y, wv, acc[c][1]);
            }
        }
        const float* __restrict__ eep = ee + cbase;
#pragma unroll
        for (int c = 0; c < 8; c++) {
            const float eec = eep[c];
            const float d0 = xx0 - 2.0f * acc[c][0] + eec;
            const float d1 = xx1 - 2.0f * acc[c][1] + eec;
            if (d0 < best0) { best0 = d0; bk0 = cbase + c; }
            if (d1 < best1) { best1 = d1; bk1 = cbase + c; }
        }
    }

    pd[w * 128 + tpx * 2]     = best0;
    pd[w * 128 + tpx * 2 + 1] = best1;
    pk[w * 128 + tpx * 2]     = bk0;
    pk[w * 128 + tpx * 2 + 1] = bk1;
    __syncthreads();

    if (tid < 128) {
        float bd = pd[tid]; int bk = pk[tid];
#pragma unroll
        for (int ww = 1; ww < 4; ww++) {
            const float od = pd[ww * 128 + tid];
            if (od < bd) { bd = od; bk = pk[ww * 128 + tid]; }
        }
        bidx_sh[tid] = bk;
    }
    __syncthreads();

    {
        const int p  = tid & 127;
        const int d0 = (tid >> 7) * 32;
        const int bk = bidx_sh[p];
        const float4* __restrict__ cp4 = (const float4*)(cb + (size_t)bk * 64 + d0);
        float* __restrict__ qb = q + ((size_t)b * 64 + d0) * 4096 + hw0 + p;
#pragma unroll
        for (int i = 0; i < 8; i++) {
            const float4 v = cp4[i];
            qb[(size_t)(4 * i + 0) * 4096] = v.x;
            qb[(size_t)(4 * i + 1) * 4096] = v.y;
            qb[(size_t)(4 * i + 2) * 4096] = v.z;
            qb[(size_t)(4 * i + 3) * 4096] = v.w;
        }
    }
}

extern "C" void kernel_launch(void* const* d_in, const int* in_sizes, int n_in,
                              void* d_out, int out_size, void* d_ws, size_t ws_size,
                              hipStream_t stream) {
    const float* x      = (const float*)d_in[0];
    const float* w_e1   = (const float*)d_in[1];
    const float* b_e1   = (const float*)d_in[2];
    const float* w_e2   = (const float*)d_in[3];
    const float* b_e2   = (const float*)d_in[4];
    const float* w_er1a = (const float*)d_in[5];
    const float* w_er1b = (const float*)d_in[6];
    const float* w_er2a = (const float*)d_in[7];
    const float* w_er2b = (const float*)d_in[8];
    const float* w_pre  = (const float*)d_in[9];
    const float* b_pre  = (const float*)d_in[10];
    const float* cbk    = (const float*)d_in[11];
    const float* w_d1   = (const float*)d_in[12];
    const float* b_d1   = (const float*)d_in[13];
    const float* w_dr1a = (const float*)d_in[14];
    const float* w_dr1b = (const float*)d_in[15];
    const float* w_dr2a = (const float*)d_in[16];
    const float* w_dr2b = (const float*)d_in[17];
    const float* w_t1   = (const float*)d_in[18];
    const float* b_t1   = (const float*)d_in[19];
    const float* w_t2   = (const float*)d_in[20];
    const float* b_t2   = (const float*)d_in[21];
    float* out = (float*)d_out;

    float* A  = (float*)d_ws;            // 16777216 floats (scratch + t1 out)
    float* Bb = A  + 16777216;           // (32,64,64,64) = 8388608
    float* C  = Bb + 8388608;            // 4194304 (unused after fusion)
    float* D  = C  + 4194304;            // (32,64,64,64) = 8388608
    float* WR = D  + 8388608;            // repacked weights + cbT (221696)
    float* EE = WR + 221696;             // ee (512)

    float* r_e1  = WR;
    float* r_e2  = WR + 512;
    float* r_er1a = WR + 33280;
    float* r_er1b = WR + 51712;
    float* r_er2a = WR + 53760;
    float* r_er2b = WR + 72192;
    float* r_pre = WR + 74240;
    float* r_d1  = WR + 78336;
    float* r_dr1a = WR + 115200;
    float* r_dr1b = WR + 133632;
    float* r_dr2a = WR + 135680;
    float* r_dr2b = WR + 154112;
    float* r_t1  = WR + 156160;
    float* r_cbT = WR + 188928;

    const dim3 blk(256);
    const dim3 blk512(512);

    repack_all<<<dim3(866), blk, 0, stream>>>(
        w_e1, w_e2, w_er1a, w_er1b, w_er2a, w_er2b, w_pre, w_d1,
        w_dr1a, w_dr1b, w_dr2a, w_dr2b, w_t1, cbk, WR);
    vq_prep_ee<<<dim3(2), blk, 0, stream>>>(cbk, EE);

    // Encoder
    conv_gemm<32, 32, 1, 4, 2, 1, false, true, false, true>
        <<<dim3(2048, 1), blk, 0, stream>>>(x, r_e1, b_e1, nullptr, A,
                                            256, 256, 128, 128);
    conv4s2_tile<<<dim3(1024), blk512, 0, stream>>>(A, r_e2, b_e2, Bb);
    // er1: Bb -> A ; er2: A -> Bb (ping-pong avoids in-place halo race)
    res_tile<<<dim3(512), blk512, 0, stream>>>(Bb, r_er1a, r_er1b, A);
    res_tile<<<dim3(512), blk512, 0, stream>>>(A, r_er2a, r_er2b, Bb);
    // pre: stage-once 1x1
    conv1x1_tile<<<dim3(512), blk512, 0, stream>>>(Bb, r_pre, b_pre, D);
    // VQ
    vq_gemm<<<dim3(1024), blk, 0, stream>>>(D, cbk, r_cbT, EE, Bb);
    // Decoder
    conv3_tile<<<dim3(512), blk512, 0, stream>>>(Bb, r_d1, b_d1, D);
    // dr1: D -> A ; dr2: A -> D
    res_tile<<<dim3(512), blk512, 0, stream>>>(D, r_dr1a, r_dr1b, A);
    res_tile<<<dim3(512), blk512, 0, stream>>>(A, r_dr2a, r_dr2b, D);
    // t1 stage-once: grid 512, both pr per block
    convt_tile<<<dim3(512), blk512, 0, stream>>>(D, r_t1, b_t1, A);
    // t2
    convt2_quad<<<dim3(64, 32), blk, 0, stream>>>(A, w_t2, b_t2, out, 32);
}